// Round 2
// baseline (330.605 us; speedup 1.0000x reference)
//
#include <hip/hip_runtime.h>
#include <math.h>

// ---------------------------------------------------------------------------
// B=1024, x:(B,66,64) f32
// conv(32,1,5,5) VALID -> relu -> maxpool4 -> hp (B,32,62,15) flat
// (B*62,480) -> G1: xa=tanh(X@bn_w+bn_b) (.,64), z=X@g_w (.,32)
// tail (fused per batch): S=xa@xa^T, softmax rows (topk==N => mask no-op),
//   diag<-1, degnorm, adj@z+gb -> stage2 -> stage3 -> maxpool3 -> fc
// ---------------------------------------------------------------------------

// ============================ conv + relu + pool4 ===========================
// wave-uniform channel-pair => weights in SGPRs; LDS-staged coalesced writes
__global__ __launch_bounds__(256) void conv_pool_kernel(
    const float* __restrict__ x,      // (B,66,64)
    const float* __restrict__ cw,     // (32,1,5,5)
    const float* __restrict__ cb,     // (32,)
    float* __restrict__ hp)           // (B,29760)
{
    __shared__ float4 xs[66 * 17];                    // 17.95 KB
    __shared__ __align__(16) float stage[4][1872];    // 29.95 KB
    const int b = blockIdx.x;
    const int tid = threadIdx.x;
    const int wv = tid >> 6, ln = tid & 63;

    const float4* xg = (const float4*)(x + (size_t)b * 4224);
    for (int idx = tid; idx < 1056; idx += 256)
        xs[(idx >> 4) * 17 + (idx & 15)] = xg[idx];
    __syncthreads();

    for (int it = 0; it < 4; ++it) {
        // wave-uniform channel pair -> scalar loads for weights
        const int c0 = __builtin_amdgcn_readfirstlane((wv * 4 + it) * 2);
        float w0[25], w1[25];
        #pragma unroll
        for (int i = 0; i < 25; ++i) {
            w0[i] = cw[c0 * 25 + i];
            w1[i] = cw[c0 * 25 + 25 + i];
        }
        const float b0 = cb[c0], b1 = cb[c0 + 1];

        if (ln < 62) {
            const int r = ln;
            float* st0 = &stage[wv][r * 15];
            float Af[5][4], Bf[5][4];
            #pragma unroll
            for (int di = 0; di < 5; ++di) {
                float4 t = xs[(r + di) * 17];
                Af[di][0] = t.x; Af[di][1] = t.y; Af[di][2] = t.z; Af[di][3] = t.w;
            }
            #pragma unroll
            for (int jp = 0; jp < 15; ++jp) {
                #pragma unroll
                for (int di = 0; di < 5; ++di) {
                    float4 t = xs[(r + di) * 17 + jp + 1];
                    Bf[di][0] = t.x; Bf[di][1] = t.y; Bf[di][2] = t.z; Bf[di][3] = t.w;
                }
                float mm0 = -1e30f, mm1 = -1e30f;
                #pragma unroll
                for (int dj = 0; dj < 4; ++dj) {
                    float s0 = b0, s1 = b1;
                    #pragma unroll
                    for (int di = 0; di < 5; ++di) {
                        #pragma unroll
                        for (int k = 0; k < 5; ++k) {
                            const int col = dj + k;
                            const float v = (col < 4) ? Af[di][col] : Bf[di][col - 4];
                            s0 = fmaf(v, w0[di * 5 + k], s0);
                            s1 = fmaf(v, w1[di * 5 + k], s1);
                        }
                    }
                    mm0 = fmaxf(mm0, s0); mm1 = fmaxf(mm1, s1);
                }
                st0[jp]       = fmaxf(mm0, 0.f);   // pool(relu) == relu(max)
                st0[930 + jp] = fmaxf(mm1, 0.f);
                #pragma unroll
                for (int di = 0; di < 5; ++di) {
                    Af[di][0] = Bf[di][0]; Af[di][1] = Bf[di][1];
                    Af[di][2] = Bf[di][2]; Af[di][3] = Bf[di][3];
                }
            }
        }
        __syncthreads();
        {   // coalesced flush of this wave's 1860-float span
            float4* dst = (float4*)(hp + (size_t)b * 29760 + c0 * 930);
            const float4* src = (const float4*)stage[wv];
            #pragma unroll
            for (int i = 0; i < 8; ++i) {
                const int idx = ln + i * 64;
                if (idx < 465) dst[idx] = src[idx];
            }
        }
        __syncthreads();
    }
}

// =================== G1: (63488,480)@(480,96) + activations =================
__global__ __launch_bounds__(256) void g1_kernel(
    const float* __restrict__ X,    // (63488,480) == hp
    const float* __restrict__ bnw,  // (480,64)
    const float* __restrict__ bnb,  // (64,)
    const float* __restrict__ gw,   // (480,32)
    float* __restrict__ xa,         // (63488,64) tanh'ed
    float* __restrict__ z)          // (63488,32)
{
    __shared__ float4 Xs[128 * 9];
    __shared__ float4 Wt[96 * 9];
    const int tid = threadIdx.x;
    const int m0 = blockIdx.x * 128;
    const int tx = tid & 15, ty = tid >> 4;

    float acc[8][6];
    #pragma unroll
    for (int i = 0; i < 8; ++i)
        #pragma unroll
        for (int j = 0; j < 6; ++j) acc[i][j] = 0.f;

    for (int kc = 0; kc < 15; ++kc) {
        #pragma unroll
        for (int i = 0; i < 4; ++i) {
            const int idx = tid + i * 256;
            const int row = idx >> 3, c4 = idx & 7;
            Xs[row * 9 + c4] = ((const float4*)X)[(size_t)(m0 + row) * 120 + kc * 8 + c4];
        }
        #pragma unroll
        for (int i = 0; i < 3; ++i) {
            const int idx = tid + i * 256;
            const int j = idx >> 3, c4 = idx & 7;
            const int k0 = kc * 32 + c4 * 4;
            float4 v;
            if (j < 64) {
                v.x = bnw[(k0+0)*64 + j]; v.y = bnw[(k0+1)*64 + j];
                v.z = bnw[(k0+2)*64 + j]; v.w = bnw[(k0+3)*64 + j];
            } else {
                const int jj = j - 64;
                v.x = gw[(k0+0)*32 + jj]; v.y = gw[(k0+1)*32 + jj];
                v.z = gw[(k0+2)*32 + jj]; v.w = gw[(k0+3)*32 + jj];
            }
            Wt[j * 9 + c4] = v;
        }
        __syncthreads();
        #pragma unroll 4
        for (int c4 = 0; c4 < 8; ++c4) {
            float4 xv[8], wvv[6];
            #pragma unroll
            for (int i = 0; i < 8; ++i) xv[i] = Xs[(ty + i * 16) * 9 + c4];
            #pragma unroll
            for (int j = 0; j < 6; ++j) wvv[j] = Wt[(tx + j * 16) * 9 + c4];
            #pragma unroll
            for (int i = 0; i < 8; ++i)
                #pragma unroll
                for (int j = 0; j < 6; ++j) {
                    acc[i][j] = fmaf(xv[i].x, wvv[j].x, acc[i][j]);
                    acc[i][j] = fmaf(xv[i].y, wvv[j].y, acc[i][j]);
                    acc[i][j] = fmaf(xv[i].z, wvv[j].z, acc[i][j]);
                    acc[i][j] = fmaf(xv[i].w, wvv[j].w, acc[i][j]);
                }
        }
        __syncthreads();
    }
    #pragma unroll
    for (int i = 0; i < 8; ++i) {
        const size_t row = (size_t)m0 + ty + i * 16;
        #pragma unroll
        for (int j = 0; j < 6; ++j) {
            const int col = tx + j * 16;
            if (col < 64) xa[row * 64 + col] = tanhf(acc[i][j] + bnb[col]);
            else          z[row * 32 + (col - 64)] = acc[i][j];
        }
    }
}

// ===================== fused tail helpers (all in LDS) ======================
// xasf: [64][68] floats; S: [64][68]; zbuf/xbuf: [64][36]
__device__ __forceinline__ void sgemm62(const float* __restrict__ xasf,
                                        float* __restrict__ S,
                                        const int tx, const int ty)
{
    const int n0 = ty * 4, m0 = tx * 4;
    float acc[4][4] = {};
    #pragma unroll 4
    for (int c4 = 0; c4 < 16; ++c4) {
        float4 xv[4], wv[4];
        #pragma unroll
        for (int i = 0; i < 4; ++i) xv[i] = *(const float4*)&xasf[(n0 + i) * 68 + c4 * 4];
        #pragma unroll
        for (int j = 0; j < 4; ++j) wv[j] = *(const float4*)&xasf[(m0 + j) * 68 + c4 * 4];
        #pragma unroll
        for (int i = 0; i < 4; ++i)
            #pragma unroll
            for (int j = 0; j < 4; ++j) {
                acc[i][j] = fmaf(xv[i].x, wv[j].x, acc[i][j]);
                acc[i][j] = fmaf(xv[i].y, wv[j].y, acc[i][j]);
                acc[i][j] = fmaf(xv[i].z, wv[j].z, acc[i][j]);
                acc[i][j] = fmaf(xv[i].w, wv[j].w, acc[i][j]);
            }
    }
    #pragma unroll
    for (int i = 0; i < 4; ++i)
        #pragma unroll
        for (int j = 0; j < 4; ++j)
            if (n0 + i < 62 && m0 + j < 62) S[(n0 + i) * 68 + (m0 + j)] = acc[i][j];
}

// softmax rows, diag<-1, deg-norm, out = D S D @ z + gb  (out stride 36, LDS)
__device__ __forceinline__ void graph_post36(
    float* __restrict__ S, const float* __restrict__ zf,
    float* __restrict__ degis, const float* __restrict__ gb,
    float* __restrict__ outp, const int tid)
{
    if (tid < 248) {
        const int n = tid >> 2, s = tid & 3;
        float* Sr = S + n * 68;
        float mx = -1e30f;
        for (int m = s; m < 62; m += 4) mx = fmaxf(mx, Sr[m]);
        mx = fmaxf(mx, __shfl_xor(mx, 1));
        mx = fmaxf(mx, __shfl_xor(mx, 2));
        float sum = 0.f;
        for (int m = s; m < 62; m += 4) { const float e = __expf(Sr[m] - mx); Sr[m] = e; sum += e; }
        sum += __shfl_xor(sum, 1);
        sum += __shfl_xor(sum, 2);
        const float inv = 1.f / sum;
        for (int m = s; m < 62; m += 4) Sr[m] *= inv;
    }
    __syncthreads();
    if (tid < 62) S[tid * 68 + tid] = 1.f;
    __syncthreads();
    if (tid < 248) {
        const int n = tid >> 2, s = tid & 3;
        const float* Sr = S + n * 68;
        float dg = 0.f;
        for (int m = s; m < 62; m += 4) dg += Sr[m];
        dg += __shfl_xor(dg, 1);
        dg += __shfl_xor(dg, 2);
        if (s == 0) degis[n] = rsqrtf(fmaxf(dg, 1.f));
    }
    __syncthreads();
    if (tid < 248) {
        const int n = tid >> 2, s = tid & 3;
        float* Sr = S + n * 68;
        for (int m = s; m < 62; m += 4) Sr[m] *= degis[m];
    }
    __syncthreads();
    {
        const int tx = tid & 15, ty = tid >> 4;
        const int n0 = ty * 4, o0 = tx * 2;
        float a[4][2] = {};
        for (int m = 0; m < 62; ++m) {
            const float z0 = zf[m * 36 + o0], z1 = zf[m * 36 + o0 + 1];
            #pragma unroll
            for (int i = 0; i < 4; ++i) {
                const float sv = S[(n0 + i) * 68 + m];
                a[i][0] = fmaf(sv, z0, a[i][0]);
                a[i][1] = fmaf(sv, z1, a[i][1]);
            }
        }
        const float gb0 = gb[o0], gb1 = gb[o0 + 1];
        #pragma unroll
        for (int i = 0; i < 4; ++i) {
            const int n = n0 + i;
            if (n < 62) {
                const float d = degis[n];
                outp[n * 36 + o0]     = fmaf(d, a[i][0], gb0);
                outp[n * 36 + o0 + 1] = fmaf(d, a[i][1], gb1);
            }
        }
    }
}

// xa2 = tanh(x@bnw+bnb) -> xasf; z2 = x@gw -> zbuf
__device__ __forceinline__ void stage_gemms(
    const float* __restrict__ xbuf, const float* __restrict__ bnws,
    const float* __restrict__ bnb, const float* __restrict__ gws,
    float* __restrict__ xasf, float* __restrict__ zbuf,
    const int tx, const int ty)
{
    const int n0 = ty * 4;
    {
        const int j0 = tx * 4;
        float acc[4][4] = {};
        #pragma unroll 4
        for (int k = 0; k < 32; ++k) {
            const float4 wv = *(const float4*)&bnws[k * 68 + j0];
            #pragma unroll
            for (int i = 0; i < 4; ++i) {
                const float xv = xbuf[(n0 + i) * 36 + k];
                acc[i][0] = fmaf(xv, wv.x, acc[i][0]);
                acc[i][1] = fmaf(xv, wv.y, acc[i][1]);
                acc[i][2] = fmaf(xv, wv.z, acc[i][2]);
                acc[i][3] = fmaf(xv, wv.w, acc[i][3]);
            }
        }
        #pragma unroll
        for (int i = 0; i < 4; ++i)
            #pragma unroll
            for (int j = 0; j < 4; ++j)
                xasf[(n0 + i) * 68 + j0 + j] = tanhf(acc[i][j] + bnb[j0 + j]);
    }
    {
        const int o0 = tx * 2;
        float acc[4][2] = {};
        #pragma unroll 4
        for (int k = 0; k < 32; ++k) {
            const float w0 = gws[k * 36 + o0], w1 = gws[k * 36 + o0 + 1];
            #pragma unroll
            for (int i = 0; i < 4; ++i) {
                const float xv = xbuf[(n0 + i) * 36 + k];
                acc[i][0] = fmaf(xv, w0, acc[i][0]);
                acc[i][1] = fmaf(xv, w1, acc[i][1]);
            }
        }
        #pragma unroll
        for (int i = 0; i < 4; ++i)
            if (n0 + i < 62) {
                zbuf[(n0 + i) * 36 + o0]     = acc[i][0];
                zbuf[(n0 + i) * 36 + o0 + 1] = acc[i][1];
            }
    }
}

// ====== fused tail: sogc1(from xa,z) -> sogc2 -> sogc3 -> pool3 -> fc =======
__global__ __launch_bounds__(256) void sogc_tail_kernel(
    const float* __restrict__ xa,   // (B,62,64)
    const float* __restrict__ z,    // (B,62,32)
    const float* __restrict__ gb1,
    const float* __restrict__ bnw2, const float* __restrict__ bnb2,
    const float* __restrict__ gw2,  const float* __restrict__ gb2,
    const float* __restrict__ bnw3, const float* __restrict__ bnb3,
    const float* __restrict__ gw3,  const float* __restrict__ gb3,
    const float* __restrict__ fcw,  const float* __restrict__ fcb,
    float* __restrict__ out)        // (B,3)
{
    __shared__ __align__(16) float xasf[64 * 68];
    __shared__ __align__(16) float S[64 * 68];
    __shared__ __align__(16) float zbuf[64 * 36];
    __shared__ __align__(16) float xbuf[64 * 36];
    __shared__ __align__(16) float bnws[32 * 68];
    __shared__ __align__(16) float gws[32 * 36];
    __shared__ float degis[62];
    const int b = blockIdx.x;
    const int tid = threadIdx.x;
    const int tx = tid & 15, ty = tid >> 4;

    // stage-1 inputs + stage-2 weights
    const float4* xag = (const float4*)(xa + (size_t)b * 3968);
    for (int idx = tid; idx < 992; idx += 256)
        *(float4*)&xasf[(idx >> 4) * 68 + (idx & 15) * 4] = xag[idx];
    const float4* zg = (const float4*)(z + (size_t)b * 1984);
    for (int idx = tid; idx < 496; idx += 256)
        *(float4*)&zbuf[(idx >> 3) * 36 + (idx & 7) * 4] = zg[idx];
    for (int idx = tid; idx < 512; idx += 256)
        *(float4*)&bnws[(idx >> 4) * 68 + (idx & 15) * 4] = ((const float4*)bnw2)[idx];
    if (tid < 256)
        *(float4*)&gws[(tid >> 3) * 36 + (tid & 7) * 4] = ((const float4*)gw2)[tid];
    __syncthreads();

    // ---- stage 1 ----
    sgemm62(xasf, S, tx, ty);
    __syncthreads();
    graph_post36(S, zbuf, degis, gb1, xbuf, tid);
    __syncthreads();

    // ---- stage 2 ----
    stage_gemms(xbuf, bnws, bnb2, gws, xasf, zbuf, tx, ty);
    __syncthreads();
    // prefetch stage-3 weights (bnws/gws dead until after next barrier)
    for (int idx = tid; idx < 512; idx += 256)
        *(float4*)&bnws[(idx >> 4) * 68 + (idx & 15) * 4] = ((const float4*)bnw3)[idx];
    if (tid < 256)
        *(float4*)&gws[(tid >> 3) * 36 + (tid & 7) * 4] = ((const float4*)gw3)[tid];
    sgemm62(xasf, S, tx, ty);
    __syncthreads();
    graph_post36(S, zbuf, degis, gb2, xbuf, tid);
    __syncthreads();

    // ---- stage 3 ----
    stage_gemms(xbuf, bnws, bnb3, gws, xasf, zbuf, tx, ty);
    __syncthreads();
    sgemm62(xasf, S, tx, ty);
    __syncthreads();
    graph_post36(S, zbuf, degis, gb3, xbuf, tid);
    __syncthreads();

    // ---- maxpool3 + fc ----
    float a0 = 0.f, a1 = 0.f, a2 = 0.f;
    for (int t = tid; t < 620; t += 256) {
        const int n = t / 10, tt = t % 10;
        const float* p3 = &xbuf[n * 36 + tt * 3];
        const float p = fmaxf(fmaxf(p3[0], p3[1]), p3[2]);
        a0 = fmaf(p, fcw[t * 3 + 0], a0);
        a1 = fmaf(p, fcw[t * 3 + 1], a1);
        a2 = fmaf(p, fcw[t * 3 + 2], a2);
    }
    #pragma unroll
    for (int off = 32; off; off >>= 1) {
        a0 += __shfl_down(a0, off);
        a1 += __shfl_down(a1, off);
        a2 += __shfl_down(a2, off);
    }
    float* red = S;  // S is dead now; reuse as reduction scratch
    const int wv = tid >> 6, ln = tid & 63;
    if (ln == 0) { red[wv * 3 + 0] = a0; red[wv * 3 + 1] = a1; red[wv * 3 + 2] = a2; }
    __syncthreads();
    if (tid == 0) {
        out[b * 3 + 0] = red[0] + red[3] + red[6] + red[9]  + fcb[0];
        out[b * 3 + 1] = red[1] + red[4] + red[7] + red[10] + fcb[1];
        out[b * 3 + 2] = red[2] + red[5] + red[8] + red[11] + fcb[2];
    }
}

// ============================== launcher ====================================
extern "C" void kernel_launch(void* const* d_in, const int* in_sizes, int n_in,
                              void* d_out, int out_size, void* d_ws, size_t ws_size,
                              hipStream_t stream) {
    const float* x     = (const float*)d_in[0];
    const float* convw = (const float*)d_in[1];
    const float* convb = (const float*)d_in[2];
    const float* bnw1  = (const float*)d_in[3];
    const float* bnb1  = (const float*)d_in[4];
    const float* gw1   = (const float*)d_in[5];
    const float* gb1   = (const float*)d_in[6];
    const float* bnw2  = (const float*)d_in[7];
    const float* bnb2  = (const float*)d_in[8];
    const float* gw2   = (const float*)d_in[9];
    const float* gb2   = (const float*)d_in[10];
    const float* bnw3  = (const float*)d_in[11];
    const float* bnb3  = (const float*)d_in[12];
    const float* gw3   = (const float*)d_in[13];
    const float* gb3   = (const float*)d_in[14];
    const float* fcw   = (const float*)d_in[15];
    const float* fcb   = (const float*)d_in[16];

    char* ws = (char*)d_ws;
    float* hp = (float*)(ws);                    // 121,927,680 B
    float* xa = (float*)(ws + 121927680);        // 16,252,928 B
    float* z  = (float*)(ws + 138180608);        //  8,126,464 B

    conv_pool_kernel<<<1024, 256, 0, stream>>>(x, convw, convb, hp);
    g1_kernel<<<496, 256, 0, stream>>>(hp, bnw1, bnb1, gw1, xa, z);
    sogc_tail_kernel<<<1024, 256, 0, stream>>>(xa, z, gb1,
                                               bnw2, bnb2, gw2, gb2,
                                               bnw3, bnb3, gw3, gb3,
                                               fcw, fcb, (float*)d_out);
}

// Round 3
// 253.555 us; speedup vs baseline: 1.3039x; 1.3039x over previous
//
#include <hip/hip_runtime.h>
#include <math.h>

// ---------------------------------------------------------------------------
// B=1024, x:(B,66,64) f32
// conv(32,1,5,5) VALID -> relu -> maxpool4 -> hp (B,32,62,15) flat
// (B*62,480) -> G1: xa=tanh(X@bn_w+bn_b) (.,64), z=X@g_w (.,32)
// tail (fused per batch, v3): S=xa@xa^T (LDS, XOR-swizzled), REGISTER softmax
//   (row ops via shfl_xor across tx lanes), diag<-1, degnorm folded into S,
//   adj@z via transposed zT (all-float4), weights overlaid into S region.
// ---------------------------------------------------------------------------

// ============================ conv + relu + pool4 ===========================
__global__ __launch_bounds__(256) void conv_pool_kernel(
    const float* __restrict__ x,      // (B,66,64)
    const float* __restrict__ cw,     // (32,1,5,5)
    const float* __restrict__ cb,     // (32,)
    float* __restrict__ hp)           // (B,29760)
{
    __shared__ float4 xs[66 * 17];
    __shared__ __align__(16) float stage[4][1872];
    const int b = blockIdx.x;
    const int tid = threadIdx.x;
    const int wv = tid >> 6, ln = tid & 63;

    const float4* xg = (const float4*)(x + (size_t)b * 4224);
    for (int idx = tid; idx < 1056; idx += 256)
        xs[(idx >> 4) * 17 + (idx & 15)] = xg[idx];
    __syncthreads();

    for (int it = 0; it < 4; ++it) {
        const int c0 = __builtin_amdgcn_readfirstlane((wv * 4 + it) * 2);
        float w0[25], w1[25];
        #pragma unroll
        for (int i = 0; i < 25; ++i) {
            w0[i] = cw[c0 * 25 + i];
            w1[i] = cw[c0 * 25 + 25 + i];
        }
        const float b0 = cb[c0], b1 = cb[c0 + 1];

        if (ln < 62) {
            const int r = ln;
            float* st0 = &stage[wv][r * 15];
            float Af[5][4], Bf[5][4];
            #pragma unroll
            for (int di = 0; di < 5; ++di) {
                float4 t = xs[(r + di) * 17];
                Af[di][0] = t.x; Af[di][1] = t.y; Af[di][2] = t.z; Af[di][3] = t.w;
            }
            #pragma unroll
            for (int jp = 0; jp < 15; ++jp) {
                #pragma unroll
                for (int di = 0; di < 5; ++di) {
                    float4 t = xs[(r + di) * 17 + jp + 1];
                    Bf[di][0] = t.x; Bf[di][1] = t.y; Bf[di][2] = t.z; Bf[di][3] = t.w;
                }
                float mm0 = -1e30f, mm1 = -1e30f;
                #pragma unroll
                for (int dj = 0; dj < 4; ++dj) {
                    float s0 = b0, s1 = b1;
                    #pragma unroll
                    for (int di = 0; di < 5; ++di) {
                        #pragma unroll
                        for (int k = 0; k < 5; ++k) {
                            const int col = dj + k;
                            const float v = (col < 4) ? Af[di][col] : Bf[di][col - 4];
                            s0 = fmaf(v, w0[di * 5 + k], s0);
                            s1 = fmaf(v, w1[di * 5 + k], s1);
                        }
                    }
                    mm0 = fmaxf(mm0, s0); mm1 = fmaxf(mm1, s1);
                }
                st0[jp]       = fmaxf(mm0, 0.f);
                st0[930 + jp] = fmaxf(mm1, 0.f);
                #pragma unroll
                for (int di = 0; di < 5; ++di) {
                    Af[di][0] = Bf[di][0]; Af[di][1] = Bf[di][1];
                    Af[di][2] = Bf[di][2]; Af[di][3] = Bf[di][3];
                }
            }
        }
        __syncthreads();
        {
            float4* dst = (float4*)(hp + (size_t)b * 29760 + c0 * 930);
            const float4* src = (const float4*)stage[wv];
            #pragma unroll
            for (int i = 0; i < 8; ++i) {
                const int idx = ln + i * 64;
                if (idx < 465) dst[idx] = src[idx];
            }
        }
        __syncthreads();
    }
}

// =================== G1: (63488,480)@(480,96) + activations =================
__global__ __launch_bounds__(256) void g1_kernel(
    const float* __restrict__ X,
    const float* __restrict__ bnw,  // (480,64)
    const float* __restrict__ bnb,
    const float* __restrict__ gw,   // (480,32)
    float* __restrict__ xa,         // (63488,64)
    float* __restrict__ z)          // (63488,32)
{
    __shared__ float4 Xs[128 * 9];
    __shared__ float4 Wt[96 * 9];
    const int tid = threadIdx.x;
    const int m0 = blockIdx.x * 128;
    const int tx = tid & 15, ty = tid >> 4;

    float acc[8][6];
    #pragma unroll
    for (int i = 0; i < 8; ++i)
        #pragma unroll
        for (int j = 0; j < 6; ++j) acc[i][j] = 0.f;

    for (int kc = 0; kc < 15; ++kc) {
        #pragma unroll
        for (int i = 0; i < 4; ++i) {
            const int idx = tid + i * 256;
            const int row = idx >> 3, c4 = idx & 7;
            Xs[row * 9 + c4] = ((const float4*)X)[(size_t)(m0 + row) * 120 + kc * 8 + c4];
        }
        #pragma unroll
        for (int i = 0; i < 3; ++i) {
            const int idx = tid + i * 256;
            const int j = idx >> 3, c4 = idx & 7;
            const int k0 = kc * 32 + c4 * 4;
            float4 v;
            if (j < 64) {
                v.x = bnw[(k0+0)*64 + j]; v.y = bnw[(k0+1)*64 + j];
                v.z = bnw[(k0+2)*64 + j]; v.w = bnw[(k0+3)*64 + j];
            } else {
                const int jj = j - 64;
                v.x = gw[(k0+0)*32 + jj]; v.y = gw[(k0+1)*32 + jj];
                v.z = gw[(k0+2)*32 + jj]; v.w = gw[(k0+3)*32 + jj];
            }
            Wt[j * 9 + c4] = v;
        }
        __syncthreads();
        #pragma unroll 4
        for (int c4 = 0; c4 < 8; ++c4) {
            float4 xv[8], wvv[6];
            #pragma unroll
            for (int i = 0; i < 8; ++i) xv[i] = Xs[(ty + i * 16) * 9 + c4];
            #pragma unroll
            for (int j = 0; j < 6; ++j) wvv[j] = Wt[(tx + j * 16) * 9 + c4];
            #pragma unroll
            for (int i = 0; i < 8; ++i)
                #pragma unroll
                for (int j = 0; j < 6; ++j) {
                    acc[i][j] = fmaf(xv[i].x, wvv[j].x, acc[i][j]);
                    acc[i][j] = fmaf(xv[i].y, wvv[j].y, acc[i][j]);
                    acc[i][j] = fmaf(xv[i].z, wvv[j].z, acc[i][j]);
                    acc[i][j] = fmaf(xv[i].w, wvv[j].w, acc[i][j]);
                }
        }
        __syncthreads();
    }
    #pragma unroll
    for (int i = 0; i < 8; ++i) {
        const size_t row = (size_t)m0 + ty + i * 16;
        #pragma unroll
        for (int j = 0; j < 6; ++j) {
            const int col = tx + j * 16;
            if (col < 64) xa[row * 64 + col] = tanhf(acc[i][j] + bnb[col]);
            else          z[row * 32 + (col - 64)] = acc[i][j];
        }
    }
}

// ============================= fused tail v3 ================================
// xasf/S: [64 rows][17 f4], f4-index XOR-swizzled: idx = r*17 + (c4 ^ ((r>>2)&7))
// zT: [32 o-rows][17 f4] same swizzle; xbuf: [64][36] floats.
#define XF4(r, c4) ((r) * 17 + ((c4) ^ (((r) >> 2) & 7)))

__global__ __launch_bounds__(256, 3) void sogc_tail_kernel(
    const float* __restrict__ xa,   // (B,62,64)
    const float* __restrict__ z,    // (B,62,32)
    const float* __restrict__ gb1,
    const float* __restrict__ bnw2, const float* __restrict__ bnb2,
    const float* __restrict__ gw2,  const float* __restrict__ gb2,
    const float* __restrict__ bnw3, const float* __restrict__ bnb3,
    const float* __restrict__ gw3,  const float* __restrict__ gb3,
    const float* __restrict__ fcw,  const float* __restrict__ fcb,
    float* __restrict__ out)        // (B,3)
{
    __shared__ float4 xas4[64 * 17];          // 17408 B
    __shared__ float4 SW4[64 * 17];           // 17408 B: S  (union: stage weights)
    __shared__ float4 zT4[32 * 17];           //  8704 B
    __shared__ __align__(16) float xbuf[64 * 36];  // 9216 B
    __shared__ float degis[64];               // also reused as fc-reduction scratch
    const int b = blockIdx.x;
    const int tid = threadIdx.x;
    const int tx = tid & 15, ty = tid >> 4;
    const int n0 = ty * 4, m0 = tx * 4, o0 = tx * 2;
    float* zTf = (float*)zT4;
    float4* bnws4 = SW4;                       // [32][17] f4 (68-float rows)
    float* gwsf = (float*)(SW4 + 32 * 17);     // flat [32*32]

    // ---------------- P0: load xa -> xasf, z -> zT (transposed) -------------
    const float4* xag = (const float4*)(xa + (size_t)b * 3968);
    for (int idx = tid; idx < 992; idx += 256)
        xas4[XF4(idx >> 4, idx & 15)] = xag[idx];
    if (tid < 32) {   // zero rows 62,63
        const float4 z4 = {0.f, 0.f, 0.f, 0.f};
        xas4[XF4(62 + (tid >> 4), tid & 15)] = z4;
    }
    const float4* zg = (const float4*)(z + (size_t)b * 1984);
    for (int idx = tid; idx < 496; idx += 256) {
        const int n = idx >> 3, ob = (idx & 7) * 4;
        const float4 v = zg[idx];
        const int nh = n >> 2, nl = n & 3;
        zTf[((ob+0) * 17 + (nh ^ (((ob+0) >> 2) & 7))) * 4 + nl] = v.x;
        zTf[((ob+1) * 17 + (nh ^ (((ob+1) >> 2) & 7))) * 4 + nl] = v.y;
        zTf[((ob+2) * 17 + (nh ^ (((ob+2) >> 2) & 7))) * 4 + nl] = v.z;
        zTf[((ob+3) * 17 + (nh ^ (((ob+3) >> 2) & 7))) * 4 + nl] = v.w;
    }
    if (tid < 64) {   // zero zT cols 62,63
        const int o = tid >> 1, n = 62 + (tid & 1);
        zTf[(o * 17 + ((n >> 2) ^ ((o >> 2) & 7))) * 4 + (n & 3)] = 0.f;
    }
    // prefetch stage-2 weights into registers (written to LDS after stage 1)
    float4 wA0 = ((const float4*)bnw2)[tid];
    float4 wA1 = ((const float4*)bnw2)[tid + 256];
    float4 wG  = ((const float4*)gw2)[tid];
    __syncthreads();

    const float* gbs[3] = {gb1, gb2, gb3};

    #pragma unroll 1
    for (int st = 0; st < 3; ++st) {
        // ---------------- S = xa @ xa^T (4x4 per thread) --------------------
        float acc[4][4];
        #pragma unroll
        for (int i = 0; i < 4; ++i)
            #pragma unroll
            for (int j = 0; j < 4; ++j) acc[i][j] = 0.f;
        #pragma unroll 4
        for (int c4 = 0; c4 < 16; ++c4) {
            float4 xv[4], wv[4];
            #pragma unroll
            for (int i = 0; i < 4; ++i) xv[i] = xas4[XF4(n0 + i, c4)];
            #pragma unroll
            for (int j = 0; j < 4; ++j) wv[j] = xas4[XF4(m0 + j, c4)];
            #pragma unroll
            for (int i = 0; i < 4; ++i)
                #pragma unroll
                for (int j = 0; j < 4; ++j) {
                    acc[i][j] = fmaf(xv[i].x, wv[j].x, acc[i][j]);
                    acc[i][j] = fmaf(xv[i].y, wv[j].y, acc[i][j]);
                    acc[i][j] = fmaf(xv[i].z, wv[j].z, acc[i][j]);
                    acc[i][j] = fmaf(xv[i].w, wv[j].w, acc[i][j]);
                }
        }
        // ------------- register softmax + diag + degree (shfl over tx) ------
        float dri[4];
        #pragma unroll
        for (int i = 0; i < 4; ++i) {
            float mx = -1e30f;
            #pragma unroll
            for (int j = 0; j < 4; ++j)
                if (m0 + j < 62) mx = fmaxf(mx, acc[i][j]);
            mx = fmaxf(mx, __shfl_xor(mx, 1));
            mx = fmaxf(mx, __shfl_xor(mx, 2));
            mx = fmaxf(mx, __shfl_xor(mx, 4));
            mx = fmaxf(mx, __shfl_xor(mx, 8));
            float sum = 0.f;
            #pragma unroll
            for (int j = 0; j < 4; ++j) {
                const float e = (m0 + j < 62) ? __expf(acc[i][j] - mx) : 0.f;
                acc[i][j] = e; sum += e;
            }
            sum += __shfl_xor(sum, 1);
            sum += __shfl_xor(sum, 2);
            sum += __shfl_xor(sum, 4);
            sum += __shfl_xor(sum, 8);
            const float inv = 1.f / sum;
            #pragma unroll
            for (int j = 0; j < 4; ++j) acc[i][j] *= inv;
            if (tx == ty) acc[i][i] = 1.f;        // diag overwrite
            float dg = acc[i][0] + acc[i][1] + acc[i][2] + acc[i][3];
            dg += __shfl_xor(dg, 1);
            dg += __shfl_xor(dg, 2);
            dg += __shfl_xor(dg, 4);
            dg += __shfl_xor(dg, 8);
            dri[i] = rsqrtf(fmaxf(dg, 1.f));
            if (tx == 0) degis[n0 + i] = dri[i];
        }
        __syncthreads();
        // ------------- scale by col-deg, store adj to S (float4) ------------
        {
            const float dc0 = degis[m0], dc1 = degis[m0 + 1];
            const float dc2 = degis[m0 + 2], dc3 = degis[m0 + 3];
            #pragma unroll
            for (int i = 0; i < 4; ++i) {
                float4 t;
                t.x = acc[i][0] * dri[i] * dc0;
                t.y = acc[i][1] * dri[i] * dc1;
                t.z = acc[i][2] * dri[i] * dc2;
                t.w = acc[i][3] * dri[i] * dc3;
                SW4[XF4(n0 + i, tx)] = t;
            }
        }
        __syncthreads();
        // ---------------- out = adj @ z + gb  (all-float4 K loop) -----------
        {
            float az[4][2];
            #pragma unroll
            for (int i = 0; i < 4; ++i) { az[i][0] = 0.f; az[i][1] = 0.f; }
            const int g0 = (o0 >> 2) & 7, g1 = ((o0 + 1) >> 2) & 7;
            #pragma unroll 4
            for (int mc = 0; mc < 16; ++mc) {
                const float4 zA = zT4[o0 * 17 + (mc ^ g0)];
                const float4 zB = zT4[(o0 + 1) * 17 + (mc ^ g1)];
                #pragma unroll
                for (int i = 0; i < 4; ++i) {
                    const float4 sv = SW4[XF4(n0 + i, mc)];
                    az[i][0] = fmaf(sv.x, zA.x, az[i][0]);
                    az[i][0] = fmaf(sv.y, zA.y, az[i][0]);
                    az[i][0] = fmaf(sv.z, zA.z, az[i][0]);
                    az[i][0] = fmaf(sv.w, zA.w, az[i][0]);
                    az[i][1] = fmaf(sv.x, zB.x, az[i][1]);
                    az[i][1] = fmaf(sv.y, zB.y, az[i][1]);
                    az[i][1] = fmaf(sv.z, zB.z, az[i][1]);
                    az[i][1] = fmaf(sv.w, zB.w, az[i][1]);
                }
            }
            const float* gb = gbs[st];
            const float gbv0 = gb[o0], gbv1 = gb[o0 + 1];
            #pragma unroll
            for (int i = 0; i < 4; ++i) {
                const int n = n0 + i;
                if (n < 62) {
                    xbuf[n * 36 + o0]     = az[i][0] + gbv0;
                    xbuf[n * 36 + o0 + 1] = az[i][1] + gbv1;
                }
            }
        }
        __syncthreads();
        if (st == 2) break;

        // ------- install stage weights (S region now dead), prefetch next ---
        bnws4[(tid >> 4) * 17 + (tid & 15)] = wA0;
        bnws4[(16 + (tid >> 4)) * 17 + (tid & 15)] = wA1;
        ((float4*)gwsf)[tid] = wG;
        if (st == 0) {
            wA0 = ((const float4*)bnw3)[tid];
            wA1 = ((const float4*)bnw3)[tid + 256];
            wG  = ((const float4*)gw3)[tid];
        }
        const float* bnb = (st == 0) ? bnb2 : bnb3;
        const float4 bnbv = ((const float4*)bnb)[tx];
        __syncthreads();

        // -------- stage gemms: xa' = tanh(x@bnw+bnb), zT' = (x@gw)^T --------
        {
            float a4[4][4], a2[4][2];
            #pragma unroll
            for (int i = 0; i < 4; ++i) {
                #pragma unroll
                for (int j = 0; j < 4; ++j) a4[i][j] = 0.f;
                a2[i][0] = 0.f; a2[i][1] = 0.f;
            }
            #pragma unroll 4
            for (int k = 0; k < 32; ++k) {
                const float4 wv = bnws4[k * 17 + tx];
                const float wz0 = gwsf[k * 32 + o0];
                const float wz1 = gwsf[k * 32 + o0 + 1];
                #pragma unroll
                for (int i = 0; i < 4; ++i) {
                    const float xv = xbuf[(n0 + i) * 36 + k];
                    a4[i][0] = fmaf(xv, wv.x, a4[i][0]);
                    a4[i][1] = fmaf(xv, wv.y, a4[i][1]);
                    a4[i][2] = fmaf(xv, wv.z, a4[i][2]);
                    a4[i][3] = fmaf(xv, wv.w, a4[i][3]);
                    a2[i][0] = fmaf(xv, wz0, a2[i][0]);
                    a2[i][1] = fmaf(xv, wz1, a2[i][1]);
                }
            }
            const int g0 = (o0 >> 2) & 7, g1 = ((o0 + 1) >> 2) & 7;
            #pragma unroll
            for (int i = 0; i < 4; ++i) {
                const int r = n0 + i;
                float4 t;
                if (r < 62) {
                    t.x = tanhf(a4[i][0] + bnbv.x);
                    t.y = tanhf(a4[i][1] + bnbv.y);
                    t.z = tanhf(a4[i][2] + bnbv.z);
                    t.w = tanhf(a4[i][3] + bnbv.w);
                } else { t.x = t.y = t.z = t.w = 0.f; }
                xas4[XF4(r, tx)] = t;
                const float z0 = (r < 62) ? a2[i][0] : 0.f;
                const float z1 = (r < 62) ? a2[i][1] : 0.f;
                zTf[(o0 * 17 + ((r >> 2) ^ g0)) * 4 + (r & 3)] = z0;
                zTf[((o0 + 1) * 17 + ((r >> 2) ^ g1)) * 4 + (r & 3)] = z1;
            }
        }
        __syncthreads();
    }

    // ---------------------- maxpool3 + fc ----------------------------------
    float a0 = 0.f, a1 = 0.f, a2 = 0.f;
    for (int t = tid; t < 620; t += 256) {
        const int n = t / 10, tt = t % 10;
        const float* p3 = &xbuf[n * 36 + tt * 3];
        const float p = fmaxf(fmaxf(p3[0], p3[1]), p3[2]);
        a0 = fmaf(p, fcw[t * 3 + 0], a0);
        a1 = fmaf(p, fcw[t * 3 + 1], a1);
        a2 = fmaf(p, fcw[t * 3 + 2], a2);
    }
    #pragma unroll
    for (int off = 32; off; off >>= 1) {
        a0 += __shfl_down(a0, off);
        a1 += __shfl_down(a1, off);
        a2 += __shfl_down(a2, off);
    }
    float* red = degis;   // dead now
    const int wvi = tid >> 6, ln = tid & 63;
    if (ln == 0) { red[wvi * 3 + 0] = a0; red[wvi * 3 + 1] = a1; red[wvi * 3 + 2] = a2; }
    __syncthreads();
    if (tid == 0) {
        out[b * 3 + 0] = red[0] + red[3] + red[6] + red[9]  + fcb[0];
        out[b * 3 + 1] = red[1] + red[4] + red[7] + red[10] + fcb[1];
        out[b * 3 + 2] = red[2] + red[5] + red[8] + red[11] + fcb[2];
    }
}

// ============================== launcher ====================================
extern "C" void kernel_launch(void* const* d_in, const int* in_sizes, int n_in,
                              void* d_out, int out_size, void* d_ws, size_t ws_size,
                              hipStream_t stream) {
    const float* x     = (const float*)d_in[0];
    const float* convw = (const float*)d_in[1];
    const float* convb = (const float*)d_in[2];
    const float* bnw1  = (const float*)d_in[3];
    const float* bnb1  = (const float*)d_in[4];
    const float* gw1   = (const float*)d_in[5];
    const float* gb1   = (const float*)d_in[6];
    const float* bnw2  = (const float*)d_in[7];
    const float* bnb2  = (const float*)d_in[8];
    const float* gw2   = (const float*)d_in[9];
    const float* gb2   = (const float*)d_in[10];
    const float* bnw3  = (const float*)d_in[11];
    const float* bnb3  = (const float*)d_in[12];
    const float* gw3   = (const float*)d_in[13];
    const float* gb3   = (const float*)d_in[14];
    const float* fcw   = (const float*)d_in[15];
    const float* fcb   = (const float*)d_in[16];

    char* ws = (char*)d_ws;
    float* hp = (float*)(ws);                    // 121,927,680 B
    float* xa = (float*)(ws + 121927680);        // 16,252,928 B
    float* z  = (float*)(ws + 138180608);        //  8,126,464 B

    conv_pool_kernel<<<1024, 256, 0, stream>>>(x, convw, convb, hp);
    g1_kernel<<<496, 256, 0, stream>>>(hp, bnw1, bnb1, gw1, xa, z);
    sogc_tail_kernel<<<1024, 256, 0, stream>>>(xa, z, gb1,
                                               bnw2, bnb2, gw2, gb2,
                                               bnw3, bnb3, gw3, gb3,
                                               fcw, fcb, (float*)d_out);
}

// Round 4
// 182.601 us; speedup vs baseline: 1.8105x; 1.3886x over previous
//
#include <hip/hip_runtime.h>
#include <math.h>

// ---------------------------------------------------------------------------
// B=1024. Fully fused per-batch mega-kernel:
//   conv(32,1,5,5)+relu+maxpool4 (fp32 VALU) -> X (62x480) bf16 in LDS
//   G1: [xa|z] = X @ [bnw1|gw1] via mfma_16x16x32_bf16 (W prepacked hi+lo)
//   epilogue: tanh -> xas4 (swizzled LDS), z -> zT4 (transposed swizzled LDS)
//   tail: 3x SOGC (register softmax) -> maxpool3 -> fc   (R3-proven code)
// Weights prepacked once per launch into ws by prepack_kernel.
// ---------------------------------------------------------------------------

typedef short bf16x8 __attribute__((ext_vector_type(8)));
typedef float f32x4  __attribute__((ext_vector_type(4)));

__device__ __forceinline__ unsigned short f32_to_bf16_rne(float f) {
    unsigned int u = __builtin_bit_cast(unsigned int, f);
    u += 0x7fffu + ((u >> 16) & 1u);
    return (unsigned short)(u >> 16);
}
__device__ __forceinline__ float bf16_bits_to_f32(unsigned short h) {
    unsigned int u = ((unsigned int)h) << 16;
    return __builtin_bit_cast(float, u);
}

// ============ prepack W = [bnw1|gw1] (480x96) -> MFMA-order bf16 hi+lo ======
// layout: wp[part*46080 + (kc*4+q)*768 + col*8 + j],  k = kc*32 + q*8 + j
__global__ __launch_bounds__(256) void prepack_kernel(
    const float* __restrict__ bnw, const float* __restrict__ gw,
    unsigned short* __restrict__ wp)
{
    const int idx = blockIdx.x * 256 + threadIdx.x;   // 46080 = 480*96
    if (idx >= 46080) return;
    const int k = idx / 96, col = idx - (idx / 96) * 96;
    const float w = (col < 64) ? bnw[k * 64 + col] : gw[k * 32 + (col - 64)];
    const unsigned short hi = f32_to_bf16_rne(w);
    const unsigned short lo = f32_to_bf16_rne(w - bf16_bits_to_f32(hi));
    const int kc = k >> 5, kk = k & 31;
    const int q = kk >> 3, j = kk & 7;
    const int base = (kc * 4 + q) * 768 + col * 8 + j;
    wp[base] = hi;
    wp[46080 + base] = lo;
}

// ============================= mega kernel ==================================
// xasf/S: [64 rows][17 f4], XOR swizzle on f4 index
#define XF4(r, c4) ((r) * 17 + ((c4) ^ (((r) >> 2) & 7)))

__global__ __launch_bounds__(256, 2) void mega_kernel(
    const float* __restrict__ x,     // (B,66,64)
    const float* __restrict__ cw,    // (32,1,5,5)
    const float* __restrict__ cb,    // (32,)
    const unsigned short* __restrict__ wp,  // prepacked G1 weights hi+lo
    const float* __restrict__ bnb1,
    const float* __restrict__ gb1,
    const float* __restrict__ bnw2, const float* __restrict__ bnb2,
    const float* __restrict__ gw2,  const float* __restrict__ gb2,
    const float* __restrict__ bnw3, const float* __restrict__ bnb3,
    const float* __restrict__ gw3,  const float* __restrict__ gb3,
    const float* __restrict__ fcw,  const float* __restrict__ fcb,
    float* __restrict__ out)        // (B,3)
{
    // LDS union: [0,17952) xs | [17952,80416) X(64x488 bf16)
    // tail overlay (X dead): xas4@17952(17408) SW4@35360(17408) zT4@52768(8704)
    //                        xbuf@61472(9216) degis@70688(256)
    __shared__ __align__(16) char lds[80416];
    float4* xs4  = (float4*)lds;
    unsigned short* Xb = (unsigned short*)(lds + 17952);
    float4* xas4 = (float4*)(lds + 17952);
    float4* SW4  = (float4*)(lds + 35360);
    float4* zT4  = (float4*)(lds + 52768);
    float*  xbuf = (float*)(lds + 61472);
    float*  degis= (float*)(lds + 70688);
    float*  zTf  = (float*)zT4;
    float4* bnws4= SW4;                       // stage weights overlay
    float*  gwsf = (float*)(SW4 + 32 * 17);

    const int b = blockIdx.x;
    const int tid = threadIdx.x;
    const int wv = tid >> 6, ln = tid & 63;

    // ---------------- load x; zero X pad rows 62,63 -------------------------
    const float4* xg = (const float4*)(x + (size_t)b * 4224);
    for (int idx = tid; idx < 1056; idx += 256)
        xs4[(idx >> 4) * 17 + (idx & 15)] = xg[idx];
    {
        unsigned int* zp = (unsigned int*)(Xb + 62 * 488);
        if (tid < 244) { zp[tid] = 0u; zp[tid + 244] = 0u; }
    }
    __syncthreads();

    // ---------------- conv + relu + pool4 -> X bf16 (LDS) -------------------
    for (int it = 0; it < 4; ++it) {
        const int c0 = __builtin_amdgcn_readfirstlane((wv * 4 + it) * 2);
        float w0[25], w1[25];
        #pragma unroll
        for (int i = 0; i < 25; ++i) {
            w0[i] = cw[c0 * 25 + i];
            w1[i] = cw[c0 * 25 + 25 + i];
        }
        const float b0 = cb[c0], b1 = cb[c0 + 1];

        if (ln < 62) {
            const int r = ln;
            const int flat0 = c0 * 930 + r * 15;
            int na = flat0 / 480, fa = flat0 - (flat0 / 480) * 480;
            const int flat1 = flat0 + 930;
            int nb = flat1 / 480, fb = flat1 - (flat1 / 480) * 480;
            float Af[5][4], Bf[5][4];
            #pragma unroll
            for (int di = 0; di < 5; ++di) {
                float4 t = xs4[(r + di) * 17];
                Af[di][0] = t.x; Af[di][1] = t.y; Af[di][2] = t.z; Af[di][3] = t.w;
            }
            #pragma unroll
            for (int jp = 0; jp < 15; ++jp) {
                #pragma unroll
                for (int di = 0; di < 5; ++di) {
                    float4 t = xs4[(r + di) * 17 + jp + 1];
                    Bf[di][0] = t.x; Bf[di][1] = t.y; Bf[di][2] = t.z; Bf[di][3] = t.w;
                }
                float mm0 = -1e30f, mm1 = -1e30f;
                #pragma unroll
                for (int dj = 0; dj < 4; ++dj) {
                    float s0 = b0, s1 = b1;
                    #pragma unroll
                    for (int di = 0; di < 5; ++di) {
                        #pragma unroll
                        for (int k = 0; k < 5; ++k) {
                            const int col = dj + k;
                            const float v = (col < 4) ? Af[di][col] : Bf[di][col - 4];
                            s0 = fmaf(v, w0[di * 5 + k], s0);
                            s1 = fmaf(v, w1[di * 5 + k], s1);
                        }
                    }
                    mm0 = fmaxf(mm0, s0); mm1 = fmaxf(mm1, s1);
                }
                Xb[na * 488 + fa] = f32_to_bf16_rne(fmaxf(mm0, 0.f));
                Xb[nb * 488 + fb] = f32_to_bf16_rne(fmaxf(mm1, 0.f));
                if (++fa == 480) { fa = 0; ++na; }
                if (++fb == 480) { fb = 0; ++nb; }
                #pragma unroll
                for (int di = 0; di < 5; ++di) {
                    Af[di][0] = Bf[di][0]; Af[di][1] = Bf[di][1];
                    Af[di][2] = Bf[di][2]; Af[di][3] = Bf[di][3];
                }
            }
        }
    }
    __syncthreads();

    // ---------------- G1 MFMA: M=64 (wave=16 rows), N=96, K=480 -------------
    const int rt = ln & 15, q = ln >> 4;
    f32x4 acc[6];
    #pragma unroll
    for (int nt = 0; nt < 6; ++nt) acc[nt] = (f32x4){0.f, 0.f, 0.f, 0.f};
    {
        const unsigned short* Arow = Xb + (wv * 16 + rt) * 488 + q * 8;
        const unsigned short* WpB  = wp + q * 768 + rt * 8;
        for (int kc = 0; kc < 15; ++kc) {
            const bf16x8 a = *(const bf16x8*)(Arow + kc * 32);
            const unsigned short* pb = WpB + kc * 3072;
            #pragma unroll
            for (int nt = 0; nt < 6; ++nt) {
                const bf16x8 bh = *(const bf16x8*)(pb + nt * 128);
                const bf16x8 bl = *(const bf16x8*)(pb + nt * 128 + 46080);
                acc[nt] = __builtin_amdgcn_mfma_f32_16x16x32_bf16(a, bh, acc[nt], 0, 0, 0);
                acc[nt] = __builtin_amdgcn_mfma_f32_16x16x32_bf16(a, bl, acc[nt], 0, 0, 0);
            }
        }
    }
    __syncthreads();   // X now dead; tail buffers may be written

    // ---------------- epilogue: xa->xas4 (tanh), z->zT4 ---------------------
    {
        float bnbv[4];
        #pragma unroll
        for (int nt = 0; nt < 4; ++nt) bnbv[nt] = bnb1[nt * 16 + rt];
        const int rq = wv * 4 + q;          // row>>2 for this lane's C rows
        #pragma unroll
        for (int nt = 0; nt < 6; ++nt) {
            if (nt < 4) {
                const int col = nt * 16 + rt;
                const int c4 = col >> 2, cl = col & 3;
                #pragma unroll
                for (int j = 0; j < 4; ++j) {
                    const int r = rq * 4 + j;
                    const float v = (r < 62) ? tanhf(acc[nt][j] + bnbv[nt]) : 0.f;
                    ((float*)xas4)[XF4(r, c4) * 4 + cl] = v;
                }
            } else {
                const int o = (nt - 4) * 16 + rt;
                float4 t;
                t.x = (rq * 4 + 0 < 62) ? acc[nt][0] : 0.f;
                t.y = (rq * 4 + 1 < 62) ? acc[nt][1] : 0.f;
                t.z = (rq * 4 + 2 < 62) ? acc[nt][2] : 0.f;
                t.w = (rq * 4 + 3 < 62) ? acc[nt][3] : 0.f;
                zT4[o * 17 + (rq ^ ((o >> 2) & 7))] = t;
            }
        }
    }
    // prefetch stage-2 weights into registers
    float4 wA0 = ((const float4*)bnw2)[tid];
    float4 wA1 = ((const float4*)bnw2)[tid + 256];
    float4 wG  = ((const float4*)gw2)[tid];
    __syncthreads();

    // ---------------- tail: 3x SOGC (R3-proven) -----------------------------
    const int tx = tid & 15, ty = tid >> 4;
    const int n0 = ty * 4, m0 = tx * 4, o0 = tx * 2;
    const float* gbs[3] = {gb1, gb2, gb3};

    #pragma unroll 1
    for (int st = 0; st < 3; ++st) {
        // S = xa @ xa^T
        float sacc[4][4];
        #pragma unroll
        for (int i = 0; i < 4; ++i)
            #pragma unroll
            for (int j = 0; j < 4; ++j) sacc[i][j] = 0.f;
        #pragma unroll 4
        for (int c4 = 0; c4 < 16; ++c4) {
            float4 xv[4], wvv[4];
            #pragma unroll
            for (int i = 0; i < 4; ++i) xv[i] = xas4[XF4(n0 + i, c4)];
            #pragma unroll
            for (int j = 0; j < 4; ++j) wvv[j] = xas4[XF4(m0 + j, c4)];
            #pragma unroll
            for (int i = 0; i < 4; ++i)
                #pragma unroll
                for (int j = 0; j < 4; ++j) {
                    sacc[i][j] = fmaf(xv[i].x, wvv[j].x, sacc[i][j]);
                    sacc[i][j] = fmaf(xv[i].y, wvv[j].y, sacc[i][j]);
                    sacc[i][j] = fmaf(xv[i].z, wvv[j].z, sacc[i][j]);
                    sacc[i][j] = fmaf(xv[i].w, wvv[j].w, sacc[i][j]);
                }
        }
        // register softmax + diag + degree
        float dri[4];
        #pragma unroll
        for (int i = 0; i < 4; ++i) {
            float mx = -1e30f;
            #pragma unroll
            for (int j = 0; j < 4; ++j)
                if (m0 + j < 62) mx = fmaxf(mx, sacc[i][j]);
            mx = fmaxf(mx, __shfl_xor(mx, 1));
            mx = fmaxf(mx, __shfl_xor(mx, 2));
            mx = fmaxf(mx, __shfl_xor(mx, 4));
            mx = fmaxf(mx, __shfl_xor(mx, 8));
            float sum = 0.f;
            #pragma unroll
            for (int j = 0; j < 4; ++j) {
                const float e = (m0 + j < 62) ? __expf(sacc[i][j] - mx) : 0.f;
                sacc[i][j] = e; sum += e;
            }
            sum += __shfl_xor(sum, 1);
            sum += __shfl_xor(sum, 2);
            sum += __shfl_xor(sum, 4);
            sum += __shfl_xor(sum, 8);
            const float inv = 1.f / sum;
            #pragma unroll
            for (int j = 0; j < 4; ++j) sacc[i][j] *= inv;
            if (tx == ty) sacc[i][i] = 1.f;
            float dg = sacc[i][0] + sacc[i][1] + sacc[i][2] + sacc[i][3];
            dg += __shfl_xor(dg, 1);
            dg += __shfl_xor(dg, 2);
            dg += __shfl_xor(dg, 4);
            dg += __shfl_xor(dg, 8);
            dri[i] = rsqrtf(fmaxf(dg, 1.f));
            if (tx == 0) degis[n0 + i] = dri[i];
        }
        __syncthreads();
        {   // scale by col-deg, store adj
            const float dc0 = degis[m0], dc1 = degis[m0 + 1];
            const float dc2 = degis[m0 + 2], dc3 = degis[m0 + 3];
            #pragma unroll
            for (int i = 0; i < 4; ++i) {
                float4 t;
                t.x = sacc[i][0] * dri[i] * dc0;
                t.y = sacc[i][1] * dri[i] * dc1;
                t.z = sacc[i][2] * dri[i] * dc2;
                t.w = sacc[i][3] * dri[i] * dc3;
                SW4[XF4(n0 + i, tx)] = t;
            }
        }
        __syncthreads();
        {   // out = adj @ z + gb
            float az[4][2];
            #pragma unroll
            for (int i = 0; i < 4; ++i) { az[i][0] = 0.f; az[i][1] = 0.f; }
            const int g0 = (o0 >> 2) & 7, g1 = ((o0 + 1) >> 2) & 7;
            #pragma unroll 4
            for (int mc = 0; mc < 16; ++mc) {
                const float4 zA = zT4[o0 * 17 + (mc ^ g0)];
                const float4 zB = zT4[(o0 + 1) * 17 + (mc ^ g1)];
                #pragma unroll
                for (int i = 0; i < 4; ++i) {
                    const float4 sv = SW4[XF4(n0 + i, mc)];
                    az[i][0] = fmaf(sv.x, zA.x, az[i][0]);
                    az[i][0] = fmaf(sv.y, zA.y, az[i][0]);
                    az[i][0] = fmaf(sv.z, zA.z, az[i][0]);
                    az[i][0] = fmaf(sv.w, zA.w, az[i][0]);
                    az[i][1] = fmaf(sv.x, zB.x, az[i][1]);
                    az[i][1] = fmaf(sv.y, zB.y, az[i][1]);
                    az[i][1] = fmaf(sv.z, zB.z, az[i][1]);
                    az[i][1] = fmaf(sv.w, zB.w, az[i][1]);
                }
            }
            const float* gb = gbs[st];
            const float gbv0 = gb[o0], gbv1 = gb[o0 + 1];
            #pragma unroll
            for (int i = 0; i < 4; ++i) {
                const int n = n0 + i;
                if (n < 62) {
                    xbuf[n * 36 + o0]     = az[i][0] + gbv0;
                    xbuf[n * 36 + o0 + 1] = az[i][1] + gbv1;
                }
            }
        }
        __syncthreads();
        if (st == 2) break;

        // install stage weights (S region dead), prefetch next
        bnws4[(tid >> 4) * 17 + (tid & 15)] = wA0;
        bnws4[(16 + (tid >> 4)) * 17 + (tid & 15)] = wA1;
        ((float4*)gwsf)[tid] = wG;
        if (st == 0) {
            wA0 = ((const float4*)bnw3)[tid];
            wA1 = ((const float4*)bnw3)[tid + 256];
            wG  = ((const float4*)gw3)[tid];
        }
        const float* bnb = (st == 0) ? bnb2 : bnb3;
        const float4 bnbv = ((const float4*)bnb)[tx];
        __syncthreads();

        // stage gemms: xa' = tanh(x@bnw+bnb), zT' = (x@gw)^T
        {
            float a4[4][4], a2[4][2];
            #pragma unroll
            for (int i = 0; i < 4; ++i) {
                #pragma unroll
                for (int j = 0; j < 4; ++j) a4[i][j] = 0.f;
                a2[i][0] = 0.f; a2[i][1] = 0.f;
            }
            #pragma unroll 4
            for (int k = 0; k < 32; ++k) {
                const float4 wvv = bnws4[k * 17 + tx];
                const float wz0 = gwsf[k * 32 + o0];
                const float wz1 = gwsf[k * 32 + o0 + 1];
                #pragma unroll
                for (int i = 0; i < 4; ++i) {
                    const float xv = xbuf[(n0 + i) * 36 + k];
                    a4[i][0] = fmaf(xv, wvv.x, a4[i][0]);
                    a4[i][1] = fmaf(xv, wvv.y, a4[i][1]);
                    a4[i][2] = fmaf(xv, wvv.z, a4[i][2]);
                    a4[i][3] = fmaf(xv, wvv.w, a4[i][3]);
                    a2[i][0] = fmaf(xv, wz0, a2[i][0]);
                    a2[i][1] = fmaf(xv, wz1, a2[i][1]);
                }
            }
            const int g0 = (o0 >> 2) & 7, g1 = ((o0 + 1) >> 2) & 7;
            #pragma unroll
            for (int i = 0; i < 4; ++i) {
                const int r = n0 + i;
                float4 t;
                if (r < 62) {
                    t.x = tanhf(a4[i][0] + bnbv.x);
                    t.y = tanhf(a4[i][1] + bnbv.y);
                    t.z = tanhf(a4[i][2] + bnbv.z);
                    t.w = tanhf(a4[i][3] + bnbv.w);
                } else { t.x = t.y = t.z = t.w = 0.f; }
                xas4[XF4(r, tx)] = t;
                const float z0 = (r < 62) ? a2[i][0] : 0.f;
                const float z1 = (r < 62) ? a2[i][1] : 0.f;
                zTf[(o0 * 17 + ((r >> 2) ^ g0)) * 4 + (r & 3)] = z0;
                zTf[((o0 + 1) * 17 + ((r >> 2) ^ g1)) * 4 + (r & 3)] = z1;
            }
        }
        __syncthreads();
    }

    // ---------------- maxpool3 + fc -----------------------------------------
    float a0 = 0.f, a1 = 0.f, a2 = 0.f;
    for (int t = tid; t < 620; t += 256) {
        const int n = t / 10, tt = t % 10;
        const float* p3 = &xbuf[n * 36 + tt * 3];
        const float p = fmaxf(fmaxf(p3[0], p3[1]), p3[2]);
        a0 = fmaf(p, fcw[t * 3 + 0], a0);
        a1 = fmaf(p, fcw[t * 3 + 1], a1);
        a2 = fmaf(p, fcw[t * 3 + 2], a2);
    }
    #pragma unroll
    for (int off = 32; off; off >>= 1) {
        a0 += __shfl_down(a0, off);
        a1 += __shfl_down(a1, off);
        a2 += __shfl_down(a2, off);
    }
    float* red = degis;   // dead now
    if (ln == 0) { red[wv * 3 + 0] = a0; red[wv * 3 + 1] = a1; red[wv * 3 + 2] = a2; }
    __syncthreads();
    if (tid == 0) {
        out[b * 3 + 0] = red[0] + red[3] + red[6] + red[9]  + fcb[0];
        out[b * 3 + 1] = red[1] + red[4] + red[7] + red[10] + fcb[1];
        out[b * 3 + 2] = red[2] + red[5] + red[8] + red[11] + fcb[2];
    }
}

// ============================== launcher ====================================
extern "C" void kernel_launch(void* const* d_in, const int* in_sizes, int n_in,
                              void* d_out, int out_size, void* d_ws, size_t ws_size,
                              hipStream_t stream) {
    const float* x     = (const float*)d_in[0];
    const float* convw = (const float*)d_in[1];
    const float* convb = (const float*)d_in[2];
    const float* bnw1  = (const float*)d_in[3];
    const float* bnb1  = (const float*)d_in[4];
    const float* gw1   = (const float*)d_in[5];
    const float* gb1   = (const float*)d_in[6];
    const float* bnw2  = (const float*)d_in[7];
    const float* bnb2  = (const float*)d_in[8];
    const float* gw2   = (const float*)d_in[9];
    const float* gb2   = (const float*)d_in[10];
    const float* bnw3  = (const float*)d_in[11];
    const float* bnb3  = (const float*)d_in[12];
    const float* gw3   = (const float*)d_in[13];
    const float* gb3   = (const float*)d_in[14];
    const float* fcw   = (const float*)d_in[15];
    const float* fcb   = (const float*)d_in[16];

    unsigned short* wp = (unsigned short*)d_ws;   // 184,320 B

    prepack_kernel<<<180, 256, 0, stream>>>(bnw1, gw1, wp);
    mega_kernel<<<1024, 256, 0, stream>>>(x, convw, convb, wp, bnb1,
                                          gb1, bnw2, bnb2, gw2, gb2,
                                          bnw3, bnb3, gw3, gb3,
                                          fcw, fcb, (float*)d_out);
}

// Round 5
// 164.476 us; speedup vs baseline: 2.0100x; 1.1102x over previous
//
#include <hip/hip_runtime.h>
#include <math.h>

// ---------------------------------------------------------------------------
// B=1024. Fully fused per-batch mega-kernel, all-MFMA for conv + G1:
//   x -> bf16 LDS rows (stride 96, zero-padded cols 64..95)
//   conv 5x5 as MFMA: A=im2col patches (pos x K), B=prepacked weights (K x ch)
//     chunk0: k=di*8+kk (di 0..3, kk 5..7 zero in W); chunk1: di=4 (k=kk)
//     D rows = positions (4 consecutive per lane) -> in-register relu+maxpool4
//     -> X (62x480 node-major, bf16, stride 488) in LDS
//   G1: [xa|z] = X @ [bnw1|gw1] via mfma (W prepacked hi+lo)
//   tail: 3x SOGC (register softmax) -> maxpool3 -> fc   (R3/R4-proven)
// ---------------------------------------------------------------------------

typedef short bf16x8 __attribute__((ext_vector_type(8)));
typedef float f32x4  __attribute__((ext_vector_type(4)));

__device__ __forceinline__ unsigned short f32_to_bf16_rne(float f) {
    unsigned int u = __builtin_bit_cast(unsigned int, f);
    u += 0x7fffu + ((u >> 16) & 1u);
    return (unsigned short)(u >> 16);
}
__device__ __forceinline__ float bf16_bits_to_f32(unsigned short h) {
    unsigned int u = ((unsigned int)h) << 16;
    return __builtin_bit_cast(float, u);
}

// ===================== prepack: G1 W (hi+lo) + conv W =======================
// G1: wp[part*46080 + (kc*4+q)*768 + col*8 + j], k = kc*32+q*8+j
// conv: wcv = wp+92160; wcv[(c*2+t)*512 + l*8 + j]; lane l: n=l&15(ch-t*16),
//       q=l>>4; chunk c=0: k=q*8+j -> di=q,kk=j (j<5 else 0)
//       chunk c=1: di=4, valid q==0 && j<5 else 0
__global__ __launch_bounds__(256) void prepack_kernel(
    const float* __restrict__ bnw, const float* __restrict__ gw,
    const float* __restrict__ cw, unsigned short* __restrict__ wp)
{
    const int idx = blockIdx.x * 256 + threadIdx.x;
    if (idx < 46080) {
        const int k = idx / 96, col = idx - (idx / 96) * 96;
        const float w = (col < 64) ? bnw[k * 64 + col] : gw[k * 32 + (col - 64)];
        const unsigned short hi = f32_to_bf16_rne(w);
        const unsigned short lo = f32_to_bf16_rne(w - bf16_bits_to_f32(hi));
        const int kc = k >> 5, kk = k & 31;
        const int q = kk >> 3, j = kk & 7;
        const int base = (kc * 4 + q) * 768 + col * 8 + j;
        wp[base] = hi;
        wp[46080 + base] = lo;
    } else if (idx < 48128) {
        const int e = idx - 46080;
        const int c = e >> 10, t = (e >> 9) & 1, l = (e >> 3) & 63, j = e & 7;
        const int n = l & 15, q = l >> 4;
        const int ch = t * 16 + n;
        float w = 0.f;
        if (c == 0) { if (j < 5) w = cw[ch * 25 + q * 5 + j]; }
        else        { if (q == 0 && j < 5) w = cw[ch * 25 + 20 + j]; }
        wp[92160 + e] = f32_to_bf16_rne(w);
    }
}

// ============================= mega kernel ==================================
#define XF4(r, c4) ((r) * 17 + ((c4) ^ (((r) >> 2) & 7)))

__global__ __launch_bounds__(256, 2) void mega_kernel(
    const float* __restrict__ x,     // (B,66,64)
    const float* __restrict__ cb,    // (32,)
    const unsigned short* __restrict__ wp,
    const float* __restrict__ bnb1,
    const float* __restrict__ gb1,
    const float* __restrict__ bnw2, const float* __restrict__ bnb2,
    const float* __restrict__ gw2,  const float* __restrict__ gb2,
    const float* __restrict__ bnw3, const float* __restrict__ bnb3,
    const float* __restrict__ gw3,  const float* __restrict__ gb3,
    const float* __restrict__ fcw,  const float* __restrict__ fcb,
    float* __restrict__ out)        // (B,3)
{
    // LDS: xb16 [0,12672) | Xb [12672,75136)
    // tail overlay (xb/Xb dead after G1 MFMA): xas4@0(17408) SW4@17408(17408)
    //   zT4@34816(8704) xbuf@43520(9216) degis@52736(256)
    __shared__ __align__(16) char lds[75136];
    unsigned short* xb = (unsigned short*)lds;            // 66 x 96 bf16
    unsigned short* Xb = (unsigned short*)(lds + 12672);  // 64 x 488 bf16
    float4* xas4 = (float4*)lds;
    float4* SW4  = (float4*)(lds + 17408);
    float4* zT4  = (float4*)(lds + 34816);
    float*  xbuf = (float*)(lds + 43520);
    float*  degis= (float*)(lds + 52736);
    float*  zTf  = (float*)zT4;
    float4* bnws4= SW4;
    float*  gwsf = (float*)(SW4 + 32 * 17);

    const int b = blockIdx.x;
    const int tid = threadIdx.x;
    const int wv = tid >> 6, ln = tid & 63;

    // ---------------- phase A: x -> bf16 LDS; zero pads ---------------------
    const float4* xg = (const float4*)(x + (size_t)b * 4224);
    for (int idx = tid; idx < 1056; idx += 256) {
        const float4 v = xg[idx];
        const int row = idx >> 4, c4 = idx & 15;
        short4 s;
        s.x = (short)f32_to_bf16_rne(v.x);
        s.y = (short)f32_to_bf16_rne(v.y);
        s.z = (short)f32_to_bf16_rne(v.z);
        s.w = (short)f32_to_bf16_rne(v.w);
        *(short4*)(xb + row * 96 + c4 * 4) = s;
    }
    for (int idx = tid; idx < 1056; idx += 256) {       // zero cols 64..95
        const int row = idx >> 4, w = idx & 15;
        ((unsigned int*)(xb + row * 96 + 64))[w] = 0u;
    }
    {                                                    // zero Xb rows 62,63
        unsigned int* zp = (unsigned int*)(Xb + 62 * 488);
        if (tid < 244) { zp[tid] = 0u; zp[tid + 244] = 0u; }
    }
    __syncthreads();

    // ---------------- phase B: conv+relu+pool4 via MFMA ---------------------
    {
        const unsigned short* wcv = wp + 92160;
        const bf16x8 w00 = *(const bf16x8*)(wcv + ln * 8);          // c0, ch 0-15
        const bf16x8 w01 = *(const bf16x8*)(wcv + 512 + ln * 8);    // c0, ch16-31
        const bf16x8 w10 = *(const bf16x8*)(wcv + 1024 + ln * 8);   // c1, ch 0-15
        const bf16x8 w11 = *(const bf16x8*)(wcv + 1536 + ln * 8);   // c1, ch16-31
        const int m = ln & 15, q = ln >> 4;
        const float cb0 = cb[m], cb1 = cb[m + 16];

        for (int jj = 0; jj < 62; ++jj) {
            const int job = wv * 62 + jj;
            const int r = job >> 2, j0 = (job & 3) << 4;
            const unsigned short* x0 = xb + (r + q) * 96 + j0 + m;
            const unsigned short* x1 = xb + (r + 4) * 96 + j0 + m + q * 8;
            bf16x8 A0, A1;
            #pragma unroll
            for (int j = 0; j < 8; ++j) { A0[j] = (short)x0[j]; A1[j] = (short)x1[j]; }
            f32x4 a0 = {0.f, 0.f, 0.f, 0.f}, a1 = {0.f, 0.f, 0.f, 0.f};
            a0 = __builtin_amdgcn_mfma_f32_16x16x32_bf16(A0, w00, a0, 0, 0, 0);
            a0 = __builtin_amdgcn_mfma_f32_16x16x32_bf16(A1, w10, a0, 0, 0, 0);
            a1 = __builtin_amdgcn_mfma_f32_16x16x32_bf16(A0, w01, a1, 0, 0, 0);
            a1 = __builtin_amdgcn_mfma_f32_16x16x32_bf16(A1, w11, a1, 0, 0, 0);
            const int pj = (j0 >> 2) + q;      // pooled col; lane's 4 regs = group
            if (pj < 15) {
                float p0 = fmaxf(fmaxf(a0[0], a0[1]), fmaxf(a0[2], a0[3])) + cb0;
                float p1 = fmaxf(fmaxf(a1[0], a1[1]), fmaxf(a1[2], a1[3])) + cb1;
                p0 = fmaxf(p0, 0.f);
                p1 = fmaxf(p1, 0.f);
                const int flat0 = m * 930 + r * 15 + pj;           // ch = m
                const int flat1 = flat0 + 16 * 930;                // ch = m+16
                Xb[(flat0 / 480) * 488 + (flat0 % 480)] = f32_to_bf16_rne(p0);
                Xb[(flat1 / 480) * 488 + (flat1 % 480)] = f32_to_bf16_rne(p1);
            }
        }
    }
    __syncthreads();

    // ---------------- phase C: G1 MFMA M=64,N=96,K=480 ----------------------
    const int rt = ln & 15, q = ln >> 4;
    f32x4 acc[6];
    #pragma unroll
    for (int nt = 0; nt < 6; ++nt) acc[nt] = (f32x4){0.f, 0.f, 0.f, 0.f};
    {
        const unsigned short* Arow = Xb + (wv * 16 + rt) * 488 + q * 8;
        const unsigned short* WpB  = wp + q * 768 + rt * 8;
        for (int kc = 0; kc < 15; ++kc) {
            const bf16x8 a = *(const bf16x8*)(Arow + kc * 32);
            const unsigned short* pb = WpB + kc * 3072;
            #pragma unroll
            for (int nt = 0; nt < 6; ++nt) {
                const bf16x8 bh = *(const bf16x8*)(pb + nt * 128);
                const bf16x8 bl = *(const bf16x8*)(pb + nt * 128 + 46080);
                acc[nt] = __builtin_amdgcn_mfma_f32_16x16x32_bf16(a, bh, acc[nt], 0, 0, 0);
                acc[nt] = __builtin_amdgcn_mfma_f32_16x16x32_bf16(a, bl, acc[nt], 0, 0, 0);
            }
        }
    }
    __syncthreads();   // xb/Xb now dead; tail overlay may be written

    // ---------------- G1 epilogue: xa->xas4 (tanh), z->zT4 ------------------
    {
        float bnbv[4];
        #pragma unroll
        for (int nt = 0; nt < 4; ++nt) bnbv[nt] = bnb1[nt * 16 + rt];
        const int rq = wv * 4 + q;
        #pragma unroll
        for (int nt = 0; nt < 6; ++nt) {
            if (nt < 4) {
                const int col = nt * 16 + rt;
                const int c4 = col >> 2, cl = col & 3;
                #pragma unroll
                for (int j = 0; j < 4; ++j) {
                    const int r = rq * 4 + j;
                    const float v = (r < 62) ? tanhf(acc[nt][j] + bnbv[nt]) : 0.f;
                    ((float*)xas4)[XF4(r, c4) * 4 + cl] = v;
                }
            } else {
                const int o = (nt - 4) * 16 + rt;
                float4 t;
                t.x = (rq * 4 + 0 < 62) ? acc[nt][0] : 0.f;
                t.y = (rq * 4 + 1 < 62) ? acc[nt][1] : 0.f;
                t.z = (rq * 4 + 2 < 62) ? acc[nt][2] : 0.f;
                t.w = (rq * 4 + 3 < 62) ? acc[nt][3] : 0.f;
                zT4[o * 17 + (rq ^ ((o >> 2) & 7))] = t;
            }
        }
    }
    float4 wA0 = ((const float4*)bnw2)[tid];
    float4 wA1 = ((const float4*)bnw2)[tid + 256];
    float4 wG  = ((const float4*)gw2)[tid];
    __syncthreads();

    // ---------------- tail: 3x SOGC (register softmax) ----------------------
    const int tx = tid & 15, ty = tid >> 4;
    const int n0 = ty * 4, m0 = tx * 4, o0 = tx * 2;
    const float* gbs[3] = {gb1, gb2, gb3};

    #pragma unroll 1
    for (int st = 0; st < 3; ++st) {
        float sacc[4][4];
        #pragma unroll
        for (int i = 0; i < 4; ++i)
            #pragma unroll
            for (int j = 0; j < 4; ++j) sacc[i][j] = 0.f;
        #pragma unroll 4
        for (int c4 = 0; c4 < 16; ++c4) {
            float4 xv[4], wvv[4];
            #pragma unroll
            for (int i = 0; i < 4; ++i) xv[i] = xas4[XF4(n0 + i, c4)];
            #pragma unroll
            for (int j = 0; j < 4; ++j) wvv[j] = xas4[XF4(m0 + j, c4)];
            #pragma unroll
            for (int i = 0; i < 4; ++i)
                #pragma unroll
                for (int j = 0; j < 4; ++j) {
                    sacc[i][j] = fmaf(xv[i].x, wvv[j].x, sacc[i][j]);
                    sacc[i][j] = fmaf(xv[i].y, wvv[j].y, sacc[i][j]);
                    sacc[i][j] = fmaf(xv[i].z, wvv[j].z, sacc[i][j]);
                    sacc[i][j] = fmaf(xv[i].w, wvv[j].w, sacc[i][j]);
                }
        }
        float dri[4];
        #pragma unroll
        for (int i = 0; i < 4; ++i) {
            float mx = -1e30f;
            #pragma unroll
            for (int j = 0; j < 4; ++j)
                if (m0 + j < 62) mx = fmaxf(mx, sacc[i][j]);
            mx = fmaxf(mx, __shfl_xor(mx, 1));
            mx = fmaxf(mx, __shfl_xor(mx, 2));
            mx = fmaxf(mx, __shfl_xor(mx, 4));
            mx = fmaxf(mx, __shfl_xor(mx, 8));
            float sum = 0.f;
            #pragma unroll
            for (int j = 0; j < 4; ++j) {
                const float e = (m0 + j < 62) ? __expf(sacc[i][j] - mx) : 0.f;
                sacc[i][j] = e; sum += e;
            }
            sum += __shfl_xor(sum, 1);
            sum += __shfl_xor(sum, 2);
            sum += __shfl_xor(sum, 4);
            sum += __shfl_xor(sum, 8);
            const float inv = 1.f / sum;
            #pragma unroll
            for (int j = 0; j < 4; ++j) sacc[i][j] *= inv;
            if (tx == ty) sacc[i][i] = 1.f;
            float dg = sacc[i][0] + sacc[i][1] + sacc[i][2] + sacc[i][3];
            dg += __shfl_xor(dg, 1);
            dg += __shfl_xor(dg, 2);
            dg += __shfl_xor(dg, 4);
            dg += __shfl_xor(dg, 8);
            dri[i] = rsqrtf(fmaxf(dg, 1.f));
            if (tx == 0) degis[n0 + i] = dri[i];
        }
        __syncthreads();
        {
            const float dc0 = degis[m0], dc1 = degis[m0 + 1];
            const float dc2 = degis[m0 + 2], dc3 = degis[m0 + 3];
            #pragma unroll
            for (int i = 0; i < 4; ++i) {
                float4 t;
                t.x = sacc[i][0] * dri[i] * dc0;
                t.y = sacc[i][1] * dri[i] * dc1;
                t.z = sacc[i][2] * dri[i] * dc2;
                t.w = sacc[i][3] * dri[i] * dc3;
                SW4[XF4(n0 + i, tx)] = t;
            }
        }
        __syncthreads();
        {
            float az[4][2];
            #pragma unroll
            for (int i = 0; i < 4; ++i) { az[i][0] = 0.f; az[i][1] = 0.f; }
            const int g0 = (o0 >> 2) & 7, g1 = ((o0 + 1) >> 2) & 7;
            #pragma unroll 4
            for (int mc = 0; mc < 16; ++mc) {
                const float4 zA = zT4[o0 * 17 + (mc ^ g0)];
                const float4 zB = zT4[(o0 + 1) * 17 + (mc ^ g1)];
                #pragma unroll
                for (int i = 0; i < 4; ++i) {
                    const float4 sv = SW4[XF4(n0 + i, mc)];
                    az[i][0] = fmaf(sv.x, zA.x, az[i][0]);
                    az[i][0] = fmaf(sv.y, zA.y, az[i][0]);
                    az[i][0] = fmaf(sv.z, zA.z, az[i][0]);
                    az[i][0] = fmaf(sv.w, zA.w, az[i][0]);
                    az[i][1] = fmaf(sv.x, zB.x, az[i][1]);
                    az[i][1] = fmaf(sv.y, zB.y, az[i][1]);
                    az[i][1] = fmaf(sv.z, zB.z, az[i][1]);
                    az[i][1] = fmaf(sv.w, zB.w, az[i][1]);
                }
            }
            const float* gb = gbs[st];
            const float gbv0 = gb[o0], gbv1 = gb[o0 + 1];
            #pragma unroll
            for (int i = 0; i < 4; ++i) {
                const int n = n0 + i;
                if (n < 62) {
                    xbuf[n * 36 + o0]     = az[i][0] + gbv0;
                    xbuf[n * 36 + o0 + 1] = az[i][1] + gbv1;
                }
            }
        }
        __syncthreads();
        if (st == 2) break;

        bnws4[(tid >> 4) * 17 + (tid & 15)] = wA0;
        bnws4[(16 + (tid >> 4)) * 17 + (tid & 15)] = wA1;
        ((float4*)gwsf)[tid] = wG;
        if (st == 0) {
            wA0 = ((const float4*)bnw3)[tid];
            wA1 = ((const float4*)bnw3)[tid + 256];
            wG  = ((const float4*)gw3)[tid];
        }
        const float* bnb = (st == 0) ? bnb2 : bnb3;
        const float4 bnbv = ((const float4*)bnb)[tx];
        __syncthreads();

        {
            float a4[4][4], a2[4][2];
            #pragma unroll
            for (int i = 0; i < 4; ++i) {
                #pragma unroll
                for (int j = 0; j < 4; ++j) a4[i][j] = 0.f;
                a2[i][0] = 0.f; a2[i][1] = 0.f;
            }
            #pragma unroll 4
            for (int k = 0; k < 32; ++k) {
                const float4 wvv = bnws4[k * 17 + tx];
                const float wz0 = gwsf[k * 32 + o0];
                const float wz1 = gwsf[k * 32 + o0 + 1];
                #pragma unroll
                for (int i = 0; i < 4; ++i) {
                    const float xv = xbuf[(n0 + i) * 36 + k];
                    a4[i][0] = fmaf(xv, wvv.x, a4[i][0]);
                    a4[i][1] = fmaf(xv, wvv.y, a4[i][1]);
                    a4[i][2] = fmaf(xv, wvv.z, a4[i][2]);
                    a4[i][3] = fmaf(xv, wvv.w, a4[i][3]);
                    a2[i][0] = fmaf(xv, wz0, a2[i][0]);
                    a2[i][1] = fmaf(xv, wz1, a2[i][1]);
                }
            }
            const int g0 = (o0 >> 2) & 7, g1 = ((o0 + 1) >> 2) & 7;
            #pragma unroll
            for (int i = 0; i < 4; ++i) {
                const int r = n0 + i;
                float4 t;
                if (r < 62) {
                    t.x = tanhf(a4[i][0] + bnbv.x);
                    t.y = tanhf(a4[i][1] + bnbv.y);
                    t.z = tanhf(a4[i][2] + bnbv.z);
                    t.w = tanhf(a4[i][3] + bnbv.w);
                } else { t.x = t.y = t.z = t.w = 0.f; }
                xas4[XF4(r, tx)] = t;
                const float z0 = (r < 62) ? a2[i][0] : 0.f;
                const float z1 = (r < 62) ? a2[i][1] : 0.f;
                zTf[(o0 * 17 + ((r >> 2) ^ g0)) * 4 + (r & 3)] = z0;
                zTf[((o0 + 1) * 17 + ((r >> 2) ^ g1)) * 4 + (r & 3)] = z1;
            }
        }
        __syncthreads();
    }

    // ---------------- maxpool3 + fc -----------------------------------------
    float a0 = 0.f, a1 = 0.f, a2 = 0.f;
    for (int t = tid; t < 620; t += 256) {
        const int n = t / 10, tt = t % 10;
        const float* p3 = &xbuf[n * 36 + tt * 3];
        const float p = fmaxf(fmaxf(p3[0], p3[1]), p3[2]);
        a0 = fmaf(p, fcw[t * 3 + 0], a0);
        a1 = fmaf(p, fcw[t * 3 + 1], a1);
        a2 = fmaf(p, fcw[t * 3 + 2], a2);
    }
    #pragma unroll
    for (int off = 32; off; off >>= 1) {
        a0 += __shfl_down(a0, off);
        a1 += __shfl_down(a1, off);
        a2 += __shfl_down(a2, off);
    }
    float* red = degis;
    if (ln == 0) { red[wv * 3 + 0] = a0; red[wv * 3 + 1] = a1; red[wv * 3 + 2] = a2; }
    __syncthreads();
    if (tid == 0) {
        out[b * 3 + 0] = red[0] + red[3] + red[6] + red[9]  + fcb[0];
        out[b * 3 + 1] = red[1] + red[4] + red[7] + red[10] + fcb[1];
        out[b * 3 + 2] = red[2] + red[5] + red[8] + red[11] + fcb[2];
    }
}

// ============================== launcher ====================================
extern "C" void kernel_launch(void* const* d_in, const int* in_sizes, int n_in,
                              void* d_out, int out_size, void* d_ws, size_t ws_size,
                              hipStream_t stream) {
    const float* x     = (const float*)d_in[0];
    const float* convw = (const float*)d_in[1];
    const float* convb = (const float*)d_in[2];
    const float* bnw1  = (const float*)d_in[3];
    const float* bnb1  = (const float*)d_in[4];
    const float* gw1   = (const float*)d_in[5];
    const float* gb1   = (const float*)d_in[6];
    const float* bnw2  = (const float*)d_in[7];
    const float* bnb2  = (const float*)d_in[8];
    const float* gw2   = (const float*)d_in[9];
    const float* gb2   = (const float*)d_in[10];
    const float* bnw3  = (const float*)d_in[11];
    const float* bnb3  = (const float*)d_in[12];
    const float* gw3   = (const float*)d_in[13];
    const float* gb3   = (const float*)d_in[14];
    const float* fcw   = (const float*)d_in[15];
    const float* fcb   = (const float*)d_in[16];

    unsigned short* wp = (unsigned short*)d_ws;   // 94,208 u16 = 188,416 B used

    prepack_kernel<<<188, 256, 0, stream>>>(bnw1, gw1, convw, wp);
    mega_kernel<<<1024, 256, 0, stream>>>(x, convb, wp, bnb1,
                                          gb1, bnw2, bnb2, gw2, gb2,
                                          bnw3, bnb3, gw3, gb3,
                                          fcw, fcb, (float*)d_out);
}

// Round 6
// 121.052 us; speedup vs baseline: 2.7311x; 1.3587x over previous
//
#include <hip/hip_runtime.h>
#include <math.h>

// ---------------------------------------------------------------------------
// B=1024. R6: split pipeline, MFMA everywhere.
// prepack: G1 W hi+lo (MFMA B-frag order), conv W, stage2/3 W (B-frag bf16)
// kernel1 (75KB LDS, 2/CU): conv(MFMA)+pool -> X bf16 LDS; G1 MFMA with
//   per-kc LDS-staged weights; epilogue -> global images xaH/xaL/zB (bf16)
// kernel2 (37.6KB LDS, 4/CU): stage images -> 3x SOGC all-MFMA
//   (S=xa@xa^T bf16 hi+lo, fp32 register softmax/deg, adj bf16, adj@z MFMA,
//    stage gemms MFMA w/ global B-frag weights) -> pool3 -> fc
// ---------------------------------------------------------------------------

typedef short bf16x8 __attribute__((ext_vector_type(8)));
typedef float f32x4  __attribute__((ext_vector_type(4)));

__device__ __forceinline__ unsigned short f32_to_bf16_rne(float f) {
    unsigned int u = __builtin_bit_cast(unsigned int, f);
    u += 0x7fffu + ((u >> 16) & 1u);
    return (unsigned short)(u >> 16);
}
__device__ __forceinline__ float bf16_bits_to_f32(unsigned short h) {
    unsigned int u = ((unsigned int)h) << 16;
    return __builtin_bit_cast(float, u);
}
__device__ __forceinline__ float fast_tanh(float v) {
    v = fminf(fmaxf(v, -15.f), 15.f);
    const float ex = __expf(2.f * v);
    return (ex - 1.f) / (ex + 1.f);
}

// ws layout (u16 units):
//   [0, 92160)        G1 W hi (46080) + lo (46080)
//   [92160, 94208)    conv W frags
//   [94208, 100352)   stage2 (3072) + stage3 (3072) B-frag [col 96][k 32]
//   [102400, ...)     images: per block 11520 u16 = xaH[64*72] xaL[64*72] zB[32*72]
#define IMG_OFF 102400
#define IMG_SZ  11520

// ============================ prepack ======================================
__global__ __launch_bounds__(256) void prepack_kernel(
    const float* __restrict__ bnw1, const float* __restrict__ gw1,
    const float* __restrict__ cw,
    const float* __restrict__ bnw2, const float* __restrict__ gw2,
    const float* __restrict__ bnw3, const float* __restrict__ gw3,
    unsigned short* __restrict__ wp)
{
    const int idx = blockIdx.x * 256 + threadIdx.x;
    if (idx < 46080) {
        const int k = idx / 96, col = idx - (idx / 96) * 96;
        const float w = (col < 64) ? bnw1[k * 64 + col] : gw1[k * 32 + (col - 64)];
        const unsigned short hi = f32_to_bf16_rne(w);
        const unsigned short lo = f32_to_bf16_rne(w - bf16_bits_to_f32(hi));
        const int kc = k >> 5, kk = k & 31;
        const int q = kk >> 3, j = kk & 7;
        const int base = (kc * 4 + q) * 768 + col * 8 + j;
        wp[base] = hi;
        wp[46080 + base] = lo;
    } else if (idx < 48128) {
        const int e = idx - 46080;
        const int c = e >> 10, t = (e >> 9) & 1, l = (e >> 3) & 63, j = e & 7;
        const int n = l & 15, q = l >> 4;
        const int ch = t * 16 + n;
        float w = 0.f;
        if (c == 0) { if (j < 5) w = cw[ch * 25 + q * 5 + j]; }
        else        { if (q == 0 && j < 5) w = cw[ch * 25 + 20 + j]; }
        wp[92160 + e] = f32_to_bf16_rne(w);
    } else if (idx < 54272) {
        const int e2 = idx - 48128;
        const int s = e2 / 3072, r = e2 - s * 3072;
        const int col = r >> 5, k = r & 31;
        const float* bnw = s ? bnw3 : bnw2;
        const float* gw  = s ? gw3  : gw2;
        const float w = (col < 64) ? bnw[k * 64 + col] : gw[k * 32 + (col - 64)];
        wp[94208 + e2] = f32_to_bf16_rne(w);
    }
}

// ================= kernel1: conv(MFMA)+pool + G1(MFMA) ======================
__global__ __launch_bounds__(256, 2) void conv_g1_kernel(
    const float* __restrict__ x,     // (B,66,64)
    const float* __restrict__ cb,    // (32,)
    const unsigned short* __restrict__ wp,
    const float* __restrict__ bnb1,
    unsigned short* __restrict__ img)
{
    // LDS: xb [0,12672) 66x96 bf16 (G1 reuses [0,12288) as weight stage) |
    //      Xb [12672,75136) 64x488 bf16
    __shared__ __align__(16) char lds[75136];
    unsigned short* xb = (unsigned short*)lds;
    unsigned short* Xb = (unsigned short*)(lds + 12672);
    unsigned short* wLds = (unsigned short*)lds;     // 6144 u16, overlays xb

    const int b = blockIdx.x;
    const int tid = threadIdx.x;
    const int wv = tid >> 6, ln = tid & 63;

    // ---- phase A: x -> bf16 LDS; zero pads ----
    const float4* xg = (const float4*)(x + (size_t)b * 4224);
    for (int idx = tid; idx < 1056; idx += 256) {
        const float4 v = xg[idx];
        const int row = idx >> 4, c4 = idx & 15;
        short4 s;
        s.x = (short)f32_to_bf16_rne(v.x);
        s.y = (short)f32_to_bf16_rne(v.y);
        s.z = (short)f32_to_bf16_rne(v.z);
        s.w = (short)f32_to_bf16_rne(v.w);
        *(short4*)(xb + row * 96 + c4 * 4) = s;
    }
    for (int idx = tid; idx < 1056; idx += 256) {
        const int row = idx >> 4, w = idx & 15;
        ((unsigned int*)(xb + row * 96 + 64))[w] = 0u;
    }
    {
        unsigned int* zp = (unsigned int*)(Xb + 62 * 488);
        if (tid < 244) { zp[tid] = 0u; zp[tid + 244] = 0u; }
    }
    __syncthreads();

    // ---- phase B: conv+relu+pool4 via MFMA ----
    {
        const unsigned short* wcv = wp + 92160;
        const bf16x8 w00 = *(const bf16x8*)(wcv + ln * 8);
        const bf16x8 w01 = *(const bf16x8*)(wcv + 512 + ln * 8);
        const bf16x8 w10 = *(const bf16x8*)(wcv + 1024 + ln * 8);
        const bf16x8 w11 = *(const bf16x8*)(wcv + 1536 + ln * 8);
        const int m = ln & 15, q = ln >> 4;
        const float cb0 = cb[m], cb1 = cb[m + 16];

        for (int jj = 0; jj < 62; ++jj) {
            const int job = wv * 62 + jj;
            const int r = job >> 2, j0 = (job & 3) << 4;
            const unsigned short* x0 = xb + (r + q) * 96 + j0 + m;
            const unsigned short* x1 = xb + (r + 4) * 96 + j0 + m + q * 8;
            bf16x8 A0, A1;
            #pragma unroll
            for (int j = 0; j < 8; ++j) { A0[j] = (short)x0[j]; A1[j] = (short)x1[j]; }
            f32x4 a0 = {0.f, 0.f, 0.f, 0.f}, a1 = {0.f, 0.f, 0.f, 0.f};
            a0 = __builtin_amdgcn_mfma_f32_16x16x32_bf16(A0, w00, a0, 0, 0, 0);
            a0 = __builtin_amdgcn_mfma_f32_16x16x32_bf16(A1, w10, a0, 0, 0, 0);
            a1 = __builtin_amdgcn_mfma_f32_16x16x32_bf16(A0, w01, a1, 0, 0, 0);
            a1 = __builtin_amdgcn_mfma_f32_16x16x32_bf16(A1, w11, a1, 0, 0, 0);
            const int pj = (j0 >> 2) + q;
            if (pj < 15) {
                float p0 = fmaxf(fmaxf(a0[0], a0[1]), fmaxf(a0[2], a0[3])) + cb0;
                float p1 = fmaxf(fmaxf(a1[0], a1[1]), fmaxf(a1[2], a1[3])) + cb1;
                p0 = fmaxf(p0, 0.f);
                p1 = fmaxf(p1, 0.f);
                const int flat0 = m * 930 + r * 15 + pj;
                const int flat1 = flat0 + 16 * 930;
                Xb[(flat0 / 480) * 488 + (flat0 % 480)] = f32_to_bf16_rne(p0);
                Xb[(flat1 / 480) * 488 + (flat1 % 480)] = f32_to_bf16_rne(p1);
            }
        }
    }
    __syncthreads();

    // ---- phase C: G1 MFMA, weights LDS-staged per kc ----
    const int rt = ln & 15, q = ln >> 4;
    f32x4 acc[6];
    #pragma unroll
    for (int nt = 0; nt < 6; ++nt) acc[nt] = (f32x4){0.f, 0.f, 0.f, 0.f};
    {
        const unsigned short* Arow = Xb + (wv * 16 + rt) * 488 + q * 8;
        const float4* wpf = (const float4*)wp;
        for (int kc = 0; kc < 15; ++kc) {
            #pragma unroll
            for (int i = 0; i < 3; ++i) {
                const int idx = tid + i * 256;      // 0..767
                const int src = (idx < 384) ? (kc * 384 + idx)
                                            : (5760 + kc * 384 + (idx - 384));
                ((float4*)wLds)[idx] = wpf[src];
            }
            __syncthreads();
            const bf16x8 a = *(const bf16x8*)(Arow + kc * 32);
            #pragma unroll
            for (int nt = 0; nt < 6; ++nt) {
                const bf16x8 bh = *(const bf16x8*)(wLds + q * 768 + nt * 128 + rt * 8);
                const bf16x8 bl = *(const bf16x8*)(wLds + 3072 + q * 768 + nt * 128 + rt * 8);
                acc[nt] = __builtin_amdgcn_mfma_f32_16x16x32_bf16(a, bh, acc[nt], 0, 0, 0);
                acc[nt] = __builtin_amdgcn_mfma_f32_16x16x32_bf16(a, bl, acc[nt], 0, 0, 0);
            }
            __syncthreads();
        }
    }

    // ---- epilogue: tanh -> xaH/xaL images; z -> zB image (transposed) ----
    {
        unsigned short* gimg = img + (size_t)b * IMG_SZ;
        const int rq = wv * 4 + q;
        #pragma unroll
        for (int nt = 0; nt < 4; ++nt) {
            const float bb = bnb1[nt * 16 + rt];
            #pragma unroll
            for (int j = 0; j < 4; ++j) {
                const int r = rq * 4 + j;
                float th = fast_tanh(acc[nt][j] + bb);
                if (r >= 62) th = 0.f;
                const unsigned short h = f32_to_bf16_rne(th);
                const unsigned short l = f32_to_bf16_rne(th - bf16_bits_to_f32(h));
                gimg[r * 72 + nt * 16 + rt] = h;
                gimg[4608 + r * 72 + nt * 16 + rt] = l;
            }
        }
        #pragma unroll
        for (int nt = 4; nt < 6; ++nt) {
            const int o = (nt - 4) * 16 + rt;
            unsigned short zv[4];
            #pragma unroll
            for (int j = 0; j < 4; ++j) {
                const int r = rq * 4 + j;
                zv[j] = (r < 62) ? f32_to_bf16_rne(acc[nt][j]) : (unsigned short)0;
            }
            *(ushort4*)(gimg + 9216 + o * 72 + rq * 4) =
                make_ushort4(zv[0], zv[1], zv[2], zv[3]);
        }
    }
}

// ==================== kernel2: all-MFMA SOGC tail ==========================
__global__ __launch_bounds__(256, 4) void sogc_tail_kernel(
    const unsigned short* __restrict__ wp,   // stage weights + images
    const float* __restrict__ gb1, const float* __restrict__ gb2,
    const float* __restrict__ gb3,
    const float* __restrict__ bnb2, const float* __restrict__ bnb3,
    const float* __restrict__ fcw,  const float* __restrict__ fcb,
    float* __restrict__ out)        // (B,3)
{
    // LDS (u16 offsets): xaH 0 [64][72] | xaL 4608 | zB 9216 [32][72] |
    //                    P 11520 [64][72] | xB 16128 [64][40] | degis @37376B
    __shared__ __align__(16) char lds2[37632];
    unsigned short* xaH = (unsigned short*)lds2;
    unsigned short* xaL = xaH + 4608;
    unsigned short* zB  = xaH + 9216;
    unsigned short* P   = xaH + 11520;
    unsigned short* xB  = xaH + 16128;
    float* degis = (float*)(lds2 + 37376);

    const int b = blockIdx.x;
    const int tid = threadIdx.x;
    const int wv = tid >> 6, ln = tid & 63;
    const int c = ln & 15, q = ln >> 4;

    // ---- stage images into LDS (flat copy: xaH|xaL|zB = 1440 f4) ----
    {
        const float4* gi = (const float4*)(wp + IMG_OFF + (size_t)b * IMG_SZ);
        float4* dst = (float4*)lds2;
        #pragma unroll
        for (int i = 0; i < 6; ++i) {
            const int idx = tid + i * 256;
            if (idx < 1440) dst[idx] = gi[idx];
        }
    }
    __syncthreads();

    const unsigned short* wstg = wp + 94208;

    #pragma unroll 1
    for (int st = 0; st < 3; ++st) {
        // ---- S = xa @ xa^T (bf16 hi+lo, fp32 acc) ----
        f32x4 acc[4];
        #pragma unroll
        for (int t = 0; t < 4; ++t) acc[t] = (f32x4){0.f, 0.f, 0.f, 0.f};
        const int arow = (wv * 16 + c) * 72;
        #pragma unroll
        for (int kh = 0; kh < 2; ++kh) {
            const int ch = (kh * 4 + q) * 8;
            const bf16x8 AH = *(const bf16x8*)(xaH + arow + ch);
            const bf16x8 AL = *(const bf16x8*)(xaL + arow + ch);
            #pragma unroll
            for (int t = 0; t < 4; ++t) {
                const bf16x8 BH = *(const bf16x8*)(xaH + (t * 16 + c) * 72 + ch);
                const bf16x8 BL = *(const bf16x8*)(xaL + (t * 16 + c) * 72 + ch);
                acc[t] = __builtin_amdgcn_mfma_f32_16x16x32_bf16(AH, BH, acc[t], 0, 0, 0);
                acc[t] = __builtin_amdgcn_mfma_f32_16x16x32_bf16(AH, BL, acc[t], 0, 0, 0);
                acc[t] = __builtin_amdgcn_mfma_f32_16x16x32_bf16(AL, BH, acc[t], 0, 0, 0);
            }
        }
        // ---- fp32 register softmax + diag + degree (shfl over c) ----
        float e[4][4], dri[4];
        #pragma unroll
        for (int j = 0; j < 4; ++j) {
            const int n = wv * 16 + q * 4 + j;
            const float v0 = acc[0][j], v1 = acc[1][j];
            const float v2 = acc[2][j], v3 = acc[3][j];
            float mx = fmaxf(fmaxf(v0, v1), v2);
            if (c < 14) mx = fmaxf(mx, v3);
            mx = fmaxf(mx, __shfl_xor(mx, 1));
            mx = fmaxf(mx, __shfl_xor(mx, 2));
            mx = fmaxf(mx, __shfl_xor(mx, 4));
            mx = fmaxf(mx, __shfl_xor(mx, 8));
            float e0 = __expf(v0 - mx), e1 = __expf(v1 - mx), e2 = __expf(v2 - mx);
            float e3 = (c < 14) ? __expf(v3 - mx) : 0.f;
            float sum = e0 + e1 + e2 + e3;
            sum += __shfl_xor(sum, 1);
            sum += __shfl_xor(sum, 2);
            sum += __shfl_xor(sum, 4);
            sum += __shfl_xor(sum, 8);
            const float inv = 1.f / sum;
            e0 *= inv; e1 *= inv; e2 *= inv; e3 *= inv;
            if (n < 62 && c == (n & 15)) {
                const int dt = n >> 4;
                if (dt == 0) e0 = 1.f;
                else if (dt == 1) e1 = 1.f;
                else if (dt == 2) e2 = 1.f;
                else e3 = 1.f;
            }
            float dg = e0 + e1 + e2 + e3;
            dg += __shfl_xor(dg, 1);
            dg += __shfl_xor(dg, 2);
            dg += __shfl_xor(dg, 4);
            dg += __shfl_xor(dg, 8);
            const float d = rsqrtf(fmaxf(dg, 1.f));
            if (c == 0) degis[n] = d;
            dri[j] = d;
            e[j][0] = e0; e[j][1] = e1; e[j][2] = e2; e[j][3] = e3;
        }
        __syncthreads();
        // ---- P = D S D as bf16 ----
        {
            const float dm0 = degis[c],      dm1 = degis[16 + c];
            const float dm2 = degis[32 + c], dm3 = degis[48 + c];
            #pragma unroll
            for (int j = 0; j < 4; ++j) {
                const int n = wv * 16 + q * 4 + j;
                unsigned short* pr = P + n * 72 + c;
                if (n < 62) {
                    pr[0]  = f32_to_bf16_rne(e[j][0] * dri[j] * dm0);
                    pr[16] = f32_to_bf16_rne(e[j][1] * dri[j] * dm1);
                    pr[32] = f32_to_bf16_rne(e[j][2] * dri[j] * dm2);
                    pr[48] = f32_to_bf16_rne(e[j][3] * dri[j] * dm3);
                } else { pr[0] = 0; pr[16] = 0; pr[32] = 0; pr[48] = 0; }
            }
        }
        __syncthreads();
        // ---- O = P @ z + gb -> xB (bf16) ----
        {
            f32x4 oa0 = {0.f, 0.f, 0.f, 0.f}, oa1 = {0.f, 0.f, 0.f, 0.f};
            #pragma unroll
            for (int kh = 0; kh < 2; ++kh) {
                const int ch = (kh * 4 + q) * 8;
                const bf16x8 pa = *(const bf16x8*)(P + (wv * 16 + c) * 72 + ch);
                const bf16x8 z0 = *(const bf16x8*)(zB + c * 72 + ch);
                const bf16x8 z1 = *(const bf16x8*)(zB + (16 + c) * 72 + ch);
                oa0 = __builtin_amdgcn_mfma_f32_16x16x32_bf16(pa, z0, oa0, 0, 0, 0);
                oa1 = __builtin_amdgcn_mfma_f32_16x16x32_bf16(pa, z1, oa1, 0, 0, 0);
            }
            const float* gbp = (st == 0) ? gb1 : (st == 1) ? gb2 : gb3;
            const float g0 = gbp[c], g1 = gbp[16 + c];
            #pragma unroll
            for (int j = 0; j < 4; ++j) {
                const int n = wv * 16 + q * 4 + j;
                unsigned short* xr = xB + n * 40 + c;
                if (n < 62) {
                    xr[0]  = f32_to_bf16_rne(oa0[j] + g0);
                    xr[16] = f32_to_bf16_rne(oa1[j] + g1);
                } else { xr[0] = 0; xr[16] = 0; }
            }
        }
        __syncthreads();
        if (st == 2) break;

        // ---- stage gemms: xa' = tanh(x@bnw+bnb) (hi+lo), z' = x@gw ----
        {
            const unsigned short* wsB = wstg + st * 3072;
            const float* bnbp = (st == 0) ? bnb2 : bnb3;
            const bf16x8 ax = *(const bf16x8*)(xB + (wv * 16 + c) * 40 + q * 8);
            f32x4 sa[6];
            #pragma unroll
            for (int nt = 0; nt < 6; ++nt) {
                const bf16x8 wb = *(const bf16x8*)(wsB + (nt * 16 + c) * 32 + q * 8);
                f32x4 zz = {0.f, 0.f, 0.f, 0.f};
                sa[nt] = __builtin_amdgcn_mfma_f32_16x16x32_bf16(ax, wb, zz, 0, 0, 0);
            }
            #pragma unroll
            for (int nt = 0; nt < 4; ++nt) {
                const float bb = bnbp[nt * 16 + c];
                #pragma unroll
                for (int j = 0; j < 4; ++j) {
                    const int n = wv * 16 + q * 4 + j;
                    float th = fast_tanh(sa[nt][j] + bb);
                    if (n >= 62) th = 0.f;
                    const unsigned short h = f32_to_bf16_rne(th);
                    const unsigned short l = f32_to_bf16_rne(th - bf16_bits_to_f32(h));
                    xaH[n * 72 + nt * 16 + c] = h;
                    xaL[n * 72 + nt * 16 + c] = l;
                }
            }
            #pragma unroll
            for (int nt = 4; nt < 6; ++nt) {
                const int o = (nt - 4) * 16 + c;
                unsigned short zv[4];
                #pragma unroll
                for (int j = 0; j < 4; ++j) {
                    const int n = wv * 16 + q * 4 + j;
                    zv[j] = (n < 62) ? f32_to_bf16_rne(sa[nt][j]) : (unsigned short)0;
                }
                *(ushort4*)(zB + o * 72 + wv * 16 + q * 4) =
                    make_ushort4(zv[0], zv[1], zv[2], zv[3]);
            }
        }
        __syncthreads();
    }

    // ---- maxpool3 + fc ----
    float a0 = 0.f, a1 = 0.f, a2 = 0.f;
    for (int t = tid; t < 620; t += 256) {
        const int n = t / 10, tt = t - (t / 10) * 10;
        const unsigned short* pr = xB + n * 40 + tt * 3;
        const float p = fmaxf(fmaxf(bf16_bits_to_f32(pr[0]), bf16_bits_to_f32(pr[1])),
                              bf16_bits_to_f32(pr[2]));
        const float* fw = fcw + t * 3;
        a0 = fmaf(p, fw[0], a0);
        a1 = fmaf(p, fw[1], a1);
        a2 = fmaf(p, fw[2], a2);
    }
    #pragma unroll
    for (int off = 32; off; off >>= 1) {
        a0 += __shfl_down(a0, off);
        a1 += __shfl_down(a1, off);
        a2 += __shfl_down(a2, off);
    }
    float* red = degis;   // dead now
    if (ln == 0) { red[wv * 3 + 0] = a0; red[wv * 3 + 1] = a1; red[wv * 3 + 2] = a2; }
    __syncthreads();
    if (tid == 0) {
        out[b * 3 + 0] = red[0] + red[3] + red[6] + red[9]  + fcb[0];
        out[b * 3 + 1] = red[1] + red[4] + red[7] + red[10] + fcb[1];
        out[b * 3 + 2] = red[2] + red[5] + red[8] + red[11] + fcb[2];
    }
}

// ============================== launcher ====================================
extern "C" void kernel_launch(void* const* d_in, const int* in_sizes, int n_in,
                              void* d_out, int out_size, void* d_ws, size_t ws_size,
                              hipStream_t stream) {
    const float* x     = (const float*)d_in[0];
    const float* convw = (const float*)d_in[1];
    const float* convb = (const float*)d_in[2];
    const float* bnw1  = (const float*)d_in[3];
    const float* bnb1  = (const float*)d_in[4];
    const float* gw1   = (const float*)d_in[5];
    const float* gb1   = (const float*)d_in[6];
    const float* bnw2  = (const float*)d_in[7];
    const float* bnb2  = (const float*)d_in[8];
    const float* gw2   = (const float*)d_in[9];
    const float* gb2   = (const float*)d_in[10];
    const float* bnw3  = (const float*)d_in[11];
    const float* bnb3  = (const float*)d_in[12];
    const float* gw3   = (const float*)d_in[13];
    const float* gb3   = (const float*)d_in[14];
    const float* fcw   = (const float*)d_in[15];
    const float* fcb   = (const float*)d_in[16];

    unsigned short* wp  = (unsigned short*)d_ws;
    unsigned short* img = wp + IMG_OFF;

    prepack_kernel<<<212, 256, 0, stream>>>(bnw1, gw1, convw, bnw2, gw2,
                                            bnw3, gw3, wp);
    conv_g1_kernel<<<1024, 256, 0, stream>>>(x, convb, wp, bnb1, img);
    sogc_tail_kernel<<<1024, 256, 0, stream>>>(wp, gb1, gb2, gb3,
                                               bnb2, bnb3, fcw, fcb,
                                               (float*)d_out);
}

// Round 8
// 99.279 us; speedup vs baseline: 3.3300x; 1.2193x over previous
//
#include <hip/hip_runtime.h>
#include <math.h>

// ---------------------------------------------------------------------------
// B=1024. R8 = R7 with the node/feature mapping fixed + G1 hi/lo restored.
//   reshape fact: node n = (c*62+r)/32, feature f = ((c*62+r)%32)*15 + j
//   G1 K-order permuted: k' = pj*32 + s  (s = (c*62+r)%32; W prepacked match)
//   conv via mfma_32x32x16 (32 pos x 32 ch), 3 K-chunks
//   per pjg: conv 4 pooled cols -> Xcol[64][128] (XOR-swizzled) -> G1 kc=pj
//   G1 B-frags from global (L2-hot), bf16 hi+lo pair
// kernel2 (tail): unchanged R6 all-MFMA SOGC.
// ---------------------------------------------------------------------------

typedef short bf16x8 __attribute__((ext_vector_type(8)));
typedef float f32x4  __attribute__((ext_vector_type(4)));
typedef float f32x16 __attribute__((ext_vector_type(16)));

__device__ __forceinline__ unsigned short f32_to_bf16_rne(float f) {
    unsigned int u = __builtin_bit_cast(unsigned int, f);
    u += 0x7fffu + ((u >> 16) & 1u);
    return (unsigned short)(u >> 16);
}
__device__ __forceinline__ float bf16_bits_to_f32(unsigned short h) {
    unsigned int u = ((unsigned int)h) << 16;
    return __builtin_bit_cast(float, u);
}
__device__ __forceinline__ float fast_tanh(float v) {
    v = fminf(fmaxf(v, -15.f), 15.f);
    const float ex = __expf(2.f * v);
    return (ex - 1.f) / (ex + 1.f);
}

// ws layout (u16 units):
//   [0, 46080)        G1 W hi (B-frag order, K-permuted k'=pj*32+s)
//   [46080, 92160)    G1 W lo
//   [92160, 93696)    conv W frags (32x32 shape, 3 chunks)
//   [94208, 100352)   stage2 (3072) + stage3 (3072) B-frag [col 96][k 32]
//   [102400, ...)     images: per block 11520 u16 = xaH[64*72] xaL[64*72] zB[32*72]
#define IMG_OFF 102400
#define IMG_SZ  11520

// ============================ prepack ======================================
__global__ __launch_bounds__(256) void prepack_kernel(
    const float* __restrict__ bnw1, const float* __restrict__ gw1,
    const float* __restrict__ cw,
    const float* __restrict__ bnw2, const float* __restrict__ gw2,
    const float* __restrict__ bnw3, const float* __restrict__ gw3,
    unsigned short* __restrict__ wp)
{
    const int idx = blockIdx.x * 256 + threadIdx.x;
    if (idx < 46080) {
        // B[k' = kc*32 + q*8 + j][col];  k' = pj*32+s -> orig k = s*15 + pj
        const int kc = idx / 3072, r = idx - kc * 3072;
        const int q = r / 768, r2 = r - q * 768;
        const int col = r2 >> 3, j = r2 & 7;
        const int s = q * 8 + j;
        const int ko = s * 15 + kc;
        const float w = (col < 64) ? bnw1[ko * 64 + col] : gw1[ko * 32 + (col - 64)];
        const unsigned short hi = f32_to_bf16_rne(w);
        const unsigned short lo = f32_to_bf16_rne(w - bf16_bits_to_f32(hi));
        wp[idx] = hi;
        wp[46080 + idx] = lo;
    } else if (idx < 47616) {
        // conv W 32x32: chunk c, lane l: ch=l&31, dio=l>>5; di = 2c+dio (c<2), 4+dio
        const int e = idx - 46080;
        const int c = e >> 9, l = (e >> 3) & 63, j = e & 7;
        const int ch = l & 31, dio = l >> 5;
        const int di = (c < 2) ? (2 * c + dio) : (4 + dio);
        const float w = (j < 5 && di < 5) ? cw[ch * 25 + di * 5 + j] : 0.f;
        wp[92160 + e] = f32_to_bf16_rne(w);
    } else if (idx < 53760) {
        const int e2 = idx - 47616;
        const int s = e2 / 3072, r = e2 - s * 3072;
        const int col = r >> 5, k = r & 31;
        const float* bnw = s ? bnw3 : bnw2;
        const float* gw  = s ? gw3  : gw2;
        const float w = (col < 64) ? bnw[k * 64 + col] : gw[k * 32 + (col - 64)];
        wp[94208 + e2] = f32_to_bf16_rne(w);
    }
}

// ================= kernel1: fused conv(MFMA 32x32) + G1 ====================
__global__ __launch_bounds__(256, 4) void conv_g1_kernel(
    const float* __restrict__ x,     // (B,66,64)
    const float* __restrict__ cb,    // (32,)
    const unsigned short* __restrict__ wp,
    const float* __restrict__ bnb1,
    unsigned short* __restrict__ img)
{
    // LDS: xb [68][96] bf16 = 13056 B | Xcol [64][128] u16 swizzled = 16384 B
    __shared__ __align__(16) char lds[29440];
    unsigned short* xb   = (unsigned short*)lds;
    unsigned short* Xcol = (unsigned short*)(lds + 13056);

    const int b = blockIdx.x;
    const int tid = threadIdx.x;
    const int wv = tid >> 6, ln = tid & 63;

    // ---- phase A: x -> bf16 LDS; zero pads ----
    const float4* xg = (const float4*)(x + (size_t)b * 4224);
    for (int idx = tid; idx < 1056; idx += 256) {
        const float4 v = xg[idx];
        const int row = idx >> 4, c4 = idx & 15;
        short4 s;
        s.x = (short)f32_to_bf16_rne(v.x);
        s.y = (short)f32_to_bf16_rne(v.y);
        s.z = (short)f32_to_bf16_rne(v.z);
        s.w = (short)f32_to_bf16_rne(v.w);
        *(short4*)(xb + row * 96 + c4 * 4) = s;
    }
    for (int idx = tid; idx < 544; idx += 256) {        // cols 64..95 zero, all 68 rows
        const int row = idx >> 3, w = idx & 7;
        ((unsigned int*)(xb + row * 96 + 64))[w] = 0u;
    }
    if (tid < 128) {                                    // rows 66,67 cols 0..63 zero
        const int row = 66 + (tid >> 5), w = tid & 31;
        ((unsigned int*)(xb + row * 96))[w] = 0u;
    }
    if (tid < 64)                                       // Xcol rows 62,63 zero
        ((unsigned int*)(Xcol + 62 * 128))[tid] = 0u;
    __syncthreads();

    // conv lane roles (32x32): ch = l&31, hi = l>>5; A: m=l&15, rp=(l>>4)&1, dio=l>>5
    const int m = ln & 15, rp = (ln >> 4) & 1, dio = ln >> 5;
    const int ch = ln & 31, hi = ln >> 5;
    bf16x8 Wc[3];
    #pragma unroll
    for (int c = 0; c < 3; ++c)
        Wc[c] = *(const bf16x8*)(wp + 92160 + c * 512 + ln * 8);
    const float cbv = cb[ch];

    // G1 lane roles (16x16): rt = l&15, q = l>>4
    const int rt = ln & 15, q = ln >> 4;
    f32x4 acc[6];
    #pragma unroll
    for (int nt = 0; nt < 6; ++nt) acc[nt] = (f32x4){0.f, 0.f, 0.f, 0.f};

    for (int pjg = 0; pjg < 4; ++pjg) {
        const int j0 = pjg * 16;
        // ---- conv: 31 row-pairs, pooled cols pjg*4 + {0..3} -> Xcol ----
        for (int p = wv; p < 31; p += 4) {
            const int r0 = 2 * p;
            const unsigned short* base = xb + (r0 + rp + dio) * 96 + j0 + m;
            f32x16 a32;
            #pragma unroll
            for (int i = 0; i < 16; ++i) a32[i] = 0.f;
            #pragma unroll
            for (int c = 0; c < 3; ++c) {
                bf16x8 A;
                A[0] = (short)base[c * 192 + 0];
                A[1] = (short)base[c * 192 + 1];
                A[2] = (short)base[c * 192 + 2];
                A[3] = (short)base[c * 192 + 3];
                A[4] = (short)base[c * 192 + 4];
                A[5] = A[0]; A[6] = A[1]; A[7] = A[2];   // kk>=5: W=0, any finite val
                a32 = __builtin_amdgcn_mfma_f32_32x32x16_bf16(A, Wc[c], a32, 0, 0, 0);
            }
            // D: col=lane&31(ch), row a=4t+rr (t=2i+hi); regs 4i..4i+3 = pool group
            #pragma unroll
            for (int i = 0; i < 4; ++i) {
                const int t = 2 * i + hi;
                const int rpo = t >> 2, g = t & 3;
                float v = fmaxf(fmaxf(a32[4 * i], a32[4 * i + 1]),
                                fmaxf(a32[4 * i + 2], a32[4 * i + 3])) + cbv;
                v = fmaxf(v, 0.f);
                if (!(pjg == 3 && g == 3)) {
                    const int row = r0 + rpo;
                    const int tt = ch * 62 + row;        // reshape: n=tt/32, s=tt%32
                    const int n = tt >> 5, sf = tt & 31;
                    Xcol[n * 128 + ((g * 32 + sf) ^ ((n & 7) << 3))] =
                        f32_to_bf16_rne(v);
                }
            }
        }
        __syncthreads();
        // ---- G1: kc = pjg*4 + g; A from Xcol (aligned b128), B hi+lo global ----
        const int nk = (pjg < 3) ? 4 : 3;
        for (int g = 0; g < nk; ++g) {
            const int kc = pjg * 4 + g;
            const int row = wv * 16 + rt;
            const bf16x8 A = *(const bf16x8*)(
                Xcol + row * 128 + (((g * 4 + q) ^ (row & 7)) << 3));
            #pragma unroll
            for (int nt = 0; nt < 6; ++nt) {
                const bf16x8 Bh = *(const bf16x8*)(
                    wp + kc * 3072 + q * 768 + nt * 128 + rt * 8);
                const bf16x8 Bl = *(const bf16x8*)(
                    wp + 46080 + kc * 3072 + q * 768 + nt * 128 + rt * 8);
                acc[nt] = __builtin_amdgcn_mfma_f32_16x16x32_bf16(A, Bh, acc[nt], 0, 0, 0);
                acc[nt] = __builtin_amdgcn_mfma_f32_16x16x32_bf16(A, Bl, acc[nt], 0, 0, 0);
            }
        }
        __syncthreads();
    }

    // ---- epilogue: tanh -> xaH/xaL images; z -> zB image (transposed) ----
    {
        unsigned short* gimg = img + (size_t)b * IMG_SZ;
        const int rq = wv * 4 + q;
        #pragma unroll
        for (int nt = 0; nt < 4; ++nt) {
            const float bb = bnb1[nt * 16 + rt];
            #pragma unroll
            for (int j = 0; j < 4; ++j) {
                const int r = rq * 4 + j;
                float th = fast_tanh(acc[nt][j] + bb);
                if (r >= 62) th = 0.f;
                const unsigned short h = f32_to_bf16_rne(th);
                const unsigned short l = f32_to_bf16_rne(th - bf16_bits_to_f32(h));
                gimg[r * 72 + nt * 16 + rt] = h;
                gimg[4608 + r * 72 + nt * 16 + rt] = l;
            }
        }
        #pragma unroll
        for (int nt = 4; nt < 6; ++nt) {
            const int o = (nt - 4) * 16 + rt;
            unsigned short zv[4];
            #pragma unroll
            for (int j = 0; j < 4; ++j) {
                const int r = rq * 4 + j;
                zv[j] = (r < 62) ? f32_to_bf16_rne(acc[nt][j]) : (unsigned short)0;
            }
            *(ushort4*)(gimg + 9216 + o * 72 + rq * 4) =
                make_ushort4(zv[0], zv[1], zv[2], zv[3]);
        }
    }
}

// ==================== kernel2: all-MFMA SOGC tail (R6) =====================
__global__ __launch_bounds__(256, 4) void sogc_tail_kernel(
    const unsigned short* __restrict__ wp,
    const float* __restrict__ gb1, const float* __restrict__ gb2,
    const float* __restrict__ gb3,
    const float* __restrict__ bnb2, const float* __restrict__ bnb3,
    const float* __restrict__ fcw,  const float* __restrict__ fcb,
    float* __restrict__ out)        // (B,3)
{
    __shared__ __align__(16) char lds2[37632];
    unsigned short* xaH = (unsigned short*)lds2;
    unsigned short* xaL = xaH + 4608;
    unsigned short* zB  = xaH + 9216;
    unsigned short* P   = xaH + 11520;
    unsigned short* xB  = xaH + 16128;
    float* degis = (float*)(lds2 + 37376);

    const int b = blockIdx.x;
    const int tid = threadIdx.x;
    const int wv = tid >> 6, ln = tid & 63;
    const int c = ln & 15, q = ln >> 4;

    {
        const float4* gi = (const float4*)(wp + IMG_OFF + (size_t)b * IMG_SZ);
        float4* dst = (float4*)lds2;
        #pragma unroll
        for (int i = 0; i < 6; ++i) {
            const int idx = tid + i * 256;
            if (idx < 1440) dst[idx] = gi[idx];
        }
    }
    __syncthreads();

    const unsigned short* wstg = wp + 94208;

    #pragma unroll 1
    for (int st = 0; st < 3; ++st) {
        f32x4 acc[4];
        #pragma unroll
        for (int t = 0; t < 4; ++t) acc[t] = (f32x4){0.f, 0.f, 0.f, 0.f};
        const int arow = (wv * 16 + c) * 72;
        #pragma unroll
        for (int kh = 0; kh < 2; ++kh) {
            const int chh = (kh * 4 + q) * 8;
            const bf16x8 AH = *(const bf16x8*)(xaH + arow + chh);
            const bf16x8 AL = *(const bf16x8*)(xaL + arow + chh);
            #pragma unroll
            for (int t = 0; t < 4; ++t) {
                const bf16x8 BH = *(const bf16x8*)(xaH + (t * 16 + c) * 72 + chh);
                const bf16x8 BL = *(const bf16x8*)(xaL + (t * 16 + c) * 72 + chh);
                acc[t] = __builtin_amdgcn_mfma_f32_16x16x32_bf16(AH, BH, acc[t], 0, 0, 0);
                acc[t] = __builtin_amdgcn_mfma_f32_16x16x32_bf16(AH, BL, acc[t], 0, 0, 0);
                acc[t] = __builtin_amdgcn_mfma_f32_16x16x32_bf16(AL, BH, acc[t], 0, 0, 0);
            }
        }
        float e[4][4], dri[4];
        #pragma unroll
        for (int j = 0; j < 4; ++j) {
            const int n = wv * 16 + q * 4 + j;
            const float v0 = acc[0][j], v1 = acc[1][j];
            const float v2 = acc[2][j], v3 = acc[3][j];
            float mx = fmaxf(fmaxf(v0, v1), v2);
            if (c < 14) mx = fmaxf(mx, v3);
            mx = fmaxf(mx, __shfl_xor(mx, 1));
            mx = fmaxf(mx, __shfl_xor(mx, 2));
            mx = fmaxf(mx, __shfl_xor(mx, 4));
            mx = fmaxf(mx, __shfl_xor(mx, 8));
            float e0 = __expf(v0 - mx), e1 = __expf(v1 - mx), e2 = __expf(v2 - mx);
            float e3 = (c < 14) ? __expf(v3 - mx) : 0.f;
            float sum = e0 + e1 + e2 + e3;
            sum += __shfl_xor(sum, 1);
            sum += __shfl_xor(sum, 2);
            sum += __shfl_xor(sum, 4);
            sum += __shfl_xor(sum, 8);
            const float inv = 1.f / sum;
            e0 *= inv; e1 *= inv; e2 *= inv; e3 *= inv;
            if (n < 62 && c == (n & 15)) {
                const int dt = n >> 4;
                if (dt == 0) e0 = 1.f;
                else if (dt == 1) e1 = 1.f;
                else if (dt == 2) e2 = 1.f;
                else e3 = 1.f;
            }
            float dg = e0 + e1 + e2 + e3;
            dg += __shfl_xor(dg, 1);
            dg += __shfl_xor(dg, 2);
            dg += __shfl_xor(dg, 4);
            dg += __shfl_xor(dg, 8);
            const float d = rsqrtf(fmaxf(dg, 1.f));
            if (c == 0) degis[n] = d;
            dri[j] = d;
            e[j][0] = e0; e[j][1] = e1; e[j][2] = e2; e[j][3] = e3;
        }
        __syncthreads();
        {
            const float dm0 = degis[c],      dm1 = degis[16 + c];
            const float dm2 = degis[32 + c], dm3 = degis[48 + c];
            #pragma unroll
            for (int j = 0; j < 4; ++j) {
                const int n = wv * 16 + q * 4 + j;
                unsigned short* pr = P + n * 72 + c;
                if (n < 62) {
                    pr[0]  = f32_to_bf16_rne(e[j][0] * dri[j] * dm0);
                    pr[16] = f32_to_bf16_rne(e[j][1] * dri[j] * dm1);
                    pr[32] = f32_to_bf16_rne(e[j][2] * dri[j] * dm2);
                    pr[48] = f32_to_bf16_rne(e[j][3] * dri[j] * dm3);
                } else { pr[0] = 0; pr[16] = 0; pr[32] = 0; pr[48] = 0; }
            }
        }
        __syncthreads();
        {
            f32x4 oa0 = {0.f, 0.f, 0.f, 0.f}, oa1 = {0.f, 0.f, 0.f, 0.f};
            #pragma unroll
            for (int kh = 0; kh < 2; ++kh) {
                const int chh = (kh * 4 + q) * 8;
                const bf16x8 pa = *(const bf16x8*)(P + (wv * 16 + c) * 72 + chh);
                const bf16x8 z0 = *(const bf16x8*)(zB + c * 72 + chh);
                const bf16x8 z1 = *(const bf16x8*)(zB + (16 + c) * 72 + chh);
                oa0 = __builtin_amdgcn_mfma_f32_16x16x32_bf16(pa, z0, oa0, 0, 0, 0);
                oa1 = __builtin_amdgcn_mfma_f32_16x16x32_bf16(pa, z1, oa1, 0, 0, 0);
            }
            const float* gbp = (st == 0) ? gb1 : (st == 1) ? gb2 : gb3;
            const float g0 = gbp[c], g1 = gbp[16 + c];
            #pragma unroll
            for (int j = 0; j < 4; ++j) {
                const int n = wv * 16 + q * 4 + j;
                unsigned short* xr = xB + n * 40 + c;
                if (n < 62) {
                    xr[0]  = f32_to_bf16_rne(oa0[j] + g0);
                    xr[16] = f32_to_bf16_rne(oa1[j] + g1);
                } else { xr[0] = 0; xr[16] = 0; }
            }
        }
        __syncthreads();
        if (st == 2) break;

        {
            const unsigned short* wsB = wstg + st * 3072;
            const float* bnbp = (st == 0) ? bnb2 : bnb3;
            const bf16x8 ax = *(const bf16x8*)(xB + (wv * 16 + c) * 40 + q * 8);
            f32x4 sa[6];
            #pragma unroll
            for (int nt = 0; nt < 6; ++nt) {
                const bf16x8 wb = *(const bf16x8*)(wsB + (nt * 16 + c) * 32 + q * 8);
                f32x4 zz = {0.f, 0.f, 0.f, 0.f};
                sa[nt] = __builtin_amdgcn_mfma_f32_16x16x32_bf16(ax, wb, zz, 0, 0, 0);
            }
            #pragma unroll
            for (int nt = 0; nt < 4; ++nt) {
                const float bb = bnbp[nt * 16 + c];
                #pragma unroll
                for (int j = 0; j < 4; ++j) {
                    const int n = wv * 16 + q * 4 + j;
                    float th = fast_tanh(sa[nt][j] + bb);
                    if (n >= 62) th = 0.f;
                    const unsigned short h = f32_to_bf16_rne(th);
                    const unsigned short l = f32_to_bf16_rne(th - bf16_bits_to_f32(h));
                    xaH[n * 72 + nt * 16 + c] = h;
                    xaL[n * 72 + nt * 16 + c] = l;
                }
            }
            #pragma unroll
            for (int nt = 4; nt < 6; ++nt) {
                const int o = (nt - 4) * 16 + c;
                unsigned short zv[4];
                #pragma unroll
                for (int j = 0; j < 4; ++j) {
                    const int n = wv * 16 + q * 4 + j;
                    zv[j] = (n < 62) ? f32_to_bf16_rne(sa[nt][j]) : (unsigned short)0;
                }
                *(ushort4*)(zB + o * 72 + wv * 16 + q * 4) =
                    make_ushort4(zv[0], zv[1], zv[2], zv[3]);
            }
        }
        __syncthreads();
    }

    // ---- maxpool3 + fc ----
    float a0 = 0.f, a1 = 0.f, a2 = 0.f;
    for (int t = tid; t < 620; t += 256) {
        const int n = t / 10, tt = t - (t / 10) * 10;
        const unsigned short* pr = xB + n * 40 + tt * 3;
        const float p = fmaxf(fmaxf(bf16_bits_to_f32(pr[0]), bf16_bits_to_f32(pr[1])),
                              bf16_bits_to_f32(pr[2]));
        const float* fw = fcw + t * 3;
        a0 = fmaf(p, fw[0], a0);
        a1 = fmaf(p, fw[1], a1);
        a2 = fmaf(p, fw[2], a2);
    }
    #pragma unroll
    for (int off = 32; off; off >>= 1) {
        a0 += __shfl_down(a0, off);
        a1 += __shfl_down(a1, off);
        a2 += __shfl_down(a2, off);
    }
    float* red = degis;
    if (ln == 0) { red[wv * 3 + 0] = a0; red[wv * 3 + 1] = a1; red[wv * 3 + 2] = a2; }
    __syncthreads();
    if (tid == 0) {
        out[b * 3 + 0] = red[0] + red[3] + red[6] + red[9]  + fcb[0];
        out[b * 3 + 1] = red[1] + red[4] + red[7] + red[10] + fcb[1];
        out[b * 3 + 2] = red[2] + red[5] + red[8] + red[11] + fcb[2];
    }
}

// ============================== launcher ====================================
extern "C" void kernel_launch(void* const* d_in, const int* in_sizes, int n_in,
                              void* d_out, int out_size, void* d_ws, size_t ws_size,
                              hipStream_t stream) {
    const float* x     = (const float*)d_in[0];
    const float* convw = (const float*)d_in[1];
    const float* convb = (const float*)d_in[2];
    const float* bnw1  = (const float*)d_in[3];
    const float* bnb1  = (const float*)d_in[4];
    const float* gw1   = (const float*)d_in[5];
    const float* gb1   = (const float*)d_in[6];
    const float* bnw2  = (const float*)d_in[7];
    const float* bnb2  = (const float*)d_in[8];
    const float* gw2   = (const float*)d_in[9];
    const float* gb2   = (const float*)d_in[10];
    const float* bnw3  = (const float*)d_in[11];
    const float* bnb3  = (const float*)d_in[12];
    const float* gw3   = (const float*)d_in[13];
    const float* gb3   = (const float*)d_in[14];
    const float* fcw   = (const float*)d_in[15];
    const float* fcb   = (const float*)d_in[16];

    unsigned short* wp  = (unsigned short*)d_ws;
    unsigned short* img = wp + IMG_OFF;

    prepack_kernel<<<210, 256, 0, stream>>>(bnw1, gw1, convw, bnw2, gw2,
                                            bnw3, gw3, wp);
    conv_g1_kernel<<<1024, 256, 0, stream>>>(x, convb, wp, bnb1, img);
    sogc_tail_kernel<<<1024, 256, 0, stream>>>(wp, gb1, gb2, gb3,
                                               bnb2, bnb3, fcw, fcb,
                                               (float*)d_out);
}

// Round 9
// 87.262 us; speedup vs baseline: 3.7886x; 1.1377x over previous
//
#include <hip/hip_runtime.h>
#include <math.h>

// ---------------------------------------------------------------------------
// B=1024. R9: single mega-kernel (conv+G1+tail), 4 blk/CU, hi-only G1 W.
//   reshape fact: node n = (c*62+r)/32, feature f = ((c*62+r)%32)*15 + j
//   G1 K-order permuted: k' = pj*32 + s; W table padded to 16 kc (kc15 = 0)
//   conv via mfma_32x32x16 (32 pos x 32 ch), 3 K-chunks
//   per pjg: conv 4 pooled cols -> Xcol[64][128] (XOR-swizzled) -> G1 kc block
//   epilogue writes xaH/xaL/zB straight to LDS; R6-proven all-MFMA tail runs
//   in the same block (LDS overlay over dead conv buffers).
// ---------------------------------------------------------------------------

typedef short bf16x8 __attribute__((ext_vector_type(8)));
typedef float f32x4  __attribute__((ext_vector_type(4)));
typedef float f32x16 __attribute__((ext_vector_type(16)));

__device__ __forceinline__ unsigned short f32_to_bf16_rne(float f) {
    unsigned int u = __builtin_bit_cast(unsigned int, f);
    u += 0x7fffu + ((u >> 16) & 1u);
    return (unsigned short)(u >> 16);
}
__device__ __forceinline__ float bf16_bits_to_f32(unsigned short h) {
    unsigned int u = ((unsigned int)h) << 16;
    return __builtin_bit_cast(float, u);
}
__device__ __forceinline__ float fast_tanh(float v) {
    v = fminf(fmaxf(v, -15.f), 15.f);
    const float ex = __expf(2.f * v);
    return (ex - 1.f) / (ex + 1.f);
}

// ws layout (u16 units):
//   [0, 49152)        G1 W hi, 16 kc (kc=15 zeros), B-frag order k'=pj*32+s
//   [92160, 93696)    conv W frags (32x32 shape, 3 chunks)
//   [94208, 100352)   stage2 (3072) + stage3 (3072) B-frag [col 96][k 32]

// ============================ prepack ======================================
__global__ __launch_bounds__(256) void prepack_kernel(
    const float* __restrict__ bnw1, const float* __restrict__ gw1,
    const float* __restrict__ cw,
    const float* __restrict__ bnw2, const float* __restrict__ gw2,
    const float* __restrict__ bnw3, const float* __restrict__ gw3,
    unsigned short* __restrict__ wp)
{
    const int idx = blockIdx.x * 256 + threadIdx.x;   // grid covers 100352
    if (idx < 49152) {
        // B[k' = kc*32 + q*8 + j][col]; k' = pj*32+s -> orig k = s*15 + pj
        const int kc = idx / 3072, r = idx - kc * 3072;
        const int q = r / 768, r2 = r - q * 768;
        const int col = r2 >> 3, j = r2 & 7;
        float w = 0.f;
        if (kc < 15) {
            const int s = q * 8 + j;
            const int ko = s * 15 + kc;
            w = (col < 64) ? bnw1[ko * 64 + col] : gw1[ko * 32 + (col - 64)];
        }
        wp[idx] = f32_to_bf16_rne(w);
    } else if (idx >= 92160 && idx < 93696) {
        // conv W 32x32: chunk c, lane l: ch=l&31, dio=l>>5; di = 2c+dio | 4+dio
        const int e = idx - 92160;
        const int c = e >> 9, l = (e >> 3) & 63, j = e & 7;
        const int ch = l & 31, dio = l >> 5;
        const int di = (c < 2) ? (2 * c + dio) : (4 + dio);
        const float w = (j < 5 && di < 5) ? cw[ch * 25 + di * 5 + j] : 0.f;
        wp[idx] = f32_to_bf16_rne(w);
    } else if (idx >= 94208 && idx < 100352) {
        const int e2 = idx - 94208;
        const int s = e2 / 3072, r = e2 - s * 3072;
        const int col = r >> 5, k = r & 31;
        const float* bnw = s ? bnw3 : bnw2;
        const float* gw  = s ? gw3  : gw2;
        const float w = (col < 64) ? bnw[k * 64 + col] : gw[k * 32 + (col - 64)];
        wp[idx] = f32_to_bf16_rne(w);
    }
}

// ============================= mega kernel =================================
__global__ __launch_bounds__(256, 4) void mega_kernel(
    const float* __restrict__ x,     // (B,66,64)
    const float* __restrict__ cb,    // (32,)
    const unsigned short* __restrict__ wp,
    const float* __restrict__ bnb1,  const float* __restrict__ gb1,
    const float* __restrict__ bnb2,  const float* __restrict__ gb2,
    const float* __restrict__ bnb3,  const float* __restrict__ gb3,
    const float* __restrict__ fcw,   const float* __restrict__ fcb,
    float* __restrict__ out)         // (B,3)
{
    // conv phase: xb @0 (13056 B, 68x96 bf16) | Xcol @13056 (16384 B, 64x128)
    // tail phase (overlays, conv dead): xaH u16@0 [64][72] | xaL u16@4608 |
    //   zB u16@9216 [32][72] | P u16@11520 [64][72] | xB u16@16128 [64][40] |
    //   degis @byte 37376
    __shared__ __align__(16) char lds[37632];
    unsigned short* xb   = (unsigned short*)lds;
    unsigned short* Xcol = (unsigned short*)(lds + 13056);
    unsigned short* xaH  = (unsigned short*)lds;
    unsigned short* xaL  = xaH + 4608;
    unsigned short* zB   = xaH + 9216;
    unsigned short* P    = xaH + 11520;
    unsigned short* xB   = xaH + 16128;
    float* degis = (float*)(lds + 37376);

    const int b = blockIdx.x;
    const int tid = threadIdx.x;
    const int wv = tid >> 6, ln = tid & 63;

    // ---- phase A: x -> bf16 LDS; zero pads ----
    const float4* xg = (const float4*)(x + (size_t)b * 4224);
    for (int idx = tid; idx < 1056; idx += 256) {
        const float4 v = xg[idx];
        const int row = idx >> 4, c4 = idx & 15;
        short4 s;
        s.x = (short)f32_to_bf16_rne(v.x);
        s.y = (short)f32_to_bf16_rne(v.y);
        s.z = (short)f32_to_bf16_rne(v.z);
        s.w = (short)f32_to_bf16_rne(v.w);
        *(short4*)(xb + row * 96 + c4 * 4) = s;
    }
    for (int idx = tid; idx < 544; idx += 256) {        // cols 64..95 zero
        const int row = idx >> 3, w = idx & 7;
        ((unsigned int*)(xb + row * 96 + 64))[w] = 0u;
    }
    if (tid < 128) {                                    // rows 66,67 cols 0..63
        const int row = 66 + (tid >> 5), w = tid & 31;
        ((unsigned int*)(xb + row * 96))[w] = 0u;
    }
    if (tid < 128)                                      // Xcol rows 62,63 zero
        ((unsigned int*)(Xcol + 62 * 128))[tid] = 0u;
    __syncthreads();

    // conv lane roles (32x32): ch=l&31, hi=l>>5; A: m=l&15, rp=(l>>4)&1, dio=l>>5
    const int m = ln & 15, rp = (ln >> 4) & 1, dio = ln >> 5;
    const int ch = ln & 31, hi = ln >> 5;
    bf16x8 Wc[3];
    #pragma unroll
    for (int c = 0; c < 3; ++c)
        Wc[c] = *(const bf16x8*)(wp + 92160 + c * 512 + ln * 8);
    const float cbv = cb[ch];

    // G1 lane roles (16x16): rt = l&15, q = l>>4
    const int rt = ln & 15, q = ln >> 4;
    f32x4 acc[6];
    #pragma unroll
    for (int nt = 0; nt < 6; ++nt) acc[nt] = (f32x4){0.f, 0.f, 0.f, 0.f};

    for (int pjg = 0; pjg < 4; ++pjg) {
        const int j0 = pjg * 16;
        // ---- conv: 31 row-pairs, pooled cols pjg*4 + {0..3} -> Xcol ----
        for (int p = wv; p < 31; p += 4) {
            const int r0 = 2 * p;
            const unsigned short* base = xb + (r0 + rp + dio) * 96 + j0 + m;
            f32x16 a32;
            #pragma unroll
            for (int i = 0; i < 16; ++i) a32[i] = 0.f;
            #pragma unroll
            for (int c = 0; c < 3; ++c) {
                bf16x8 A;
                A[0] = (short)base[c * 192 + 0];
                A[1] = (short)base[c * 192 + 1];
                A[2] = (short)base[c * 192 + 2];
                A[3] = (short)base[c * 192 + 3];
                A[4] = (short)base[c * 192 + 4];
                A[5] = A[0]; A[6] = A[1]; A[7] = A[2];   // kk>=5: W=0
                a32 = __builtin_amdgcn_mfma_f32_32x32x16_bf16(A, Wc[c], a32, 0, 0, 0);
            }
            #pragma unroll
            for (int i = 0; i < 4; ++i) {
                const int t = 2 * i + hi;
                const int rpo = t >> 2, g = t & 3;
                float v = fmaxf(fmaxf(a32[4 * i], a32[4 * i + 1]),
                                fmaxf(a32[4 * i + 2], a32[4 * i + 3])) + cbv;
                v = fmaxf(v, 0.f);
                if (!(pjg == 3 && g == 3)) {
                    const int row = r0 + rpo;
                    const int tt = ch * 62 + row;        // n = tt/32, s = tt%32
                    const int n = tt >> 5, sf = tt & 31;
                    Xcol[n * 128 + ((g * 32 + sf) ^ ((n & 7) << 3))] =
                        f32_to_bf16_rne(v);
                }
            }
        }
        __syncthreads();
        // ---- G1: kc = pjg*4 + g (kc=15 -> zero W); full unroll ----
        {
            const int row = wv * 16 + rt;
            #pragma unroll
            for (int g = 0; g < 4; ++g) {
                const int kc = pjg * 4 + g;
                const bf16x8 A = *(const bf16x8*)(
                    Xcol + row * 128 + (((g * 4 + q) ^ (row & 7)) << 3));
                #pragma unroll
                for (int nt = 0; nt < 6; ++nt) {
                    const bf16x8 Bh = *(const bf16x8*)(
                        wp + kc * 3072 + q * 768 + nt * 128 + rt * 8);
                    acc[nt] = __builtin_amdgcn_mfma_f32_16x16x32_bf16(A, Bh, acc[nt], 0, 0, 0);
                }
            }
        }
        __syncthreads();
    }

    // ---- G1 epilogue -> tail LDS buffers (conv buffers dead) ----
    {
        const int rq = wv * 4 + q;
        #pragma unroll
        for (int nt = 0; nt < 4; ++nt) {
            const float bb = bnb1[nt * 16 + rt];
            #pragma unroll
            for (int j = 0; j < 4; ++j) {
                const int r = rq * 4 + j;
                float th = fast_tanh(acc[nt][j] + bb);
                if (r >= 62) th = 0.f;
                const unsigned short h = f32_to_bf16_rne(th);
                const unsigned short l = f32_to_bf16_rne(th - bf16_bits_to_f32(h));
                xaH[r * 72 + nt * 16 + rt] = h;
                xaL[r * 72 + nt * 16 + rt] = l;
            }
        }
        #pragma unroll
        for (int nt = 4; nt < 6; ++nt) {
            const int o = (nt - 4) * 16 + rt;
            unsigned short zv[4];
            #pragma unroll
            for (int j = 0; j < 4; ++j) {
                const int r = rq * 4 + j;
                zv[j] = (r < 62) ? f32_to_bf16_rne(acc[nt][j]) : (unsigned short)0;
            }
            *(ushort4*)(zB + o * 72 + rq * 4) =
                make_ushort4(zv[0], zv[1], zv[2], zv[3]);
        }
    }
    __syncthreads();

    // ---- tail: 3x SOGC all-MFMA (R6-proven) ----
    const int c16 = ln & 15;
    const unsigned short* wstg = wp + 94208;

    #pragma unroll 1
    for (int st = 0; st < 3; ++st) {
        f32x4 sacc[4];
        #pragma unroll
        for (int t = 0; t < 4; ++t) sacc[t] = (f32x4){0.f, 0.f, 0.f, 0.f};
        const int arow = (wv * 16 + c16) * 72;
        #pragma unroll
        for (int kh = 0; kh < 2; ++kh) {
            const int chh = (kh * 4 + q) * 8;
            const bf16x8 AH = *(const bf16x8*)(xaH + arow + chh);
            const bf16x8 AL = *(const bf16x8*)(xaL + arow + chh);
            #pragma unroll
            for (int t = 0; t < 4; ++t) {
                const bf16x8 BH = *(const bf16x8*)(xaH + (t * 16 + c16) * 72 + chh);
                const bf16x8 BL = *(const bf16x8*)(xaL + (t * 16 + c16) * 72 + chh);
                sacc[t] = __builtin_amdgcn_mfma_f32_16x16x32_bf16(AH, BH, sacc[t], 0, 0, 0);
                sacc[t] = __builtin_amdgcn_mfma_f32_16x16x32_bf16(AH, BL, sacc[t], 0, 0, 0);
                sacc[t] = __builtin_amdgcn_mfma_f32_16x16x32_bf16(AL, BH, sacc[t], 0, 0, 0);
            }
        }
        float e[4][4], dri[4];
        #pragma unroll
        for (int j = 0; j < 4; ++j) {
            const int n = wv * 16 + q * 4 + j;
            const float v0 = sacc[0][j], v1 = sacc[1][j];
            const float v2 = sacc[2][j], v3 = sacc[3][j];
            float mx = fmaxf(fmaxf(v0, v1), v2);
            if (c16 < 14) mx = fmaxf(mx, v3);
            mx = fmaxf(mx, __shfl_xor(mx, 1));
            mx = fmaxf(mx, __shfl_xor(mx, 2));
            mx = fmaxf(mx, __shfl_xor(mx, 4));
            mx = fmaxf(mx, __shfl_xor(mx, 8));
            float e0 = __expf(v0 - mx), e1 = __expf(v1 - mx), e2 = __expf(v2 - mx);
            float e3 = (c16 < 14) ? __expf(v3 - mx) : 0.f;
            float sum = e0 + e1 + e2 + e3;
            sum += __shfl_xor(sum, 1);
            sum += __shfl_xor(sum, 2);
            sum += __shfl_xor(sum, 4);
            sum += __shfl_xor(sum, 8);
            const float inv = 1.f / sum;
            e0 *= inv; e1 *= inv; e2 *= inv; e3 *= inv;
            if (n < 62 && c16 == (n & 15)) {
                const int dt = n >> 4;
                if (dt == 0) e0 = 1.f;
                else if (dt == 1) e1 = 1.f;
                else if (dt == 2) e2 = 1.f;
                else e3 = 1.f;
            }
            float dg = e0 + e1 + e2 + e3;
            dg += __shfl_xor(dg, 1);
            dg += __shfl_xor(dg, 2);
            dg += __shfl_xor(dg, 4);
            dg += __shfl_xor(dg, 8);
            const float d = rsqrtf(fmaxf(dg, 1.f));
            if (c16 == 0) degis[n] = d;
            dri[j] = d;
            e[j][0] = e0; e[j][1] = e1; e[j][2] = e2; e[j][3] = e3;
        }
        __syncthreads();
        {
            const float dm0 = degis[c16],      dm1 = degis[16 + c16];
            const float dm2 = degis[32 + c16], dm3 = degis[48 + c16];
            #pragma unroll
            for (int j = 0; j < 4; ++j) {
                const int n = wv * 16 + q * 4 + j;
                unsigned short* pr = P + n * 72 + c16;
                if (n < 62) {
                    pr[0]  = f32_to_bf16_rne(e[j][0] * dri[j] * dm0);
                    pr[16] = f32_to_bf16_rne(e[j][1] * dri[j] * dm1);
                    pr[32] = f32_to_bf16_rne(e[j][2] * dri[j] * dm2);
                    pr[48] = f32_to_bf16_rne(e[j][3] * dri[j] * dm3);
                } else { pr[0] = 0; pr[16] = 0; pr[32] = 0; pr[48] = 0; }
            }
        }
        __syncthreads();
        {
            f32x4 oa0 = {0.f, 0.f, 0.f, 0.f}, oa1 = {0.f, 0.f, 0.f, 0.f};
            #pragma unroll
            for (int kh = 0; kh < 2; ++kh) {
                const int chh = (kh * 4 + q) * 8;
                const bf16x8 pa = *(const bf16x8*)(P + (wv * 16 + c16) * 72 + chh);
                const bf16x8 z0 = *(const bf16x8*)(zB + c16 * 72 + chh);
                const bf16x8 z1 = *(const bf16x8*)(zB + (16 + c16) * 72 + chh);
                oa0 = __builtin_amdgcn_mfma_f32_16x16x32_bf16(pa, z0, oa0, 0, 0, 0);
                oa1 = __builtin_amdgcn_mfma_f32_16x16x32_bf16(pa, z1, oa1, 0, 0, 0);
            }
            const float* gbp = (st == 0) ? gb1 : (st == 1) ? gb2 : gb3;
            const float g0 = gbp[c16], g1 = gbp[16 + c16];
            #pragma unroll
            for (int j = 0; j < 4; ++j) {
                const int n = wv * 16 + q * 4 + j;
                unsigned short* xr = xB + n * 40 + c16;
                if (n < 62) {
                    xr[0]  = f32_to_bf16_rne(oa0[j] + g0);
                    xr[16] = f32_to_bf16_rne(oa1[j] + g1);
                } else { xr[0] = 0; xr[16] = 0; }
            }
        }
        __syncthreads();
        if (st == 2) break;

        {
            const unsigned short* wsB = wstg + st * 3072;
            const float* bnbp = (st == 0) ? bnb2 : bnb3;
            const bf16x8 ax = *(const bf16x8*)(xB + (wv * 16 + c16) * 40 + q * 8);
            f32x4 sa[6];
            #pragma unroll
            for (int nt = 0; nt < 6; ++nt) {
                const bf16x8 wb = *(const bf16x8*)(wsB + (nt * 16 + c16) * 32 + q * 8);
                f32x4 zz = {0.f, 0.f, 0.f, 0.f};
                sa[nt] = __builtin_amdgcn_mfma_f32_16x16x32_bf16(ax, wb, zz, 0, 0, 0);
            }
            #pragma unroll
            for (int nt = 0; nt < 4; ++nt) {
                const float bb = bnbp[nt * 16 + c16];
                #pragma unroll
                for (int j = 0; j < 4; ++j) {
                    const int n = wv * 16 + q * 4 + j;
                    float th = fast_tanh(sa[nt][j] + bb);
                    if (n >= 62) th = 0.f;
                    const unsigned short h = f32_to_bf16_rne(th);
                    const unsigned short l = f32_to_bf16_rne(th - bf16_bits_to_f32(h));
                    xaH[n * 72 + nt * 16 + c16] = h;
                    xaL[n * 72 + nt * 16 + c16] = l;
                }
            }
            #pragma unroll
            for (int nt = 4; nt < 6; ++nt) {
                const int o = (nt - 4) * 16 + c16;
                unsigned short zv[4];
                #pragma unroll
                for (int j = 0; j < 4; ++j) {
                    const int n = wv * 16 + q * 4 + j;
                    zv[j] = (n < 62) ? f32_to_bf16_rne(sa[nt][j]) : (unsigned short)0;
                }
                *(ushort4*)(zB + o * 72 + wv * 16 + q * 4) =
                    make_ushort4(zv[0], zv[1], zv[2], zv[3]);
            }
        }
        __syncthreads();
    }

    // ---- maxpool3 + fc ----
    float a0 = 0.f, a1 = 0.f, a2 = 0.f;
    for (int t = tid; t < 620; t += 256) {
        const int n = t / 10, tt = t - (t / 10) * 10;
        const unsigned short* pr = xB + n * 40 + tt * 3;
        const float p = fmaxf(fmaxf(bf16_bits_to_f32(pr[0]), bf16_bits_to_f32(pr[1])),
                              bf16_bits_to_f32(pr[2]));
        const float* fw = fcw + t * 3;
        a0 = fmaf(p, fw[0], a0);
        a1 = fmaf(p, fw[1], a1);
        a2 = fmaf(p, fw[2], a2);
    }
    #pragma unroll
    for (int off = 32; off; off >>= 1) {
        a0 += __shfl_down(a0, off);
        a1 += __shfl_down(a1, off);
        a2 += __shfl_down(a2, off);
    }
    float* red = degis;
    if (ln == 0) { red[wv * 3 + 0] = a0; red[wv * 3 + 1] = a1; red[wv * 3 + 2] = a2; }
    __syncthreads();
    if (tid == 0) {
        out[b * 3 + 0] = red[0] + red[3] + red[6] + red[9]  + fcb[0];
        out[b * 3 + 1] = red[1] + red[4] + red[7] + red[10] + fcb[1];
        out[b * 3 + 2] = red[2] + red[5] + red[8] + red[11] + fcb[2];
    }
}

// ============================== launcher ====================================
extern "C" void kernel_launch(void* const* d_in, const int* in_sizes, int n_in,
                              void* d_out, int out_size, void* d_ws, size_t ws_size,
                              hipStream_t stream) {
    const float* x     = (const float*)d_in[0];
    const float* convw = (const float*)d_in[1];
    const float* convb = (const float*)d_in[2];
    const float* bnw1  = (const float*)d_in[3];
    const float* bnb1  = (const float*)d_in[4];
    const float* gw1   = (const float*)d_in[5];
    const float* gb1   = (const float*)d_in[6];
    const float* bnw2  = (const float*)d_in[7];
    const float* bnb2  = (const float*)d_in[8];
    const float* gw2   = (const float*)d_in[9];
    const float* gb2   = (const float*)d_in[10];
    const float* bnw3  = (const float*)d_in[11];
    const float* bnb3  = (const float*)d_in[12];
    const float* gw3   = (const float*)d_in[13];
    const float* gb3   = (const float*)d_in[14];
    const float* fcw   = (const float*)d_in[15];
    const float* fcb   = (const float*)d_in[16];

    unsigned short* wp = (unsigned short*)d_ws;   // 200,704 B used

    prepack_kernel<<<392, 256, 0, stream>>>(bnw1, gw1, convw, bnw2, gw2,
                                            bnw3, gw3, wp);
    mega_kernel<<<1024, 256, 0, stream>>>(x, convb, wp, bnb1, gb1,
                                          bnb2, gb2, bnb3, gb3,
                                          fcw, fcb, (float*)d_out);
}

// Round 10
// 83.643 us; speedup vs baseline: 3.9526x; 1.0433x over previous
//
#include <hip/hip_runtime.h>
#include <math.h>

// ---------------------------------------------------------------------------
// B=1024. R10: single mega-kernel (conv+G1+tail), all-fp16 datapath.
//   reshape fact: node n = (c*62+r)/32, feature f = ((c*62+r)%32)*15 + j
//   G1 K-order permuted: k' = pj*32 + s; W table padded to 16 kc (kc15 = 0)
//   conv via mfma_32x32x16_f16 (32 pos x 32 ch), 3 K-chunks
//   per pjg: conv 4 pooled cols -> Xcol[64][128] (XOR-swizzled) -> G1 kc block
//   tail: 3x SOGC all-fp16-MFMA (single S mfma, fp32 register softmax)
// ---------------------------------------------------------------------------

typedef _Float16 f16x8 __attribute__((ext_vector_type(8)));
typedef short    s16x8 __attribute__((ext_vector_type(8)));
typedef float    f32x4  __attribute__((ext_vector_type(4)));
typedef float    f32x16 __attribute__((ext_vector_type(16)));

__device__ __forceinline__ unsigned short f32_to_f16u(float f) {
    const _Float16 h = (_Float16)f;
    return __builtin_bit_cast(unsigned short, h);
}
__device__ __forceinline__ float f16u_to_f32(unsigned short u) {
    return (float)__builtin_bit_cast(_Float16, u);
}
__device__ __forceinline__ float fast_tanh(float v) {
    v = fminf(fmaxf(v, -15.f), 15.f);
    const float ex = __expf(2.f * v);
    return (ex - 1.f) / (ex + 1.f);
}

// ws layout (u16 units):
//   [0, 49152)        G1 W fp16, 16 kc (kc=15 zeros), B-frag order k'=pj*32+s
//   [92160, 93696)    conv W frags fp16 (32x32 shape, 3 chunks)
//   [94208, 100352)   stage2 (3072) + stage3 (3072) B-frag fp16 [col 96][k 32]

// ============================ prepack ======================================
__global__ __launch_bounds__(256) void prepack_kernel(
    const float* __restrict__ bnw1, const float* __restrict__ gw1,
    const float* __restrict__ cw,
    const float* __restrict__ bnw2, const float* __restrict__ gw2,
    const float* __restrict__ bnw3, const float* __restrict__ gw3,
    unsigned short* __restrict__ wp)
{
    const int idx = blockIdx.x * 256 + threadIdx.x;   // grid covers 100352
    if (idx < 49152) {
        const int kc = idx / 3072, r = idx - kc * 3072;
        const int q = r / 768, r2 = r - q * 768;
        const int col = r2 >> 3, j = r2 & 7;
        float w = 0.f;
        if (kc < 15) {
            const int s = q * 8 + j;
            const int ko = s * 15 + kc;
            w = (col < 64) ? bnw1[ko * 64 + col] : gw1[ko * 32 + (col - 64)];
        }
        wp[idx] = f32_to_f16u(w);
    } else if (idx >= 92160 && idx < 93696) {
        const int e = idx - 92160;
        const int c = e >> 9, l = (e >> 3) & 63, j = e & 7;
        const int ch = l & 31, dio = l >> 5;
        const int di = (c < 2) ? (2 * c + dio) : (4 + dio);
        const float w = (j < 5 && di < 5) ? cw[ch * 25 + di * 5 + j] : 0.f;
        wp[idx] = f32_to_f16u(w);
    } else if (idx >= 94208 && idx < 100352) {
        const int e2 = idx - 94208;
        const int s = e2 / 3072, r = e2 - s * 3072;
        const int col = r >> 5, k = r & 31;
        const float* bnw = s ? bnw3 : bnw2;
        const float* gw  = s ? gw3  : gw2;
        const float w = (col < 64) ? bnw[k * 64 + col] : gw[k * 32 + (col - 64)];
        wp[idx] = f32_to_f16u(w);
    }
}

// ============================= mega kernel =================================
__global__ __launch_bounds__(256, 4) void mega_kernel(
    const float* __restrict__ x,     // (B,66,64)
    const float* __restrict__ cb,    // (32,)
    const unsigned short* __restrict__ wp,
    const float* __restrict__ bnb1,  const float* __restrict__ gb1,
    const float* __restrict__ bnb2,  const float* __restrict__ gb2,
    const float* __restrict__ bnb3,  const float* __restrict__ gb3,
    const float* __restrict__ fcw,   const float* __restrict__ fcb,
    float* __restrict__ out)         // (B,3)
{
    // conv phase: xb @0 (10880 B, 68x80 f16) | Xcol @10880 (16384 B, 64x128)
    // tail phase (overlays): xaH u16@0 [64][72] | zB u16@4608 [32][72] |
    //   P u16@6912 [64][72] | xB u16@11520 [64][40] | degis @byte 28160
    __shared__ __align__(16) char lds[28416];
    unsigned short* xb   = (unsigned short*)lds;
    unsigned short* Xcol = (unsigned short*)(lds + 10880);
    unsigned short* xaH  = (unsigned short*)lds;
    unsigned short* zB   = xaH + 4608;
    unsigned short* P    = xaH + 6912;
    unsigned short* xB   = xaH + 11520;
    float* degis = (float*)(lds + 28160);

    const int b = blockIdx.x;
    const int tid = threadIdx.x;
    const int wv = tid >> 6, ln = tid & 63;

    // ---- phase A: x -> f16 LDS; zero pads ----
    const float4* xg = (const float4*)(x + (size_t)b * 4224);
    for (int idx = tid; idx < 1056; idx += 256) {
        const float4 v = xg[idx];
        const int row = idx >> 4, c4 = idx & 15;
        short4 s;
        s.x = (short)f32_to_f16u(v.x);
        s.y = (short)f32_to_f16u(v.y);
        s.z = (short)f32_to_f16u(v.z);
        s.w = (short)f32_to_f16u(v.w);
        *(short4*)(xb + row * 80 + c4 * 4) = s;
    }
    for (int idx = tid; idx < 544; idx += 256) {        // cols 64..79 zero (68 rows)
        const int row = idx >> 3, w = idx & 7;
        ((unsigned int*)(xb + row * 80 + 64))[w] = 0u;
    }
    if (tid < 64) {                                     // rows 66,67 cols 0..63
        const int row = 66 + (tid >> 5), w = tid & 31;
        ((unsigned int*)(xb + row * 80))[w] = 0u;
    }
    if (tid < 128)                                      // Xcol rows 62,63 zero
        ((unsigned int*)(Xcol + 62 * 128))[tid] = 0u;
    __syncthreads();

    // conv lane roles: ch=l&31, hi=l>>5; A: m=l&15, rp=(l>>4)&1, dio=l>>5
    const int m = ln & 15, rp = (ln >> 4) & 1, dio = ln >> 5;
    const int ch = ln & 31, hi = ln >> 5;
    f16x8 Wc[3];
    #pragma unroll
    for (int c = 0; c < 3; ++c)
        Wc[c] = *(const f16x8*)(wp + 92160 + c * 512 + ln * 8);
    const float cbv = cb[ch];
    const f32x16 z16 = {};          // persistent zero accumulator

    // G1 lane roles: rt = l&15, q = l>>4
    const int rt = ln & 15, q = ln >> 4;
    f32x4 acc[6];
    #pragma unroll
    for (int nt = 0; nt < 6; ++nt) acc[nt] = (f32x4){0.f, 0.f, 0.f, 0.f};

    for (int pjg = 0; pjg < 4; ++pjg) {
        const int j0 = pjg * 16;
        // ---- conv: 31 row-pairs, pooled cols pjg*4 + {0..3} -> Xcol ----
        for (int p = wv; p < 31; p += 4) {
            const int r0 = 2 * p;
            const unsigned short* base = xb + (r0 + rp + dio) * 80 + j0 + m;
            f32x16 a32;
            #pragma unroll
            for (int c = 0; c < 3; ++c) {
                s16x8 A;
                A[0] = (short)base[c * 160 + 0];
                A[1] = (short)base[c * 160 + 1];
                A[2] = (short)base[c * 160 + 2];
                A[3] = (short)base[c * 160 + 3];
                A[4] = (short)base[c * 160 + 4];
                A[5] = A[0]; A[6] = A[1]; A[7] = A[2];   // kk>=5: W=0, finite vals
                const f16x8 Af = __builtin_bit_cast(f16x8, A);
                a32 = __builtin_amdgcn_mfma_f32_32x32x16_f16(
                          Af, Wc[c], (c == 0) ? z16 : a32, 0, 0, 0);
            }
            #pragma unroll
            for (int i = 0; i < 4; ++i) {
                const int t = 2 * i + hi;
                const int rpo = t >> 2, g = t & 3;
                float v = fmaxf(fmaxf(a32[4 * i], a32[4 * i + 1]),
                                fmaxf(a32[4 * i + 2], a32[4 * i + 3])) + cbv;
                v = fmaxf(v, 0.f);
                if (!(pjg == 3 && g == 3)) {
                    const int row = r0 + rpo;
                    const int tt = ch * 62 + row;        // n = tt/32, s = tt%32
                    const int n = tt >> 5, sf = tt & 31;
                    Xcol[n * 128 + ((g * 32 + sf) ^ ((n & 7) << 3))] =
                        f32_to_f16u(v);
                }
            }
        }
        __syncthreads();
        // ---- G1: kc = pjg*4 + g (kc=15 -> zero W); full unroll ----
        {
            const int row = wv * 16 + rt;
            #pragma unroll
            for (int g = 0; g < 4; ++g) {
                const int kc = pjg * 4 + g;
                const f16x8 A = *(const f16x8*)(
                    Xcol + row * 128 + (((g * 4 + q) ^ (row & 7)) << 3));
                #pragma unroll
                for (int nt = 0; nt < 6; ++nt) {
                    const f16x8 Bh = *(const f16x8*)(
                        wp + kc * 3072 + q * 768 + nt * 128 + rt * 8);
                    acc[nt] = __builtin_amdgcn_mfma_f32_16x16x32_f16(A, Bh, acc[nt], 0, 0, 0);
                }
            }
        }
        __syncthreads();
    }

    // ---- G1 epilogue -> tail LDS buffers (conv buffers dead) ----
    {
        const int rq = wv * 4 + q;
        #pragma unroll
        for (int nt = 0; nt < 4; ++nt) {
            const float bb = bnb1[nt * 16 + rt];
            #pragma unroll
            for (int j = 0; j < 4; ++j) {
                const int r = rq * 4 + j;
                float th = fast_tanh(acc[nt][j] + bb);
                if (r >= 62) th = 0.f;
                xaH[r * 72 + nt * 16 + rt] = f32_to_f16u(th);
            }
        }
        #pragma unroll
        for (int nt = 4; nt < 6; ++nt) {
            const int o = (nt - 4) * 16 + rt;
            unsigned short zv[4];
            #pragma unroll
            for (int j = 0; j < 4; ++j) {
                const int r = rq * 4 + j;
                zv[j] = (r < 62) ? f32_to_f16u(acc[nt][j]) : (unsigned short)0;
            }
            *(ushort4*)(zB + o * 72 + rq * 4) =
                make_ushort4(zv[0], zv[1], zv[2], zv[3]);
        }
    }
    __syncthreads();

    // ---- tail: 3x SOGC all-fp16-MFMA ----
    const int c16 = ln & 15;
    const unsigned short* wstg = wp + 94208;

    #pragma unroll 1
    for (int st = 0; st < 3; ++st) {
        f32x4 sacc[4];
        #pragma unroll
        for (int t = 0; t < 4; ++t) sacc[t] = (f32x4){0.f, 0.f, 0.f, 0.f};
        const int arow = (wv * 16 + c16) * 72;
        #pragma unroll
        for (int kh = 0; kh < 2; ++kh) {
            const int chh = (kh * 4 + q) * 8;
            const f16x8 AH = *(const f16x8*)(xaH + arow + chh);
            #pragma unroll
            for (int t = 0; t < 4; ++t) {
                const f16x8 BH = *(const f16x8*)(xaH + (t * 16 + c16) * 72 + chh);
                sacc[t] = __builtin_amdgcn_mfma_f32_16x16x32_f16(AH, BH, sacc[t], 0, 0, 0);
            }
        }
        float e[4][4], dri[4];
        #pragma unroll
        for (int j = 0; j < 4; ++j) {
            const int n = wv * 16 + q * 4 + j;
            const float v0 = sacc[0][j], v1 = sacc[1][j];
            const float v2 = sacc[2][j], v3 = sacc[3][j];
            float mx = fmaxf(fmaxf(v0, v1), v2);
            if (c16 < 14) mx = fmaxf(mx, v3);
            mx = fmaxf(mx, __shfl_xor(mx, 1));
            mx = fmaxf(mx, __shfl_xor(mx, 2));
            mx = fmaxf(mx, __shfl_xor(mx, 4));
            mx = fmaxf(mx, __shfl_xor(mx, 8));
            float e0 = __expf(v0 - mx), e1 = __expf(v1 - mx), e2 = __expf(v2 - mx);
            float e3 = (c16 < 14) ? __expf(v3 - mx) : 0.f;
            float sum = e0 + e1 + e2 + e3;
            sum += __shfl_xor(sum, 1);
            sum += __shfl_xor(sum, 2);
            sum += __shfl_xor(sum, 4);
            sum += __shfl_xor(sum, 8);
            const float inv = 1.f / sum;
            e0 *= inv; e1 *= inv; e2 *= inv; e3 *= inv;
            if (n < 62 && c16 == (n & 15)) {
                const int dt = n >> 4;
                if (dt == 0) e0 = 1.f;
                else if (dt == 1) e1 = 1.f;
                else if (dt == 2) e2 = 1.f;
                else e3 = 1.f;
            }
            float dg = e0 + e1 + e2 + e3;
            dg += __shfl_xor(dg, 1);
            dg += __shfl_xor(dg, 2);
            dg += __shfl_xor(dg, 4);
            dg += __shfl_xor(dg, 8);
            const float d = rsqrtf(fmaxf(dg, 1.f));
            if (c16 == 0) degis[n] = d;
            dri[j] = d;
            e[j][0] = e0; e[j][1] = e1; e[j][2] = e2; e[j][3] = e3;
        }
        __syncthreads();
        {
            const float dm0 = degis[c16],      dm1 = degis[16 + c16];
            const float dm2 = degis[32 + c16], dm3 = degis[48 + c16];
            #pragma unroll
            for (int j = 0; j < 4; ++j) {
                const int n = wv * 16 + q * 4 + j;
                unsigned short* pr = P + n * 72 + c16;
                if (n < 62) {
                    pr[0]  = f32_to_f16u(e[j][0] * dri[j] * dm0);
                    pr[16] = f32_to_f16u(e[j][1] * dri[j] * dm1);
                    pr[32] = f32_to_f16u(e[j][2] * dri[j] * dm2);
                    pr[48] = f32_to_f16u(e[j][3] * dri[j] * dm3);
                } else { pr[0] = 0; pr[16] = 0; pr[32] = 0; pr[48] = 0; }
            }
        }
        __syncthreads();
        {
            f32x4 oa0 = {0.f, 0.f, 0.f, 0.f}, oa1 = {0.f, 0.f, 0.f, 0.f};
            #pragma unroll
            for (int kh = 0; kh < 2; ++kh) {
                const int chh = (kh * 4 + q) * 8;
                const f16x8 pa = *(const f16x8*)(P + (wv * 16 + c16) * 72 + chh);
                const f16x8 z0 = *(const f16x8*)(zB + c16 * 72 + chh);
                const f16x8 z1 = *(const f16x8*)(zB + (16 + c16) * 72 + chh);
                oa0 = __builtin_amdgcn_mfma_f32_16x16x32_f16(pa, z0, oa0, 0, 0, 0);
                oa1 = __builtin_amdgcn_mfma_f32_16x16x32_f16(pa, z1, oa1, 0, 0, 0);
            }
            const float* gbp = (st == 0) ? gb1 : (st == 1) ? gb2 : gb3;
            const float g0 = gbp[c16], g1 = gbp[16 + c16];
            #pragma unroll
            for (int j = 0; j < 4; ++j) {
                const int n = wv * 16 + q * 4 + j;
                unsigned short* xr = xB + n * 40 + c16;
                if (n < 62) {
                    xr[0]  = f32_to_f16u(oa0[j] + g0);
                    xr[16] = f32_to_f16u(oa1[j] + g1);
                } else { xr[0] = 0; xr[16] = 0; }
            }
        }
        __syncthreads();
        if (st == 2) break;

        {
            const unsigned short* wsB = wstg + st * 3072;
            const float* bnbp = (st == 0) ? bnb2 : bnb3;
            const f16x8 ax = *(const f16x8*)(xB + (wv * 16 + c16) * 40 + q * 8);
            f32x4 sa[6];
            #pragma unroll
            for (int nt = 0; nt < 6; ++nt) {
                const f16x8 wb = *(const f16x8*)(wsB + (nt * 16 + c16) * 32 + q * 8);
                f32x4 zz = {0.f, 0.f, 0.f, 0.f};
                sa[nt] = __builtin_amdgcn_mfma_f32_16x16x32_f16(ax, wb, zz, 0, 0, 0);
            }
            #pragma unroll
            for (int nt = 0; nt < 4; ++nt) {
                const float bb = bnbp[nt * 16 + c16];
                #pragma unroll
                for (int j = 0; j < 4; ++j) {
                    const int n = wv * 16 + q * 4 + j;
                    float th = fast_tanh(sa[nt][j] + bb);
                    if (n >= 62) th = 0.f;
                    xaH[n * 72 + nt * 16 + c16] = f32_to_f16u(th);
                }
            }
            #pragma unroll
            for (int nt = 4; nt < 6; ++nt) {
                const int o = (nt - 4) * 16 + c16;
                unsigned short zv[4];
                #pragma unroll
                for (int j = 0; j < 4; ++j) {
                    const int n = wv * 16 + q * 4 + j;
                    zv[j] = (n < 62) ? f32_to_f16u(sa[nt][j]) : (unsigned short)0;
                }
                *(ushort4*)(zB + o * 72 + wv * 16 + q * 4) =
                    make_ushort4(zv[0], zv[1], zv[2], zv[3]);
            }
        }
        __syncthreads();
    }

    // ---- maxpool3 + fc ----
    float a0 = 0.f, a1 = 0.f, a2 = 0.f;
    for (int t = tid; t < 620; t += 256) {
        const int n = t / 10, tt = t - (t / 10) * 10;
        const unsigned short* pr = xB + n * 40 + tt * 3;
        const float p = fmaxf(fmaxf(f16u_to_f32(pr[0]), f16u_to_f32(pr[1])),
                              f16u_to_f32(pr[2]));
        const float* fw = fcw + t * 3;
        a0 = fmaf(p, fw[0], a0);
        a1 = fmaf(p, fw[1], a1);
        a2 = fmaf(p, fw[2], a2);
    }
    #pragma unroll
    for (int off = 32; off; off >>= 1) {
        a0 += __shfl_down(a0, off);
        a1 += __shfl_down(a1, off);
        a2 += __shfl_down(a2, off);
    }
    float* red = degis;
    if (ln == 0) { red[wv * 3 + 0] = a0; red[wv * 3 + 1] = a1; red[wv * 3 + 2] = a2; }
    __syncthreads();
    if (tid == 0) {
        out[b * 3 + 0] = red[0] + red[3] + red[6] + red[9]  + fcb[0];
        out[b * 3 + 1] = red[1] + red[4] + red[7] + red[10] + fcb[1];
        out[b * 3 + 2] = red[2] + red[5] + red[8] + red[11] + fcb[2];
    }
}

// ============================== launcher ====================================
extern "C" void kernel_launch(void* const* d_in, const int* in_sizes, int n_in,
                              void* d_out, int out_size, void* d_ws, size_t ws_size,
                              hipStream_t stream) {
    const float* x     = (const float*)d_in[0];
    const float* convw = (const float*)d_in[1];
    const float* convb = (const float*)d_in[2];
    const float* bnw1  = (const float*)d_in[3];
    const float* bnb1  = (const float*)d_in[4];
    const float* gw1   = (const float*)d_in[5];
    const float* gb1   = (const float*)d_in[6];
    const float* bnw2  = (const float*)d_in[7];
    const float* bnb2  = (const float*)d_in[8];
    const float* gw2   = (const float*)d_in[9];
    const float* gb2   = (const float*)d_in[10];
    const float* bnw3  = (const float*)d_in[11];
    const float* bnb3  = (const float*)d_in[12];
    const float* gw3   = (const float*)d_in[13];
    const float* gb3   = (const float*)d_in[14];
    const float* fcw   = (const float*)d_in[15];
    const float* fcb   = (const float*)d_in[16];

    unsigned short* wp = (unsigned short*)d_ws;   // 200,704 B used

    prepack_kernel<<<392, 256, 0, stream>>>(bnw1, gw1, convw, bnw2, gw2,
                                            bnw3, gw3, wp);
    mega_kernel<<<1024, 256, 0, stream>>>(x, convb, wp, bnb1, gb1,
                                          bnb2, gb2, bnb3, gb3,
                                          fcw, fcb, (float*)d_out);
}

// Round 11
// 76.603 us; speedup vs baseline: 4.3158x; 1.0919x over previous
//
#include <hip/hip_runtime.h>
#include <math.h>

// ---------------------------------------------------------------------------
// B=1024. R11: R10 + transposed-S softmax (symmetry => row-per-lane, 2-round
// shfl) + conv job-loop unroll 2.
//   reshape fact: node n = (c*62+r)/32, feature f = ((c*62+r)%32)*15 + j
//   G1 K-order permuted: k' = pj*32 + s; W table padded to 16 kc (kc15 = 0)
//   conv via mfma_32x32x16_f16 (32 pos x 32 ch), 3 K-chunks
//   per pjg: conv 4 pooled cols -> Xcol[64][128] (XOR-swizzled) -> G1 kc block
//   tail: 3x SOGC all-fp16-MFMA; S computed TRANSPOSED (swap A/B operands) so
//   lane (c16,q) of wave wv owns full row r=wv*16+c16 -> softmax reductions
//   are 15 local ops + shfl_xor(16,32) only.
// ---------------------------------------------------------------------------

typedef _Float16 f16x8 __attribute__((ext_vector_type(8)));
typedef short    s16x8 __attribute__((ext_vector_type(8)));
typedef float    f32x4  __attribute__((ext_vector_type(4)));
typedef float    f32x16 __attribute__((ext_vector_type(16)));

__device__ __forceinline__ unsigned short f32_to_f16u(float f) {
    const _Float16 h = (_Float16)f;
    return __builtin_bit_cast(unsigned short, h);
}
__device__ __forceinline__ float f16u_to_f32(unsigned short u) {
    return (float)__builtin_bit_cast(_Float16, u);
}
__device__ __forceinline__ float fast_tanh(float v) {
    v = fminf(fmaxf(v, -15.f), 15.f);
    const float ex = __expf(2.f * v);
    return (ex - 1.f) / (ex + 1.f);
}

// ws layout (u16 units):
//   [0, 49152)        G1 W fp16, 16 kc (kc=15 zeros), B-frag order k'=pj*32+s
//   [92160, 93696)    conv W frags fp16 (32x32 shape, 3 chunks)
//   [94208, 100352)   stage2 (3072) + stage3 (3072) B-frag fp16 [col 96][k 32]

// ============================ prepack ======================================
__global__ __launch_bounds__(256) void prepack_kernel(
    const float* __restrict__ bnw1, const float* __restrict__ gw1,
    const float* __restrict__ cw,
    const float* __restrict__ bnw2, const float* __restrict__ gw2,
    const float* __restrict__ bnw3, const float* __restrict__ gw3,
    unsigned short* __restrict__ wp)
{
    const int idx = blockIdx.x * 256 + threadIdx.x;   // grid covers 100352
    if (idx < 49152) {
        const int kc = idx / 3072, r = idx - kc * 3072;
        const int q = r / 768, r2 = r - q * 768;
        const int col = r2 >> 3, j = r2 & 7;
        float w = 0.f;
        if (kc < 15) {
            const int s = q * 8 + j;
            const int ko = s * 15 + kc;
            w = (col < 64) ? bnw1[ko * 64 + col] : gw1[ko * 32 + (col - 64)];
        }
        wp[idx] = f32_to_f16u(w);
    } else if (idx >= 92160 && idx < 93696) {
        const int e = idx - 92160;
        const int c = e >> 9, l = (e >> 3) & 63, j = e & 7;
        const int ch = l & 31, dio = l >> 5;
        const int di = (c < 2) ? (2 * c + dio) : (4 + dio);
        const float w = (j < 5 && di < 5) ? cw[ch * 25 + di * 5 + j] : 0.f;
        wp[idx] = f32_to_f16u(w);
    } else if (idx >= 94208 && idx < 100352) {
        const int e2 = idx - 94208;
        const int s = e2 / 3072, r = e2 - s * 3072;
        const int col = r >> 5, k = r & 31;
        const float* bnw = s ? bnw3 : bnw2;
        const float* gw  = s ? gw3  : gw2;
        const float w = (col < 64) ? bnw[k * 64 + col] : gw[k * 32 + (col - 64)];
        wp[idx] = f32_to_f16u(w);
    }
}

// ============================= mega kernel =================================
__global__ __launch_bounds__(256, 4) void mega_kernel(
    const float* __restrict__ x,     // (B,66,64)
    const float* __restrict__ cb,    // (32,)
    const unsigned short* __restrict__ wp,
    const float* __restrict__ bnb1,  const float* __restrict__ gb1,
    const float* __restrict__ bnb2,  const float* __restrict__ gb2,
    const float* __restrict__ bnb3,  const float* __restrict__ gb3,
    const float* __restrict__ fcw,   const float* __restrict__ fcb,
    float* __restrict__ out)         // (B,3)
{
    // conv phase: xb @0 (10880 B, 68x80 f16) | Xcol @10880 (16384 B, 64x128)
    // tail phase (overlays): xaH u16@0 [64][72] | zB u16@4608 [32][72] |
    //   P u16@6912 [64][72] | xB u16@11520 [64][40] | degis @byte 28160
    __shared__ __align__(16) char lds[28416];
    unsigned short* xb   = (unsigned short*)lds;
    unsigned short* Xcol = (unsigned short*)(lds + 10880);
    unsigned short* xaH  = (unsigned short*)lds;
    unsigned short* zB   = xaH + 4608;
    unsigned short* P    = xaH + 6912;
    unsigned short* xB   = xaH + 11520;
    float* degis = (float*)(lds + 28160);

    const int b = blockIdx.x;
    const int tid = threadIdx.x;
    const int wv = tid >> 6, ln = tid & 63;

    // ---- phase A: x -> f16 LDS; zero pads ----
    const float4* xg = (const float4*)(x + (size_t)b * 4224);
    for (int idx = tid; idx < 1056; idx += 256) {
        const float4 v = xg[idx];
        const int row = idx >> 4, c4 = idx & 15;
        short4 s;
        s.x = (short)f32_to_f16u(v.x);
        s.y = (short)f32_to_f16u(v.y);
        s.z = (short)f32_to_f16u(v.z);
        s.w = (short)f32_to_f16u(v.w);
        *(short4*)(xb + row * 80 + c4 * 4) = s;
    }
    for (int idx = tid; idx < 544; idx += 256) {        // cols 64..79 zero (68 rows)
        const int row = idx >> 3, w = idx & 7;
        ((unsigned int*)(xb + row * 80 + 64))[w] = 0u;
    }
    if (tid < 64) {                                     // rows 66,67 cols 0..63
        const int row = 66 + (tid >> 5), w = tid & 31;
        ((unsigned int*)(xb + row * 80))[w] = 0u;
    }
    if (tid < 128)                                      // Xcol rows 62,63 zero
        ((unsigned int*)(Xcol + 62 * 128))[tid] = 0u;
    __syncthreads();

    // conv lane roles: ch=l&31, hi=l>>5; A: m=l&15, rp=(l>>4)&1, dio=l>>5
    const int m = ln & 15, rp = (ln >> 4) & 1, dio = ln >> 5;
    const int ch = ln & 31, hi = ln >> 5;
    f16x8 Wc[3];
    #pragma unroll
    for (int c = 0; c < 3; ++c)
        Wc[c] = *(const f16x8*)(wp + 92160 + c * 512 + ln * 8);
    const float cbv = cb[ch];
    const f32x16 z16 = {};          // persistent zero accumulator

    // G1 lane roles: rt = l&15, q = l>>4
    const int rt = ln & 15, q = ln >> 4;
    f32x4 acc[6];
    #pragma unroll
    for (int nt = 0; nt < 6; ++nt) acc[nt] = (f32x4){0.f, 0.f, 0.f, 0.f};

    for (int pjg = 0; pjg < 4; ++pjg) {
        const int j0 = pjg * 16;
        // ---- conv: 31 row-pairs, pooled cols pjg*4 + {0..3} -> Xcol ----
        #pragma unroll 2
        for (int p = wv; p < 31; p += 4) {
            const int r0 = 2 * p;
            const unsigned short* base = xb + (r0 + rp + dio) * 80 + j0 + m;
            f32x16 a32;
            #pragma unroll
            for (int c = 0; c < 3; ++c) {
                s16x8 A;
                A[0] = (short)base[c * 160 + 0];
                A[1] = (short)base[c * 160 + 1];
                A[2] = (short)base[c * 160 + 2];
                A[3] = (short)base[c * 160 + 3];
                A[4] = (short)base[c * 160 + 4];
                A[5] = A[0]; A[6] = A[1]; A[7] = A[2];   // kk>=5: W=0, finite vals
                const f16x8 Af = __builtin_bit_cast(f16x8, A);
                a32 = __builtin_amdgcn_mfma_f32_32x32x16_f16(
                          Af, Wc[c], (c == 0) ? z16 : a32, 0, 0, 0);
            }
            #pragma unroll
            for (int i = 0; i < 4; ++i) {
                const int t = 2 * i + hi;
                const int rpo = t >> 2, g = t & 3;
                float v = fmaxf(fmaxf(a32[4 * i], a32[4 * i + 1]),
                                fmaxf(a32[4 * i + 2], a32[4 * i + 3])) + cbv;
                v = fmaxf(v, 0.f);
                if (!(pjg == 3 && g == 3)) {
                    const int row = r0 + rpo;
                    const int tt = ch * 62 + row;        // n = tt/32, s = tt%32
                    const int n = tt >> 5, sf = tt & 31;
                    Xcol[n * 128 + ((g * 32 + sf) ^ ((n & 7) << 3))] =
                        f32_to_f16u(v);
                }
            }
        }
        __syncthreads();
        // ---- G1: kc = pjg*4 + g (kc=15 -> zero W); full unroll ----
        {
            const int row = wv * 16 + rt;
            #pragma unroll
            for (int g = 0; g < 4; ++g) {
                const int kc = pjg * 4 + g;
                const f16x8 A = *(const f16x8*)(
                    Xcol + row * 128 + (((g * 4 + q) ^ (row & 7)) << 3));
                #pragma unroll
                for (int nt = 0; nt < 6; ++nt) {
                    const f16x8 Bh = *(const f16x8*)(
                        wp + kc * 3072 + q * 768 + nt * 128 + rt * 8);
                    acc[nt] = __builtin_amdgcn_mfma_f32_16x16x32_f16(A, Bh, acc[nt], 0, 0, 0);
                }
            }
        }
        __syncthreads();
    }

    // ---- G1 epilogue -> tail LDS buffers (conv buffers dead) ----
    {
        const int rq = wv * 4 + q;
        #pragma unroll
        for (int nt = 0; nt < 4; ++nt) {
            const float bb = bnb1[nt * 16 + rt];
            #pragma unroll
            for (int j = 0; j < 4; ++j) {
                const int r = rq * 4 + j;
                float th = fast_tanh(acc[nt][j] + bb);
                if (r >= 62) th = 0.f;
                xaH[r * 72 + nt * 16 + rt] = f32_to_f16u(th);
            }
        }
        #pragma unroll
        for (int nt = 4; nt < 6; ++nt) {
            const int o = (nt - 4) * 16 + rt;
            unsigned short zv[4];
            #pragma unroll
            for (int j = 0; j < 4; ++j) {
                const int r = rq * 4 + j;
                zv[j] = (r < 62) ? f32_to_f16u(acc[nt][j]) : (unsigned short)0;
            }
            *(ushort4*)(zB + o * 72 + rq * 4) =
                make_ushort4(zv[0], zv[1], zv[2], zv[3]);
        }
    }
    __syncthreads();

    // ---- tail: 3x SOGC all-fp16-MFMA, transposed-S softmax ----
    const int c16 = ln & 15;
    const int r62 = wv * 16 + c16;          // this lane's S row
    const unsigned short* wstg = wp + 94208;

    #pragma unroll 1
    for (int st = 0; st < 3; ++st) {
        // S^T tiles: sacc[ct][j] = S[r62][ct*16 + q*4 + j]
        f32x4 sacc[4];
        #pragma unroll
        for (int ct = 0; ct < 4; ++ct) sacc[ct] = (f32x4){0.f, 0.f, 0.f, 0.f};
        const int arow = r62 * 72;
        #pragma unroll
        for (int kh = 0; kh < 2; ++kh) {
            const int chh = (kh * 4 + q) * 8;
            const f16x8 Bw = *(const f16x8*)(xaH + arow + chh);   // B: cols of wv-block
            #pragma unroll
            for (int ct = 0; ct < 4; ++ct) {
                const f16x8 Act = *(const f16x8*)(xaH + (ct * 16 + c16) * 72 + chh);
                sacc[ct] = __builtin_amdgcn_mfma_f32_16x16x32_f16(Act, Bw, sacc[ct], 0, 0, 0);
            }
        }
        // ---- row softmax, fully lane-local + 2 shfl rounds over q ----
        float mx = -1e30f;
        #pragma unroll
        for (int ct = 0; ct < 4; ++ct)
            #pragma unroll
            for (int j = 0; j < 4; ++j) mx = fmaxf(mx, sacc[ct][j]);
        mx = fmaxf(mx, __shfl_xor(mx, 16));
        mx = fmaxf(mx, __shfl_xor(mx, 32));
        float e[4][4];
        float sum = 0.f;
        #pragma unroll
        for (int ct = 0; ct < 4; ++ct)
            #pragma unroll
            for (int j = 0; j < 4; ++j) {
                float v = __expf(sacc[ct][j] - mx);
                if (ct == 3 && j >= 2 && q == 3) v = 0.f;    // cols 62,63
                e[ct][j] = v; sum += v;
            }
        sum += __shfl_xor(sum, 16);
        sum += __shfl_xor(sum, 32);
        const float inv = 1.f / sum;
        #pragma unroll
        for (int ct = 0; ct < 4; ++ct)
            #pragma unroll
            for (int j = 0; j < 4; ++j) e[ct][j] *= inv;
        // diag <- 1 at col == r62 (ct==wv, q==c16>>2, j==c16&3)
        if (r62 < 62 && q == (c16 >> 2)) {
            #pragma unroll
            for (int ct = 0; ct < 4; ++ct)
                if (ct == wv) {
                    #pragma unroll
                    for (int j = 0; j < 4; ++j)
                        if (j == (c16 & 3)) e[ct][j] = 1.f;
                }
        }
        // degree
        float dg = 0.f;
        #pragma unroll
        for (int ct = 0; ct < 4; ++ct)
            #pragma unroll
            for (int j = 0; j < 4; ++j) dg += e[ct][j];
        dg += __shfl_xor(dg, 16);
        dg += __shfl_xor(dg, 32);
        float dri = rsqrtf(fmaxf(dg, 1.f));
        if (r62 >= 62) dri = 1.f;
        if (q == 0) degis[r62] = dri;
        __syncthreads();
        // ---- P[r62][*] = dri * e * degis[col], 4x ushort4 ----
        {
            unsigned short* pr = P + r62 * 72 + q * 4;
            if (r62 < 62) {
                #pragma unroll
                for (int ct = 0; ct < 4; ++ct) {
                    const float4 dm = *(const float4*)(degis + ct * 16 + q * 4);
                    ushort4 pv;
                    pv.x = f32_to_f16u(e[ct][0] * dri * dm.x);
                    pv.y = f32_to_f16u(e[ct][1] * dri * dm.y);
                    pv.z = f32_to_f16u(e[ct][2] * dri * dm.z);
                    pv.w = f32_to_f16u(e[ct][3] * dri * dm.w);
                    *(ushort4*)(pr + ct * 16) = pv;
                }
            } else {
                #pragma unroll
                for (int ct = 0; ct < 4; ++ct)
                    *(ushort4*)(pr + ct * 16) = make_ushort4(0, 0, 0, 0);
            }
        }
        __syncthreads();
        // ---- O = P @ z + gb -> xB ----
        {
            f32x4 oa0 = {0.f, 0.f, 0.f, 0.f}, oa1 = {0.f, 0.f, 0.f, 0.f};
            #pragma unroll
            for (int kh = 0; kh < 2; ++kh) {
                const int chh = (kh * 4 + q) * 8;
                const f16x8 pa = *(const f16x8*)(P + (wv * 16 + c16) * 72 + chh);
                const f16x8 z0 = *(const f16x8*)(zB + c16 * 72 + chh);
                const f16x8 z1 = *(const f16x8*)(zB + (16 + c16) * 72 + chh);
                oa0 = __builtin_amdgcn_mfma_f32_16x16x32_f16(pa, z0, oa0, 0, 0, 0);
                oa1 = __builtin_amdgcn_mfma_f32_16x16x32_f16(pa, z1, oa1, 0, 0, 0);
            }
            const float* gbp = (st == 0) ? gb1 : (st == 1) ? gb2 : gb3;
            const float g0 = gbp[c16], g1 = gbp[16 + c16];
            #pragma unroll
            for (int j = 0; j < 4; ++j) {
                const int n = wv * 16 + q * 4 + j;
                unsigned short* xr = xB + n * 40 + c16;
                if (n < 62) {
                    xr[0]  = f32_to_f16u(oa0[j] + g0);
                    xr[16] = f32_to_f16u(oa1[j] + g1);
                } else { xr[0] = 0; xr[16] = 0; }
            }
        }
        __syncthreads();
        if (st == 2) break;

        // ---- stage gemms: xa' = tanh(x@bnw+bnb), z' = x@gw ----
        {
            const unsigned short* wsB = wstg + st * 3072;
            const float* bnbp = (st == 0) ? bnb2 : bnb3;
            const f16x8 ax = *(const f16x8*)(xB + (wv * 16 + c16) * 40 + q * 8);
            f32x4 sa[6];
            #pragma unroll
            for (int nt = 0; nt < 6; ++nt) {
                const f16x8 wb = *(const f16x8*)(wsB + (nt * 16 + c16) * 32 + q * 8);
                f32x4 zz = {0.f, 0.f, 0.f, 0.f};
                sa[nt] = __builtin_amdgcn_mfma_f32_16x16x32_f16(ax, wb, zz, 0, 0, 0);
            }
            #pragma unroll
            for (int nt = 0; nt < 4; ++nt) {
                const float bb = bnbp[nt * 16 + c16];
                #pragma unroll
                for (int j = 0; j < 4; ++j) {
                    const int n = wv * 16 + q * 4 + j;
                    float th = fast_tanh(sa[nt][j] + bb);
                    if (n >= 62) th = 0.f;
                    xaH[n * 72 + nt * 16 + c16] = f32_to_f16u(th);
                }
            }
            #pragma unroll
            for (int nt = 4; nt < 6; ++nt) {
                const int o = (nt - 4) * 16 + c16;
                unsigned short zv[4];
                #pragma unroll
                for (int j = 0; j < 4; ++j) {
                    const int n = wv * 16 + q * 4 + j;
                    zv[j] = (n < 62) ? f32_to_f16u(sa[nt][j]) : (unsigned short)0;
                }
                *(ushort4*)(zB + o * 72 + wv * 16 + q * 4) =
                    make_ushort4(zv[0], zv[1], zv[2], zv[3]);
            }
        }
        __syncthreads();
    }

    // ---- maxpool3 + fc ----
    float a0 = 0.f, a1 = 0.f, a2 = 0.f;
    for (int t = tid; t < 620; t += 256) {
        const int n = t / 10, tt = t - (t / 10) * 10;
        const unsigned short* pr = xB + n * 40 + tt * 3;
        const float p = fmaxf(fmaxf(f16u_to_f32(pr[0]), f16u_to_f32(pr[1])),
                              f16u_to_f32(pr[2]));
        const float* fw = fcw + t * 3;
        a0 = fmaf(p, fw[0], a0);
        a1 = fmaf(p, fw[1], a1);
        a2 = fmaf(p, fw[2], a2);
    }
    #pragma unroll
    for (int off = 32; off; off >>= 1) {
        a0 += __shfl_down(a0, off);
        a1 += __shfl_down(a1, off);
        a2 += __shfl_down(a2, off);
    }
    float* red = degis;
    if (ln == 0) { red[wv * 3 + 0] = a0; red[wv * 3 + 1] = a1; red[wv * 3 + 2] = a2; }
    __syncthreads();
    if (tid == 0) {
        out[b * 3 + 0] = red[0] + red[3] + red[6] + red[9]  + fcb[0];
        out[b * 3 + 1] = red[1] + red[4] + red[7] + red[10] + fcb[1];
        out[b * 3 + 2] = red[2] + red[5] + red[8] + red[11] + fcb[2];
    }
}

// ============================== launcher ====================================
extern "C" void kernel_launch(void* const* d_in, const int* in_sizes, int n_in,
                              void* d_out, int out_size, void* d_ws, size_t ws_size,
                              hipStream_t stream) {
    const float* x     = (const float*)d_in[0];
    const float* convw = (const float*)d_in[1];
    const float* convb = (const float*)d_in[2];
    const float* bnw1  = (const float*)d_in[3];
    const float* bnb1  = (const float*)d_in[4];
    const float* gw1   = (const float*)d_in[5];
    const float* gb1   = (const float*)d_in[6];
    const float* bnw2  = (const float*)d_in[7];
    const float* bnb2  = (const float*)d_in[8];
    const float* gw2   = (const float*)d_in[9];
    const float* gb2   = (const float*)d_in[10];
    const float* bnw3  = (const float*)d_in[11];
    const float* bnb3  = (const float*)d_in[12];
    const float* gw3   = (const float*)d_in[13];
    const float* gb3   = (const float*)d_in[14];
    const float* fcw   = (const float*)d_in[15];
    const float* fcb   = (const float*)d_in[16];

    unsigned short* wp = (unsigned short*)d_ws;   // 200,704 B used

    prepack_kernel<<<392, 256, 0, stream>>>(bnw1, gw1, convw, bnw2, gw2,
                                            bnw3, gw3, wp);
    mega_kernel<<<1024, 256, 0, stream>>>(x, convb, wp, bnb1, gb1,
                                          bnb2, gb2, bnb3, gb3,
                                          fcw, fcb, (float*)d_out);
}

// Round 12
// 74.915 us; speedup vs baseline: 4.4131x; 1.0225x over previous
//
#include <hip/hip_runtime.h>
#include <math.h>

// ---------------------------------------------------------------------------
// B=1024. R12: R11 + ILP round: G1 B-frag software pipeline (prefetch under
// conv), conv job unroll 4, tail weight/z prefetch. Dataflow identical to R11.
//   reshape fact: node n = (c*62+r)/32, feature f = ((c*62+r)%32)*15 + j
//   G1 K-order permuted: k' = pj*32 + s; W table padded to 16 kc (kc15 = 0)
//   conv via mfma_32x32x16_f16 (32 pos x 32 ch), 3 K-chunks
//   tail: 3x SOGC all-fp16-MFMA; transposed-S softmax (row-per-lane).
// ---------------------------------------------------------------------------

typedef _Float16 f16x8 __attribute__((ext_vector_type(8)));
typedef short    s16x8 __attribute__((ext_vector_type(8)));
typedef float    f32x4  __attribute__((ext_vector_type(4)));
typedef float    f32x16 __attribute__((ext_vector_type(16)));

__device__ __forceinline__ unsigned short f32_to_f16u(float f) {
    const _Float16 h = (_Float16)f;
    return __builtin_bit_cast(unsigned short, h);
}
__device__ __forceinline__ float f16u_to_f32(unsigned short u) {
    return (float)__builtin_bit_cast(_Float16, u);
}
__device__ __forceinline__ float fast_tanh(float v) {
    v = fminf(fmaxf(v, -15.f), 15.f);
    const float ex = __expf(2.f * v);
    return (ex - 1.f) / (ex + 1.f);
}

// ws layout (u16 units):
//   [0, 49152)        G1 W fp16, 16 kc (kc=15 zeros), B-frag order k'=pj*32+s
//   [92160, 93696)    conv W frags fp16 (32x32 shape, 3 chunks)
//   [94208, 100352)   stage2 (3072) + stage3 (3072) B-frag fp16 [col 96][k 32]

// ============================ prepack ======================================
__global__ __launch_bounds__(256) void prepack_kernel(
    const float* __restrict__ bnw1, const float* __restrict__ gw1,
    const float* __restrict__ cw,
    const float* __restrict__ bnw2, const float* __restrict__ gw2,
    const float* __restrict__ bnw3, const float* __restrict__ gw3,
    unsigned short* __restrict__ wp)
{
    const int idx = blockIdx.x * 256 + threadIdx.x;   // grid covers 100352
    if (idx < 49152) {
        const int kc = idx / 3072, r = idx - kc * 3072;
        const int q = r / 768, r2 = r - q * 768;
        const int col = r2 >> 3, j = r2 & 7;
        float w = 0.f;
        if (kc < 15) {
            const int s = q * 8 + j;
            const int ko = s * 15 + kc;
            w = (col < 64) ? bnw1[ko * 64 + col] : gw1[ko * 32 + (col - 64)];
        }
        wp[idx] = f32_to_f16u(w);
    } else if (idx >= 92160 && idx < 93696) {
        const int e = idx - 92160;
        const int c = e >> 9, l = (e >> 3) & 63, j = e & 7;
        const int ch = l & 31, dio = l >> 5;
        const int di = (c < 2) ? (2 * c + dio) : (4 + dio);
        const float w = (j < 5 && di < 5) ? cw[ch * 25 + di * 5 + j] : 0.f;
        wp[idx] = f32_to_f16u(w);
    } else if (idx >= 94208 && idx < 100352) {
        const int e2 = idx - 94208;
        const int s = e2 / 3072, r = e2 - s * 3072;
        const int col = r >> 5, k = r & 31;
        const float* bnw = s ? bnw3 : bnw2;
        const float* gw  = s ? gw3  : gw2;
        const float w = (col < 64) ? bnw[k * 64 + col] : gw[k * 32 + (col - 64)];
        wp[idx] = f32_to_f16u(w);
    }
}

// ============================= mega kernel =================================
__global__ __launch_bounds__(256, 4) void mega_kernel(
    const float* __restrict__ x,     // (B,66,64)
    const float* __restrict__ cb,    // (32,)
    const unsigned short* __restrict__ wp,
    const float* __restrict__ bnb1,  const float* __restrict__ gb1,
    const float* __restrict__ bnb2,  const float* __restrict__ gb2,
    const float* __restrict__ bnb3,  const float* __restrict__ gb3,
    const float* __restrict__ fcw,   const float* __restrict__ fcb,
    float* __restrict__ out)         // (B,3)
{
    // conv phase: xb @0 (10880 B, 68x80 f16) | Xcol @10880 (16384 B, 64x128)
    // tail phase (overlays): xaH u16@0 [64][72] | zB u16@4608 [32][72] |
    //   P u16@6912 [64][72] | xB u16@11520 [64][40] | degis @byte 28160
    __shared__ __align__(16) char lds[28416];
    unsigned short* xb   = (unsigned short*)lds;
    unsigned short* Xcol = (unsigned short*)(lds + 10880);
    unsigned short* xaH  = (unsigned short*)lds;
    unsigned short* zB   = xaH + 4608;
    unsigned short* P    = xaH + 6912;
    unsigned short* xB   = xaH + 11520;
    float* degis = (float*)(lds + 28160);

    const int b = blockIdx.x;
    const int tid = threadIdx.x;
    const int wv = tid >> 6, ln = tid & 63;

    // ---- phase A: x -> f16 LDS; zero pads ----
    const float4* xg = (const float4*)(x + (size_t)b * 4224);
    for (int idx = tid; idx < 1056; idx += 256) {
        const float4 v = xg[idx];
        const int row = idx >> 4, c4 = idx & 15;
        short4 s;
        s.x = (short)f32_to_f16u(v.x);
        s.y = (short)f32_to_f16u(v.y);
        s.z = (short)f32_to_f16u(v.z);
        s.w = (short)f32_to_f16u(v.w);
        *(short4*)(xb + row * 80 + c4 * 4) = s;
    }
    for (int idx = tid; idx < 544; idx += 256) {        // cols 64..79 zero (68 rows)
        const int row = idx >> 3, w = idx & 7;
        ((unsigned int*)(xb + row * 80 + 64))[w] = 0u;
    }
    if (tid < 64) {                                     // rows 66,67 cols 0..63
        const int row = 66 + (tid >> 5), w = tid & 31;
        ((unsigned int*)(xb + row * 80))[w] = 0u;
    }
    if (tid < 128)                                      // Xcol rows 62,63 zero
        ((unsigned int*)(Xcol + 62 * 128))[tid] = 0u;
    __syncthreads();

    // conv lane roles: ch=l&31, hi=l>>5; A: m=l&15, rp=(l>>4)&1, dio=l>>5
    const int m = ln & 15, rp = (ln >> 4) & 1, dio = ln >> 5;
    const int ch = ln & 31, hi = ln >> 5;
    f16x8 Wc[3];
    #pragma unroll
    for (int c = 0; c < 3; ++c)
        Wc[c] = *(const f16x8*)(wp + 92160 + c * 512 + ln * 8);
    const float cbv = cb[ch];
    const f32x16 z16 = {};          // persistent zero accumulator

    // G1 lane roles: rt = l&15, q = l>>4
    const int rt = ln & 15, q = ln >> 4;
    f32x4 acc[6];
    #pragma unroll
    for (int nt = 0; nt < 6; ++nt) acc[nt] = (f32x4){0.f, 0.f, 0.f, 0.f};

    for (int pjg = 0; pjg < 4; ++pjg) {
        const int j0 = pjg * 16;
        // prefetch g=0 G1 B-frags (independent of Xcol; hidden under conv)
        f16x8 Bp[6];
        {
            const unsigned short* wB = wp + (pjg * 4) * 3072 + q * 768 + rt * 8;
            #pragma unroll
            for (int nt = 0; nt < 6; ++nt) Bp[nt] = *(const f16x8*)(wB + nt * 128);
        }
        // ---- conv: 31 row-pairs, pooled cols pjg*4 + {0..3} -> Xcol ----
        #pragma unroll 4
        for (int p = wv; p < 31; p += 4) {
            const int r0 = 2 * p;
            const unsigned short* base = xb + (r0 + rp + dio) * 80 + j0 + m;
            f32x16 a32;
            #pragma unroll
            for (int c = 0; c < 3; ++c) {
                s16x8 A;
                A[0] = (short)base[c * 160 + 0];
                A[1] = (short)base[c * 160 + 1];
                A[2] = (short)base[c * 160 + 2];
                A[3] = (short)base[c * 160 + 3];
                A[4] = (short)base[c * 160 + 4];
                A[5] = A[0]; A[6] = A[1]; A[7] = A[2];   // kk>=5: W=0, finite vals
                const f16x8 Af = __builtin_bit_cast(f16x8, A);
                a32 = __builtin_amdgcn_mfma_f32_32x32x16_f16(
                          Af, Wc[c], (c == 0) ? z16 : a32, 0, 0, 0);
            }
            #pragma unroll
            for (int i = 0; i < 4; ++i) {
                const int t = 2 * i + hi;
                const int rpo = t >> 2, g = t & 3;
                float v = fmaxf(fmaxf(a32[4 * i], a32[4 * i + 1]),
                                fmaxf(a32[4 * i + 2], a32[4 * i + 3])) + cbv;
                v = fmaxf(v, 0.f);
                if (!(pjg == 3 && g == 3)) {
                    const int row = r0 + rpo;
                    const int tt = ch * 62 + row;        // n = tt/32, s = tt%32
                    const int n = tt >> 5, sf = tt & 31;
                    Xcol[n * 128 + ((g * 32 + sf) ^ ((n & 7) << 3))] =
                        f32_to_f16u(v);
                }
            }
        }
        __syncthreads();
        // ---- G1: kc = pjg*4 + g (kc=15 -> zero W); 1-deep B pipeline ----
        {
            const int row = wv * 16 + rt;
            #pragma unroll
            for (int g = 0; g < 4; ++g) {
                f16x8 Bn[6];
                #pragma unroll
                for (int nt = 0; nt < 6; ++nt)
                    Bn[nt] = (g < 3)
                        ? *(const f16x8*)(wp + (pjg * 4 + g + 1) * 3072
                                          + q * 768 + nt * 128 + rt * 8)
                        : Bp[nt];
                const f16x8 A = *(const f16x8*)(
                    Xcol + row * 128 + (((g * 4 + q) ^ (row & 7)) << 3));
                #pragma unroll
                for (int nt = 0; nt < 6; ++nt)
                    acc[nt] = __builtin_amdgcn_mfma_f32_16x16x32_f16(A, Bp[nt], acc[nt], 0, 0, 0);
                #pragma unroll
                for (int nt = 0; nt < 6; ++nt) Bp[nt] = Bn[nt];
            }
        }
        __syncthreads();
    }

    // ---- G1 epilogue -> tail LDS buffers (conv buffers dead) ----
    {
        const int rq = wv * 4 + q;
        #pragma unroll
        for (int nt = 0; nt < 4; ++nt) {
            const float bb = bnb1[nt * 16 + rt];
            #pragma unroll
            for (int j = 0; j < 4; ++j) {
                const int r = rq * 4 + j;
                float th = fast_tanh(acc[nt][j] + bb);
                if (r >= 62) th = 0.f;
                xaH[r * 72 + nt * 16 + rt] = f32_to_f16u(th);
            }
        }
        #pragma unroll
        for (int nt = 4; nt < 6; ++nt) {
            const int o = (nt - 4) * 16 + rt;
            unsigned short zv[4];
            #pragma unroll
            for (int j = 0; j < 4; ++j) {
                const int r = rq * 4 + j;
                zv[j] = (r < 62) ? f32_to_f16u(acc[nt][j]) : (unsigned short)0;
            }
            *(ushort4*)(zB + o * 72 + rq * 4) =
                make_ushort4(zv[0], zv[1], zv[2], zv[3]);
        }
    }
    __syncthreads();

    // ---- tail: 3x SOGC all-fp16-MFMA, transposed-S softmax ----
    const int c16 = ln & 15;
    const int r62 = wv * 16 + c16;          // this lane's S row
    const unsigned short* wstg = wp + 94208;

    #pragma unroll 1
    for (int st = 0; st < 3; ++st) {
        // zB is stable this whole stage: hoist PV z-frag reads to stage top
        f16x8 zPre[2][2];
        #pragma unroll
        for (int kh = 0; kh < 2; ++kh) {
            const int chh = (kh * 4 + q) * 8;
            zPre[kh][0] = *(const f16x8*)(zB + c16 * 72 + chh);
            zPre[kh][1] = *(const f16x8*)(zB + (16 + c16) * 72 + chh);
        }
        // S^T tiles: sacc[ct][j] = S[r62][ct*16 + q*4 + j]
        f32x4 sacc[4];
        #pragma unroll
        for (int ct = 0; ct < 4; ++ct) sacc[ct] = (f32x4){0.f, 0.f, 0.f, 0.f};
        const int arow = r62 * 72;
        #pragma unroll
        for (int kh = 0; kh < 2; ++kh) {
            const int chh = (kh * 4 + q) * 8;
            const f16x8 Bw = *(const f16x8*)(xaH + arow + chh);   // B: cols of wv-block
            #pragma unroll
            for (int ct = 0; ct < 4; ++ct) {
                const f16x8 Act = *(const f16x8*)(xaH + (ct * 16 + c16) * 72 + chh);
                sacc[ct] = __builtin_amdgcn_mfma_f32_16x16x32_f16(Act, Bw, sacc[ct], 0, 0, 0);
            }
        }
        // prefetch next-stage gemm weights (global; hidden under softmax)
        f16x8 wbPre[6];
        if (st < 2) {
            const unsigned short* wsB = wstg + st * 3072;
            #pragma unroll
            for (int nt = 0; nt < 6; ++nt)
                wbPre[nt] = *(const f16x8*)(wsB + (nt * 16 + c16) * 32 + q * 8);
        }
        // ---- row softmax, fully lane-local + 2 shfl rounds over q ----
        float mx = -1e30f;
        #pragma unroll
        for (int ct = 0; ct < 4; ++ct)
            #pragma unroll
            for (int j = 0; j < 4; ++j) mx = fmaxf(mx, sacc[ct][j]);
        mx = fmaxf(mx, __shfl_xor(mx, 16));
        mx = fmaxf(mx, __shfl_xor(mx, 32));
        float e[4][4];
        float sum = 0.f;
        #pragma unroll
        for (int ct = 0; ct < 4; ++ct)
            #pragma unroll
            for (int j = 0; j < 4; ++j) {
                float v = __expf(sacc[ct][j] - mx);
                if (ct == 3 && j >= 2 && q == 3) v = 0.f;    // cols 62,63
                e[ct][j] = v; sum += v;
            }
        sum += __shfl_xor(sum, 16);
        sum += __shfl_xor(sum, 32);
        const float inv = 1.f / sum;
        #pragma unroll
        for (int ct = 0; ct < 4; ++ct)
            #pragma unroll
            for (int j = 0; j < 4; ++j) e[ct][j] *= inv;
        // diag <- 1 at col == r62 (ct==wv, q==c16>>2, j==c16&3)
        if (r62 < 62 && q == (c16 >> 2)) {
            #pragma unroll
            for (int ct = 0; ct < 4; ++ct)
                if (ct == wv) {
                    #pragma unroll
                    for (int j = 0; j < 4; ++j)
                        if (j == (c16 & 3)) e[ct][j] = 1.f;
                }
        }
        // degree
        float dg = 0.f;
        #pragma unroll
        for (int ct = 0; ct < 4; ++ct)
            #pragma unroll
            for (int j = 0; j < 4; ++j) dg += e[ct][j];
        dg += __shfl_xor(dg, 16);
        dg += __shfl_xor(dg, 32);
        float dri = rsqrtf(fmaxf(dg, 1.f));
        if (r62 >= 62) dri = 1.f;
        if (q == 0) degis[r62] = dri;
        __syncthreads();
        // ---- P[r62][*] = dri * e * degis[col], 4x ushort4 ----
        {
            unsigned short* pr = P + r62 * 72 + q * 4;
            if (r62 < 62) {
                #pragma unroll
                for (int ct = 0; ct < 4; ++ct) {
                    const float4 dm = *(const float4*)(degis + ct * 16 + q * 4);
                    ushort4 pv;
                    pv.x = f32_to_f16u(e[ct][0] * dri * dm.x);
                    pv.y = f32_to_f16u(e[ct][1] * dri * dm.y);
                    pv.z = f32_to_f16u(e[ct][2] * dri * dm.z);
                    pv.w = f32_to_f16u(e[ct][3] * dri * dm.w);
                    *(ushort4*)(pr + ct * 16) = pv;
                }
            } else {
                #pragma unroll
                for (int ct = 0; ct < 4; ++ct)
                    *(ushort4*)(pr + ct * 16) = make_ushort4(0, 0, 0, 0);
            }
        }
        __syncthreads();
        // ---- O = P @ z + gb -> xB ----
        {
            f32x4 oa0 = {0.f, 0.f, 0.f, 0.f}, oa1 = {0.f, 0.f, 0.f, 0.f};
            #pragma unroll
            for (int kh = 0; kh < 2; ++kh) {
                const int chh = (kh * 4 + q) * 8;
                const f16x8 pa = *(const f16x8*)(P + (wv * 16 + c16) * 72 + chh);
                oa0 = __builtin_amdgcn_mfma_f32_16x16x32_f16(pa, zPre[kh][0], oa0, 0, 0, 0);
                oa1 = __builtin_amdgcn_mfma_f32_16x16x32_f16(pa, zPre[kh][1], oa1, 0, 0, 0);
            }
            const float* gbp = (st == 0) ? gb1 : (st == 1) ? gb2 : gb3;
            const float g0 = gbp[c16], g1 = gbp[16 + c16];
            #pragma unroll
            for (int j = 0; j < 4; ++j) {
                const int n = wv * 16 + q * 4 + j;
                unsigned short* xr = xB + n * 40 + c16;
                if (n < 62) {
                    xr[0]  = f32_to_f16u(oa0[j] + g0);
                    xr[16] = f32_to_f16u(oa1[j] + g1);
                } else { xr[0] = 0; xr[16] = 0; }
            }
        }
        __syncthreads();
        if (st == 2) break;

        // ---- stage gemms: xa' = tanh(x@bnw+bnb), z' = x@gw ----
        {
            const float* bnbp = (st == 0) ? bnb2 : bnb3;
            const f16x8 ax = *(const f16x8*)(xB + (wv * 16 + c16) * 40 + q * 8);
            f32x4 sa[6];
            #pragma unroll
            for (int nt = 0; nt < 6; ++nt) {
                f32x4 zz = {0.f, 0.f, 0.f, 0.f};
                sa[nt] = __builtin_amdgcn_mfma_f32_16x16x32_f16(ax, wbPre[nt], zz, 0, 0, 0);
            }
            #pragma unroll
            for (int nt = 0; nt < 4; ++nt) {
                const float bb = bnbp[nt * 16 + c16];
                #pragma unroll
                for (int j = 0; j < 4; ++j) {
                    const int n = wv * 16 + q * 4 + j;
                    float th = fast_tanh(sa[nt][j] + bb);
                    if (n >= 62) th = 0.f;
                    xaH[n * 72 + nt * 16 + c16] = f32_to_f16u(th);
                }
            }
            #pragma unroll
            for (int nt = 4; nt < 6; ++nt) {
                const int o = (nt - 4) * 16 + c16;
                unsigned short zv[4];
                #pragma unroll
                for (int j = 0; j < 4; ++j) {
                    const int n = wv * 16 + q * 4 + j;
                    zv[j] = (n < 62) ? f32_to_f16u(sa[nt][j]) : (unsigned short)0;
                }
                *(ushort4*)(zB + o * 72 + wv * 16 + q * 4) =
                    make_ushort4(zv[0], zv[1], zv[2], zv[3]);
            }
        }
        __syncthreads();
    }

    // ---- maxpool3 + fc ----
    float a0 = 0.f, a1 = 0.f, a2 = 0.f;
    for (int t = tid; t < 620; t += 256) {
        const int n = t / 10, tt = t - (t / 10) * 10;
        const unsigned short* pr = xB + n * 40 + tt * 3;
        const float p = fmaxf(fmaxf(f16u_to_f32(pr[0]), f16u_to_f32(pr[1])),
                              f16u_to_f32(pr[2]));
        const float* fw = fcw + t * 3;
        a0 = fmaf(p, fw[0], a0);
        a1 = fmaf(p, fw[1], a1);
        a2 = fmaf(p, fw[2], a2);
    }
    #pragma unroll
    for (int off = 32; off; off >>= 1) {
        a0 += __shfl_down(a0, off);
        a1 += __shfl_down(a1, off);
        a2 += __shfl_down(a2, off);
    }
    float* red = degis;
    if (ln == 0) { red[wv * 3 + 0] = a0; red[wv * 3 + 1] = a1; red[wv * 3 + 2] = a2; }
    __syncthreads();
    if (tid == 0) {
        out[b * 3 + 0] = red[0] + red[3] + red[6] + red[9]  + fcb[0];
        out[b * 3 + 1] = red[1] + red[4] + red[7] + red[10] + fcb[1];
        out[b * 3 + 2] = red[2] + red[5] + red[8] + red[11] + fcb[2];
    }
}

// ============================== launcher ====================================
extern "C" void kernel_launch(void* const* d_in, const int* in_sizes, int n_in,
                              void* d_out, int out_size, void* d_ws, size_t ws_size,
                              hipStream_t stream) {
    const float* x     = (const float*)d_in[0];
    const float* convw = (const float*)d_in[1];
    const float* convb = (const float*)d_in[2];
    const float* bnw1  = (const float*)d_in[3];
    const float* bnb1  = (const float*)d_in[4];
    const float* gw1   = (const float*)d_in[5];
    const float* gb1   = (const float*)d_in[6];
    const float* bnw2  = (const float*)d_in[7];
    const float* bnb2  = (const float*)d_in[8];
    const float* gw2   = (const float*)d_in[9];
    const float* gb2   = (const float*)d_in[10];
    const float* bnw3  = (const float*)d_in[11];
    const float* bnb3  = (const float*)d_in[12];
    const float* gw3   = (const float*)d_in[13];
    const float* gb3   = (const float*)d_in[14];
    const float* fcw   = (const float*)d_in[15];
    const float* fcb   = (const float*)d_in[16];

    unsigned short* wp = (unsigned short*)d_ws;   // 200,704 B used

    prepack_kernel<<<392, 256, 0, stream>>>(bnw1, gw1, convw, bnw2, gw2,
                                            bnw3, gw3, wp);
    mega_kernel<<<1024, 256, 0, stream>>>(x, convb, wp, bnb1, gb1,
                                          bnb2, gb2, bnb3, gb3,
                                          fcw, fcb, (float*)d_out);
}

// Round 13
// 73.525 us; speedup vs baseline: 4.4965x; 1.0189x over previous
//
#include <hip/hip_runtime.h>
#include <math.h>

// ---------------------------------------------------------------------------
// B=1024. R13 = R12 with conv im2col A-frag loaded as ONE (misaligned)
// f16x8 LDS read per chunk: taps are contiguous; elems 5..7 are finite
// x values multiplied by exactly-zero prepacked weights. 15 scalar
// ds_read_u16/job -> 3 ds_read_b128/job.
//   reshape fact: node n = (c*62+r)/32, feature f = ((c*62+r)%32)*15 + j
//   G1 K-order permuted: k' = pj*32 + s; W table padded to 16 kc (kc15 = 0)
//   conv via mfma_32x32x16_f16 (32 pos x 32 ch), 3 K-chunks
//   tail: 3x SOGC all-fp16-MFMA; transposed-S softmax (row-per-lane).
// ---------------------------------------------------------------------------

typedef _Float16 f16x8 __attribute__((ext_vector_type(8)));
typedef float    f32x4  __attribute__((ext_vector_type(4)));
typedef float    f32x16 __attribute__((ext_vector_type(16)));

__device__ __forceinline__ unsigned short f32_to_f16u(float f) {
    const _Float16 h = (_Float16)f;
    return __builtin_bit_cast(unsigned short, h);
}
__device__ __forceinline__ float f16u_to_f32(unsigned short u) {
    return (float)__builtin_bit_cast(_Float16, u);
}
__device__ __forceinline__ float fast_tanh(float v) {
    v = fminf(fmaxf(v, -15.f), 15.f);
    const float ex = __expf(2.f * v);
    return (ex - 1.f) / (ex + 1.f);
}

// ws layout (u16 units):
//   [0, 49152)        G1 W fp16, 16 kc (kc=15 zeros), B-frag order k'=pj*32+s
//   [92160, 93696)    conv W frags fp16 (32x32 shape, 3 chunks)
//   [94208, 100352)   stage2 (3072) + stage3 (3072) B-frag fp16 [col 96][k 32]

// ============================ prepack ======================================
__global__ __launch_bounds__(256) void prepack_kernel(
    const float* __restrict__ bnw1, const float* __restrict__ gw1,
    const float* __restrict__ cw,
    const float* __restrict__ bnw2, const float* __restrict__ gw2,
    const float* __restrict__ bnw3, const float* __restrict__ gw3,
    unsigned short* __restrict__ wp)
{
    const int idx = blockIdx.x * 256 + threadIdx.x;   // grid covers 100352
    if (idx < 49152) {
        const int kc = idx / 3072, r = idx - kc * 3072;
        const int q = r / 768, r2 = r - q * 768;
        const int col = r2 >> 3, j = r2 & 7;
        float w = 0.f;
        if (kc < 15) {
            const int s = q * 8 + j;
            const int ko = s * 15 + kc;
            w = (col < 64) ? bnw1[ko * 64 + col] : gw1[ko * 32 + (col - 64)];
        }
        wp[idx] = f32_to_f16u(w);
    } else if (idx >= 92160 && idx < 93696) {
        const int e = idx - 92160;
        const int c = e >> 9, l = (e >> 3) & 63, j = e & 7;
        const int ch = l & 31, dio = l >> 5;
        const int di = (c < 2) ? (2 * c + dio) : (4 + dio);
        const float w = (j < 5 && di < 5) ? cw[ch * 25 + di * 5 + j] : 0.f;
        wp[idx] = f32_to_f16u(w);
    } else if (idx >= 94208 && idx < 100352) {
        const int e2 = idx - 94208;
        const int s = e2 / 3072, r = e2 - s * 3072;
        const int col = r >> 5, k = r & 31;
        const float* bnw = s ? bnw3 : bnw2;
        const float* gw  = s ? gw3  : gw2;
        const float w = (col < 64) ? bnw[k * 64 + col] : gw[k * 32 + (col - 64)];
        wp[idx] = f32_to_f16u(w);
    }
}

// ============================= mega kernel =================================
__global__ __launch_bounds__(256, 4) void mega_kernel(
    const float* __restrict__ x,     // (B,66,64)
    const float* __restrict__ cb,    // (32,)
    const unsigned short* __restrict__ wp,
    const float* __restrict__ bnb1,  const float* __restrict__ gb1,
    const float* __restrict__ bnb2,  const float* __restrict__ gb2,
    const float* __restrict__ bnb3,  const float* __restrict__ gb3,
    const float* __restrict__ fcw,   const float* __restrict__ fcb,
    float* __restrict__ out)         // (B,3)
{
    // conv phase: xb @0 (10880 B, 68x80 f16) | Xcol @10880 (16384 B, 64x128)
    // tail phase (overlays): xaH u16@0 [64][72] | zB u16@4608 [32][72] |
    //   P u16@6912 [64][72] | xB u16@11520 [64][40] | degis @byte 28160
    __shared__ __align__(16) char lds[28416];
    unsigned short* xb   = (unsigned short*)lds;
    unsigned short* Xcol = (unsigned short*)(lds + 10880);
    unsigned short* xaH  = (unsigned short*)lds;
    unsigned short* zB   = xaH + 4608;
    unsigned short* P    = xaH + 6912;
    unsigned short* xB   = xaH + 11520;
    float* degis = (float*)(lds + 28160);

    const int b = blockIdx.x;
    const int tid = threadIdx.x;
    const int wv = tid >> 6, ln = tid & 63;

    // ---- phase A: x -> f16 LDS; zero pads ----
    const float4* xg = (const float4*)(x + (size_t)b * 4224);
    for (int idx = tid; idx < 1056; idx += 256) {
        const float4 v = xg[idx];
        const int row = idx >> 4, c4 = idx & 15;
        short4 s;
        s.x = (short)f32_to_f16u(v.x);
        s.y = (short)f32_to_f16u(v.y);
        s.z = (short)f32_to_f16u(v.z);
        s.w = (short)f32_to_f16u(v.w);
        *(short4*)(xb + row * 80 + c4 * 4) = s;
    }
    for (int idx = tid; idx < 544; idx += 256) {        // cols 64..79 zero (68 rows)
        const int row = idx >> 3, w = idx & 7;
        ((unsigned int*)(xb + row * 80 + 64))[w] = 0u;
    }
    if (tid < 64) {                                     // rows 66,67 cols 0..63
        const int row = 66 + (tid >> 5), w = tid & 31;
        ((unsigned int*)(xb + row * 80))[w] = 0u;
    }
    if (tid < 128)                                      // Xcol rows 62,63 zero
        ((unsigned int*)(Xcol + 62 * 128))[tid] = 0u;
    __syncthreads();

    // conv lane roles: ch=l&31, hi=l>>5; A: m=l&15, rp=(l>>4)&1, dio=l>>5
    const int m = ln & 15, rp = (ln >> 4) & 1, dio = ln >> 5;
    const int ch = ln & 31, hi = ln >> 5;
    f16x8 Wc[3];
    #pragma unroll
    for (int c = 0; c < 3; ++c)
        Wc[c] = *(const f16x8*)(wp + 92160 + c * 512 + ln * 8);
    const float cbv = cb[ch];
    const f32x16 z16 = {};          // persistent zero accumulator

    // G1 lane roles: rt = l&15, q = l>>4
    const int rt = ln & 15, q = ln >> 4;
    f32x4 acc[6];
    #pragma unroll
    for (int nt = 0; nt < 6; ++nt) acc[nt] = (f32x4){0.f, 0.f, 0.f, 0.f};

    for (int pjg = 0; pjg < 4; ++pjg) {
        const int j0 = pjg * 16;
        // prefetch g=0 G1 B-frags (independent of Xcol; hidden under conv)
        f16x8 Bp[6];
        {
            const unsigned short* wB = wp + (pjg * 4) * 3072 + q * 768 + rt * 8;
            #pragma unroll
            for (int nt = 0; nt < 6; ++nt) Bp[nt] = *(const f16x8*)(wB + nt * 128);
        }
        // ---- conv: 31 row-pairs, pooled cols pjg*4 + {0..3} -> Xcol ----
        #pragma unroll 4
        for (int p = wv; p < 31; p += 4) {
            const int r0 = 2 * p;
            const unsigned short* base = xb + (r0 + rp + dio) * 80 + j0 + m;
            f32x16 a32;
            #pragma unroll
            for (int c = 0; c < 3; ++c) {
                // taps 0..4 contiguous; elems 5..7 finite x values * zero W.
                // misaligned (2B) LDS b128 read — gfx950 unaligned DS access.
                const f16x8 Af = *(const f16x8*)(base + c * 160);
                a32 = __builtin_amdgcn_mfma_f32_32x32x16_f16(
                          Af, Wc[c], (c == 0) ? z16 : a32, 0, 0, 0);
            }
            #pragma unroll
            for (int i = 0; i < 4; ++i) {
                const int t = 2 * i + hi;
                const int rpo = t >> 2, g = t & 3;
                float v = fmaxf(fmaxf(a32[4 * i], a32[4 * i + 1]),
                                fmaxf(a32[4 * i + 2], a32[4 * i + 3])) + cbv;
                v = fmaxf(v, 0.f);
                if (!(pjg == 3 && g == 3)) {
                    const int row = r0 + rpo;
                    const int tt = ch * 62 + row;        // n = tt/32, s = tt%32
                    const int n = tt >> 5, sf = tt & 31;
                    Xcol[n * 128 + ((g * 32 + sf) ^ ((n & 7) << 3))] =
                        f32_to_f16u(v);
                }
            }
        }
        __syncthreads();
        // ---- G1: kc = pjg*4 + g (kc=15 -> zero W); 1-deep B pipeline ----
        {
            const int row = wv * 16 + rt;
            #pragma unroll
            for (int g = 0; g < 4; ++g) {
                f16x8 Bn[6];
                #pragma unroll
                for (int nt = 0; nt < 6; ++nt)
                    Bn[nt] = (g < 3)
                        ? *(const f16x8*)(wp + (pjg * 4 + g + 1) * 3072
                                          + q * 768 + nt * 128 + rt * 8)
                        : Bp[nt];
                const f16x8 A = *(const f16x8*)(
                    Xcol + row * 128 + (((g * 4 + q) ^ (row & 7)) << 3));
                #pragma unroll
                for (int nt = 0; nt < 6; ++nt)
                    acc[nt] = __builtin_amdgcn_mfma_f32_16x16x32_f16(A, Bp[nt], acc[nt], 0, 0, 0);
                #pragma unroll
                for (int nt = 0; nt < 6; ++nt) Bp[nt] = Bn[nt];
            }
        }
        __syncthreads();
    }

    // ---- G1 epilogue -> tail LDS buffers (conv buffers dead) ----
    {
        const int rq = wv * 4 + q;
        #pragma unroll
        for (int nt = 0; nt < 4; ++nt) {
            const float bb = bnb1[nt * 16 + rt];
            #pragma unroll
            for (int j = 0; j < 4; ++j) {
                const int r = rq * 4 + j;
                float th = fast_tanh(acc[nt][j] + bb);
                if (r >= 62) th = 0.f;
                xaH[r * 72 + nt * 16 + rt] = f32_to_f16u(th);
            }
        }
        #pragma unroll
        for (int nt = 4; nt < 6; ++nt) {
            const int o = (nt - 4) * 16 + rt;
            unsigned short zv[4];
            #pragma unroll
            for (int j = 0; j < 4; ++j) {
                const int r = rq * 4 + j;
                zv[j] = (r < 62) ? f32_to_f16u(acc[nt][j]) : (unsigned short)0;
            }
            *(ushort4*)(zB + o * 72 + rq * 4) =
                make_ushort4(zv[0], zv[1], zv[2], zv[3]);
        }
    }
    __syncthreads();

    // ---- tail: 3x SOGC all-fp16-MFMA, transposed-S softmax ----
    const int c16 = ln & 15;
    const int r62 = wv * 16 + c16;          // this lane's S row
    const unsigned short* wstg = wp + 94208;

    #pragma unroll 1
    for (int st = 0; st < 3; ++st) {
        // zB is stable this whole stage: hoist PV z-frag reads to stage top
        f16x8 zPre[2][2];
        #pragma unroll
        for (int kh = 0; kh < 2; ++kh) {
            const int chh = (kh * 4 + q) * 8;
            zPre[kh][0] = *(const f16x8*)(zB + c16 * 72 + chh);
            zPre[kh][1] = *(const f16x8*)(zB + (16 + c16) * 72 + chh);
        }
        // S^T tiles: sacc[ct][j] = S[r62][ct*16 + q*4 + j]
        f32x4 sacc[4];
        #pragma unroll
        for (int ct = 0; ct < 4; ++ct) sacc[ct] = (f32x4){0.f, 0.f, 0.f, 0.f};
        const int arow = r62 * 72;
        #pragma unroll
        for (int kh = 0; kh < 2; ++kh) {
            const int chh = (kh * 4 + q) * 8;
            const f16x8 Bw = *(const f16x8*)(xaH + arow + chh);   // B: cols of wv-block
            #pragma unroll
            for (int ct = 0; ct < 4; ++ct) {
                const f16x8 Act = *(const f16x8*)(xaH + (ct * 16 + c16) * 72 + chh);
                sacc[ct] = __builtin_amdgcn_mfma_f32_16x16x32_f16(Act, Bw, sacc[ct], 0, 0, 0);
            }
        }
        // prefetch next-stage gemm weights (global; hidden under softmax)
        f16x8 wbPre[6];
        if (st < 2) {
            const unsigned short* wsB = wstg + st * 3072;
            #pragma unroll
            for (int nt = 0; nt < 6; ++nt)
                wbPre[nt] = *(const f16x8*)(wsB + (nt * 16 + c16) * 32 + q * 8);
        }
        // ---- row softmax, fully lane-local + 2 shfl rounds over q ----
        float mx = -1e30f;
        #pragma unroll
        for (int ct = 0; ct < 4; ++ct)
            #pragma unroll
            for (int j = 0; j < 4; ++j) mx = fmaxf(mx, sacc[ct][j]);
        mx = fmaxf(mx, __shfl_xor(mx, 16));
        mx = fmaxf(mx, __shfl_xor(mx, 32));
        float e[4][4];
        float sum = 0.f;
        #pragma unroll
        for (int ct = 0; ct < 4; ++ct)
            #pragma unroll
            for (int j = 0; j < 4; ++j) {
                float v = __expf(sacc[ct][j] - mx);
                if (ct == 3 && j >= 2 && q == 3) v = 0.f;    // cols 62,63
                e[ct][j] = v; sum += v;
            }
        sum += __shfl_xor(sum, 16);
        sum += __shfl_xor(sum, 32);
        const float inv = 1.f / sum;
        #pragma unroll
        for (int ct = 0; ct < 4; ++ct)
            #pragma unroll
            for (int j = 0; j < 4; ++j) e[ct][j] *= inv;
        // diag <- 1 at col == r62 (ct==wv, q==c16>>2, j==c16&3)
        if (r62 < 62 && q == (c16 >> 2)) {
            #pragma unroll
            for (int ct = 0; ct < 4; ++ct)
                if (ct == wv) {
                    #pragma unroll
                    for (int j = 0; j < 4; ++j)
                        if (j == (c16 & 3)) e[ct][j] = 1.f;
                }
        }
        // degree
        float dg = 0.f;
        #pragma unroll
        for (int ct = 0; ct < 4; ++ct)
            #pragma unroll
            for (int j = 0; j < 4; ++j) dg += e[ct][j];
        dg += __shfl_xor(dg, 16);
        dg += __shfl_xor(dg, 32);
        float dri = rsqrtf(fmaxf(dg, 1.f));
        if (r62 >= 62) dri = 1.f;
        if (q == 0) degis[r62] = dri;
        __syncthreads();
        // ---- P[r62][*] = dri * e * degis[col], 4x ushort4 ----
        {
            unsigned short* pr = P + r62 * 72 + q * 4;
            if (r62 < 62) {
                #pragma unroll
                for (int ct = 0; ct < 4; ++ct) {
                    const float4 dm = *(const float4*)(degis + ct * 16 + q * 4);
                    ushort4 pv;
                    pv.x = f32_to_f16u(e[ct][0] * dri * dm.x);
                    pv.y = f32_to_f16u(e[ct][1] * dri * dm.y);
                    pv.z = f32_to_f16u(e[ct][2] * dri * dm.z);
                    pv.w = f32_to_f16u(e[ct][3] * dri * dm.w);
                    *(ushort4*)(pr + ct * 16) = pv;
                }
            } else {
                #pragma unroll
                for (int ct = 0; ct < 4; ++ct)
                    *(ushort4*)(pr + ct * 16) = make_ushort4(0, 0, 0, 0);
            }
        }
        __syncthreads();
        // ---- O = P @ z + gb -> xB ----
        {
            f32x4 oa0 = {0.f, 0.f, 0.f, 0.f}, oa1 = {0.f, 0.f, 0.f, 0.f};
            #pragma unroll
            for (int kh = 0; kh < 2; ++kh) {
                const int chh = (kh * 4 + q) * 8;
                const f16x8 pa = *(const f16x8*)(P + (wv * 16 + c16) * 72 + chh);
                oa0 = __builtin_amdgcn_mfma_f32_16x16x32_f16(pa, zPre[kh][0], oa0, 0, 0, 0);
                oa1 = __builtin_amdgcn_mfma_f32_16x16x32_f16(pa, zPre[kh][1], oa1, 0, 0, 0);
            }
            const float* gbp = (st == 0) ? gb1 : (st == 1) ? gb2 : gb3;
            const float g0 = gbp[c16], g1 = gbp[16 + c16];
            #pragma unroll
            for (int j = 0; j < 4; ++j) {
                const int n = wv * 16 + q * 4 + j;
                unsigned short* xr = xB + n * 40 + c16;
                if (n < 62) {
                    xr[0]  = f32_to_f16u(oa0[j] + g0);
                    xr[16] = f32_to_f16u(oa1[j] + g1);
                } else { xr[0] = 0; xr[16] = 0; }
            }
        }
        __syncthreads();
        if (st == 2) break;

        // ---- stage gemms: xa' = tanh(x@bnw+bnb), z' = x@gw ----
        {
            const float* bnbp = (st == 0) ? bnb2 : bnb3;
            const f16x8 ax = *(const f16x8*)(xB + (wv * 16 + c16) * 40 + q * 8);
            f32x4 sa[6];
            #pragma unroll
            for (int nt = 0; nt < 6; ++nt) {
                f32x4 zz = {0.f, 0.f, 0.f, 0.f};
                sa[nt] = __builtin_amdgcn_mfma_f32_16x16x32_f16(ax, wbPre[nt], zz, 0, 0, 0);
            }
            #pragma unroll
            for (int nt = 0; nt < 4; ++nt) {
                const float bb = bnbp[nt * 16 + c16];
                #pragma unroll
                for (int j = 0; j < 4; ++j) {
                    const int n = wv * 16 + q * 4 + j;
                    float th = fast_tanh(sa[nt][j] + bb);
                    if (n >= 62) th = 0.f;
                    xaH[n * 72 + nt * 16 + c16] = f32_to_f16u(th);
                }
            }
            #pragma unroll
            for (int nt = 4; nt < 6; ++nt) {
                const int o = (nt - 4) * 16 + c16;
                unsigned short zv[4];
                #pragma unroll
                for (int j = 0; j < 4; ++j) {
                    const int n = wv * 16 + q * 4 + j;
                    zv[j] = (n < 62) ? f32_to_f16u(sa[nt][j]) : (unsigned short)0;
                }
                *(ushort4*)(zB + o * 72 + wv * 16 + q * 4) =
                    make_ushort4(zv[0], zv[1], zv[2], zv[3]);
            }
        }
        __syncthreads();
    }

    // ---- maxpool3 + fc ----
    float a0 = 0.f, a1 = 0.f, a2 = 0.f;
    for (int t = tid; t < 620; t += 256) {
        const int n = t / 10, tt = t - (t / 10) * 10;
        const unsigned short* pr = xB + n * 40 + tt * 3;
        const float p = fmaxf(fmaxf(f16u_to_f32(pr[0]), f16u_to_f32(pr[1])),
                              f16u_to_f32(pr[2]));
        const float* fw = fcw + t * 3;
        a0 = fmaf(p, fw[0], a0);
        a1 = fmaf(p, fw[1], a1);
        a2 = fmaf(p, fw[2], a2);
    }
    #pragma unroll
    for (int off = 32; off; off >>= 1) {
        a0 += __shfl_down(a0, off);
        a1 += __shfl_down(a1, off);
        a2 += __shfl_down(a2, off);
    }
    float* red = degis;
    if (ln == 0) { red[wv * 3 + 0] = a0; red[wv * 3 + 1] = a1; red[wv * 3 + 2] = a2; }
    __syncthreads();
    if (tid == 0) {
        out[b * 3 + 0] = red[0] + red[3] + red[6] + red[9]  + fcb[0];
        out[b * 3 + 1] = red[1] + red[4] + red[7] + red[10] + fcb[1];
        out[b * 3 + 2] = red[2] + red[5] + red[8] + red[11] + fcb[2];
    }
}

// ============================== launcher ====================================
extern "C" void kernel_launch(void* const* d_in, const int* in_sizes, int n_in,
                              void* d_out, int out_size, void* d_ws, size_t ws_size,
                              hipStream_t stream) {
    const float* x     = (const float*)d_in[0];
    const float* convw = (const float*)d_in[1];
    const float* convb = (const float*)d_in[2];
    const float* bnw1  = (const float*)d_in[3];
    const float* bnb1  = (const float*)d_in[4];
    const float* gw1   = (const float*)d_in[5];
    const float* gb1   = (const float*)d_in[6];
    const float* bnw2  = (const float*)d_in[7];
    const float* bnb2  = (const float*)d_in[8];
    const float* gw2   = (const float*)d_in[9];
    const float* gb2   = (const float*)d_in[10];
    const float* bnw3  = (const float*)d_in[11];
    const float* bnb3  = (const float*)d_in[12];
    const float* gw3   = (const float*)d_in[13];
    const float* gb3   = (const float*)d_in[14];
    const float* fcw   = (const float*)d_in[15];
    const float* fcb   = (const float*)d_in[16];

    unsigned short* wp = (unsigned short*)d_ws;   // 200,704 B used

    prepack_kernel<<<392, 256, 0, stream>>>(bnw1, gw1, convw, bnw2, gw2,
                                            bnw3, gw3, wp);
    mega_kernel<<<1024, 256, 0, stream>>>(x, convb, wp, bnb1, gb1,
                                          bnb2, gb2, bnb3, gb3,
                                          fcw, fcb, (float*)d_out);
}